// Round 1
// baseline (14420.398 us; speedup 1.0000x reference)
//
#include <hip/hip_runtime.h>
#include <hip/hip_bf16.h>
#include <math.h>

// ---------------------------------------------------------------------------
// FCSwitchedBetaVAE forward, f32, correctness-first implementation.
// B=1024, C=3, L=10 latents, D=192, K=10 switches, S=10 hidden.
// ---------------------------------------------------------------------------

#define BATCH 1024

// ---------------- conv stride-2, pad-1, k=4 (NCHW, OIHW) -------------------
template<int CIN, int COUT, int HIN, int WIN, bool RELU>
__global__ __launch_bounds__(256)
void conv_s2(const float* __restrict__ in, const float* __restrict__ w,
             const float* __restrict__ bias, float* __restrict__ out) {
    constexpr int HOUT = HIN / 2, WOUT = WIN / 2;
    const size_t total = (size_t)BATCH * COUT * HOUT * WOUT;
    size_t idx = (size_t)blockIdx.x * blockDim.x + threadIdx.x;
    if (idx >= total) return;
    int ox = (int)(idx % WOUT); size_t t2 = idx / WOUT;
    int oy = (int)(t2 % HOUT); t2 /= HOUT;
    int o  = (int)(t2 % COUT); int n = (int)(t2 / COUT);
    const float* ip0 = in + ((size_t)n * CIN) * HIN * WIN;
    const float* wp0 = w + (size_t)o * CIN * 16;
    float acc = bias[o];
    const int iy0 = 2 * oy - 1, ix0 = 2 * ox - 1;
    for (int i = 0; i < CIN; ++i) {
        const float* ip = ip0 + i * HIN * WIN;
        const float* wp = wp0 + i * 16;
        #pragma unroll
        for (int ky = 0; ky < 4; ++ky) {
            int iy = iy0 + ky;
            if ((unsigned)iy >= (unsigned)HIN) continue;
            #pragma unroll
            for (int kx = 0; kx < 4; ++kx) {
                int ix = ix0 + kx;
                if ((unsigned)ix >= (unsigned)WIN) continue;
                acc = fmaf(ip[iy * WIN + ix], wp[ky * 4 + kx], acc);
            }
        }
    }
    out[idx] = RELU ? fmaxf(acc, 0.f) : acc;
}

// ------------- conv_transpose k=4 s=2 'SAME' (lhs_dilation=2, pad 2/2) -----
// weights [O][I][4][4], NO spatial flip (jax transpose_kernel=False)
template<int CIN, int COUT, int HIN, int WIN, bool RELU>
__global__ __launch_bounds__(256)
void deconv_s2(const float* __restrict__ in, const float* __restrict__ w,
               const float* __restrict__ bias, float* __restrict__ out) {
    constexpr int HOUT = HIN * 2, WOUT = WIN * 2;
    const size_t total = (size_t)BATCH * COUT * HOUT * WOUT;
    size_t idx = (size_t)blockIdx.x * blockDim.x + threadIdx.x;
    if (idx >= total) return;
    int ox = (int)(idx % WOUT); size_t t2 = idx / WOUT;
    int oy = (int)(t2 % HOUT); t2 /= HOUT;
    int o  = (int)(t2 % COUT); int n = (int)(t2 / COUT);
    const float* ip0 = in + ((size_t)n * CIN) * HIN * WIN;
    const float* wp0 = w + (size_t)o * CIN * 16;
    float acc = bias[o];
    for (int i = 0; i < CIN; ++i) {
        const float* ip = ip0 + i * HIN * WIN;
        const float* wp = wp0 + i * 16;
        #pragma unroll
        for (int ky = 0; ky < 4; ++ky) {
            int dy = oy + ky - 2;
            if (dy & 1) continue;
            int iy = dy >> 1;
            if ((unsigned)iy >= (unsigned)HIN) continue;
            #pragma unroll
            for (int kx = 0; kx < 4; ++kx) {
                int dx = ox + kx - 2;
                if (dx & 1) continue;
                int ix = dx >> 1;
                if ((unsigned)ix >= (unsigned)WIN) continue;
                acc = fmaf(ip[iy * WIN + ix], wp[ky * 4 + kx], acc);
            }
        }
    }
    out[idx] = RELU ? fmaxf(acc, 0.f) : acc;
}

// ---------------- dense FC: out[b,j] = act(in_act[b,:] @ W[:,j] + bias) ----
template<int DIN, int DOUT, bool RELU_IN, bool RELU_OUT>
__global__ __launch_bounds__(256)
void fc_kernel(const float* __restrict__ in, const float* __restrict__ w,
               const float* __restrict__ bias, float* __restrict__ out) {
    constexpr int TB = 4;
    __shared__ float a[TB][DIN];
    int b0 = blockIdx.x * TB;
    for (int idx = threadIdx.x; idx < TB * DIN; idx += 256) {
        int r = idx / DIN, c = idx % DIN;
        float v = in[(size_t)(b0 + r) * DIN + c];
        a[r][c] = RELU_IN ? fmaxf(v, 0.f) : v;
    }
    __syncthreads();
    for (int j = threadIdx.x; j < DOUT; j += 256) {
        float acc[TB];
        #pragma unroll
        for (int r = 0; r < TB; ++r) acc[r] = bias[j];
        for (int d = 0; d < DIN; ++d) {
            float wv = w[(size_t)d * DOUT + j];
            #pragma unroll
            for (int r = 0; r < TB; ++r) acc[r] = fmaf(a[r][d], wv, acc[r]);
        }
        #pragma unroll
        for (int r = 0; r < TB; ++r) {
            float v = RELU_OUT ? fmaxf(acc[r], 0.f) : acc[r];
            out[(size_t)(b0 + r) * DOUT + j] = v;
        }
    }
}

// ---------------- encoder switch (one block per batch row) -----------------
// h[b] <- h[b] + gate * (hid[b,yi,:] @ wout[yi] + bout[yi]);  stores yi, gate
__global__ __launch_bounds__(128)
void enc_switch(float* __restrict__ h,
                const float* __restrict__ win,   // [K,192,10]
                const float* __restrict__ bin,   // [K,10]
                const float* __restrict__ wout,  // [K,10,192]
                const float* __restrict__ bout,  // [K,192]
                const float* __restrict__ wsw,   // [K,10]
                const float* __restrict__ bsw,   // [K]
                const float* __restrict__ gn,    // [B,K]
                int* __restrict__ yidx, float* __restrict__ gateArr) {
    const int b = blockIdx.x, t = threadIdx.x;
    __shared__ float r[192], hold[192], hid[100], lg[10];
    __shared__ int s_yi; __shared__ float s_gate;
    for (int d = t; d < 192; d += 128) {
        float v = h[(size_t)b * 192 + d];
        hold[d] = v; r[d] = fmaxf(v, 0.f);
    }
    __syncthreads();
    if (t < 100) {
        int k = t / 10, s = t % 10;
        const float* wp = win + k * 1920 + s;
        float acc = bin[t];
        #pragma unroll 4
        for (int d = 0; d < 192; ++d) acc = fmaf(r[d], wp[d * 10], acc);
        hid[t] = acc;
    }
    __syncthreads();
    if (t < 10) {
        float acc = bsw[t];
        #pragma unroll
        for (int s = 0; s < 10; ++s) acc = fmaf(hid[t * 10 + s], wsw[t * 10 + s], acc);
        lg[t] = acc - logf(gn[(size_t)b * 10 + t] + 1e-20f);
    }
    __syncthreads();
    if (t == 0) {
        int bi = 0; float best = lg[0];
        #pragma unroll
        for (int k = 1; k < 10; ++k) if (lg[k] > best) { best = lg[k]; bi = k; }
        float sum = 0.f;
        #pragma unroll
        for (int k = 0; k < 10; ++k) sum += expf(lg[k] - best);
        float ysoft = 1.0f / sum;                 // exp(0)/sum at the argmax
        float gate = (1.0f - ysoft) + ysoft;      // straight-through arithmetic
        s_yi = bi; s_gate = gate;
        yidx[b] = bi; gateArr[b] = gate;
    }
    __syncthreads();
    const int yi = s_yi; const float gate = s_gate;
    for (int d = t; d < 192; d += 128) {
        float acc = bout[yi * 192 + d];
        const float* wp = wout + yi * 1920 + d;
        #pragma unroll
        for (int s = 0; s < 10; ++s) acc = fmaf(hid[yi * 10 + s], wp[s * 192], acc);
        h[(size_t)b * 192 + d] = hold[d] + acc * gate;
    }
}

// ---------------- decoder switch (reuses stored yi/gate) -------------------
__global__ __launch_bounds__(128)
void dec_switch(float* __restrict__ h,
                const float* __restrict__ win,   // [K,192,10]
                const float* __restrict__ bin,   // [K,10]
                const float* __restrict__ wout,  // [K,10,192]
                const float* __restrict__ bout,  // [K,192]
                const int* __restrict__ yidx, const float* __restrict__ gateArr) {
    const int b = blockIdx.x, t = threadIdx.x;
    __shared__ float r[192], hold[192], part[120], hid[10];
    const int yi = yidx[b]; const float gate = gateArr[b];
    for (int d = t; d < 192; d += 128) {
        float v = h[(size_t)b * 192 + d];
        hold[d] = v; r[d] = fmaxf(v, 0.f);
    }
    __syncthreads();
    if (t < 120) {   // s = t%10, 12 groups of 16 d's
        int s = t % 10, g = t / 10;
        const float* wp = win + yi * 1920 + s;
        float acc = 0.f;
        #pragma unroll
        for (int d = g * 16; d < g * 16 + 16; ++d) acc = fmaf(r[d], wp[d * 10], acc);
        part[t] = acc;
    }
    __syncthreads();
    if (t < 10) {
        float acc = bin[yi * 10 + t];
        #pragma unroll
        for (int g = 0; g < 12; ++g) acc += part[g * 10 + t];
        hid[t] = acc;
    }
    __syncthreads();
    for (int d = t; d < 192; d += 128) {
        float acc = bout[yi * 192 + d];
        const float* wp = wout + yi * 1920 + d;
        #pragma unroll
        for (int s = 0; s < 10; ++s) acc = fmaf(hid[s], wp[s * 192], acc);
        h[(size_t)b * 192 + d] = hold[d] + acc * gate;
    }
}

// ------- z stats + reparameterize + decoder input FC (one block per b) -----
__global__ __launch_bounds__(192)
void zfcl_kernel(const float* __restrict__ h,
                 const float* __restrict__ mw, const float* __restrict__ mb,   // [192,10],[10]
                 const float* __restrict__ lw, const float* __restrict__ lb,   // [192,10],[10]
                 const float* __restrict__ zn,                                  // [B,10]
                 const float* __restrict__ fw, const float* __restrict__ fb,   // [10,192],[192]
                 float* __restrict__ out_z, float* __restrict__ out_mean,
                 float* __restrict__ out_lv, float* __restrict__ dbuf) {
    const int b = blockIdx.x, t = threadIdx.x;
    __shared__ float r[192], pm[160], pl[160], zsh[10];
    for (int d = t; d < 192; d += 192) r[d] = fmaxf(h[(size_t)b * 192 + d], 0.f);
    __syncthreads();
    if (t < 160) {   // l = t%10, 16 groups of 12 d's
        int l = t % 10, g = t / 10;
        float am = 0.f, al = 0.f;
        #pragma unroll
        for (int d = g * 12; d < g * 12 + 12; ++d) {
            am = fmaf(r[d], mw[d * 10 + l], am);
            al = fmaf(r[d], lw[d * 10 + l], al);
        }
        pm[t] = am; pl[t] = al;
    }
    __syncthreads();
    if (t < 10) {
        float zm = mb[t], zl = lb[t];
        #pragma unroll
        for (int g = 0; g < 16; ++g) { zm += pm[g * 10 + t]; zl += pl[g * 10 + t]; }
        float z = zn[(size_t)b * 10 + t] * expf(zl * 0.5f) + zm;
        out_mean[(size_t)b * 10 + t] = zm;
        out_lv[(size_t)b * 10 + t] = zl;
        out_z[(size_t)b * 10 + t] = z;
        zsh[t] = z;
    }
    __syncthreads();
    for (int d = t; d < 192; d += 192) {
        float acc = fb[d];
        #pragma unroll
        for (int l = 0; l < 10; ++l) acc = fmaf(zsh[l], fw[l * 192 + d], acc);
        dbuf[(size_t)b * 192 + d] = acc;
    }
}

// ---------------------------------------------------------------------------
extern "C" void kernel_launch(void* const* d_in, const int* in_sizes, int n_in,
                              void* d_out, int out_size, void* d_ws, size_t ws_size,
                              hipStream_t stream) {
    const float* x      = (const float*)d_in[0];
    const float* gnoise = (const float*)d_in[1];
    const float* znoise = (const float*)d_in[2];
    const float* cw1 = (const float*)d_in[3];  const float* cb1 = (const float*)d_in[4];
    const float* cw2 = (const float*)d_in[5];  const float* cb2 = (const float*)d_in[6];
    const float* cw3 = (const float*)d_in[7];  const float* cb3 = (const float*)d_in[8];
    const float* cw4 = (const float*)d_in[9];  const float* cb4 = (const float*)d_in[10];
    const float* fc_w = (const float*)d_in[11]; const float* fc_b = (const float*)d_in[12];
    const float* ein_w = (const float*)d_in[13]; const float* ein_b = (const float*)d_in[14];
    const float* eout_w = (const float*)d_in[15]; const float* eout_b = (const float*)d_in[16];
    const float* esw_w = (const float*)d_in[17]; const float* esw_b = (const float*)d_in[18];
    const float* mean_w = (const float*)d_in[19]; const float* mean_b = (const float*)d_in[20];
    const float* lv_w = (const float*)d_in[21]; const float* lv_b = (const float*)d_in[22];
    const float* fcl_w = (const float*)d_in[23]; const float* fcl_b = (const float*)d_in[24];
    const float* din_w = (const float*)d_in[25]; const float* din_b = (const float*)d_in[26];
    const float* dout_w = (const float*)d_in[27]; const float* dout_b = (const float*)d_in[28];
    const float* dfc_w = (const float*)d_in[29]; const float* dfc_b = (const float*)d_in[30];
    const float* dw1 = (const float*)d_in[31]; const float* db1 = (const float*)d_in[32];
    const float* dw2 = (const float*)d_in[33]; const float* db2 = (const float*)d_in[34];
    const float* dw3 = (const float*)d_in[35]; const float* db3 = (const float*)d_in[36];
    const float* dw4 = (const float*)d_in[37]; const float* db4 = (const float*)d_in[38];

    float* out = (float*)d_out;
    float* recon  = out;                        // [1024,3,64,64]
    float* z_out  = out + 12582912;             // [1024,10]
    float* zm_out = z_out + 10240;              // [1024,10]
    float* zl_out = zm_out + 10240;             // [1024,10]

    // workspace layout (bytes)
    char* ws = (char*)d_ws;
    float* bufA  = (float*)(ws);                             // 33554432 f (conv1 out / deconv3 out)
    float* bufB  = (float*)(ws + 134217728);                 //  8388608 f (conv2 out / deconv2 out)
    float* bufC  = (float*)(ws + 134217728 + 33554432);      //  4194304 f (conv3 out / deconv1 out)
    float* bufD  = (float*)(ws + 134217728 + 33554432 + 16777216);             // 1048576 f (conv4 out / dfc out)
    float* bufH  = (float*)(ws + 134217728 + 33554432 + 16777216 + 4194304);   //  196608 f (encoder h)
    float* bufD2 = (float*)(ws + 134217728 + 33554432 + 16777216 + 4194304 + 786432); // 196608 f (decoder d)
    int*   yidx  = (int*)  (ws + 134217728 + 33554432 + 16777216 + 4194304 + 786432 + 786432); // 10240 i
    float* gate  = (float*)(ws + 134217728 + 33554432 + 16777216 + 4194304 + 786432 + 786432 + 40960); // 10240 f

    // ---- encoder convs ----
    conv_s2<3, 32, 64, 64, true><<<(1024 * 32 * 1024 + 255) / 256, 256, 0, stream>>>(x, cw1, cb1, bufA);
    conv_s2<32, 32, 32, 32, true><<<(1024 * 32 * 256 + 255) / 256, 256, 0, stream>>>(bufA, cw2, cb2, bufB);
    conv_s2<32, 64, 16, 16, true><<<(1024 * 64 * 64 + 255) / 256, 256, 0, stream>>>(bufB, cw3, cb3, bufC);
    conv_s2<64, 64, 8, 8, true><<<(1024 * 64 * 16 + 255) / 256, 256, 0, stream>>>(bufC, cw4, cb4, bufD);

    // ---- fc to h [1024,192] ----
    fc_kernel<1024, 192, false, false><<<256, 256, 0, stream>>>(bufD, fc_w, fc_b, bufH);

    // ---- encoder switches ----
    for (int i = 0; i < 10; ++i) {
        enc_switch<<<1024, 128, 0, stream>>>(bufH,
            ein_w + (size_t)i * 19200, ein_b + (size_t)i * 100,
            eout_w + (size_t)i * 19200, eout_b + (size_t)i * 1920,
            esw_w + (size_t)i * 100, esw_b + (size_t)i * 10,
            gnoise + (size_t)i * 10240,
            yidx + (size_t)i * 1024, gate + (size_t)i * 1024);
    }

    // ---- z stats + reparam + decoder input fc ----
    zfcl_kernel<<<1024, 192, 0, stream>>>(bufH, mean_w, mean_b, lv_w, lv_b,
                                          znoise, fcl_w, fcl_b,
                                          z_out, zm_out, zl_out, bufD2);

    // ---- decoder switches ----
    for (int i = 0; i < 10; ++i) {
        dec_switch<<<1024, 128, 0, stream>>>(bufD2,
            din_w + (size_t)i * 19200, din_b + (size_t)i * 100,
            dout_w + (size_t)i * 19200, dout_b + (size_t)i * 1920,
            yidx + (size_t)i * 1024, gate + (size_t)i * 1024);
    }

    // ---- decoder fc: e = relu(relu(d) @ dfc_w + dfc_b) ----
    fc_kernel<192, 1024, true, true><<<256, 256, 0, stream>>>(bufD2, dfc_w, dfc_b, bufD);

    // ---- decoder deconvs ----
    deconv_s2<64, 64, 4, 4, true><<<(1024 * 64 * 64 + 255) / 256, 256, 0, stream>>>(bufD, dw1, db1, bufC);
    deconv_s2<64, 32, 8, 8, true><<<(1024 * 32 * 256 + 255) / 256, 256, 0, stream>>>(bufC, dw2, db2, bufB);
    deconv_s2<32, 32, 16, 16, true><<<(1024 * 32 * 1024 + 255) / 256, 256, 0, stream>>>(bufB, dw3, db3, bufA);
    deconv_s2<32, 3, 32, 32, false><<<(1024 * 3 * 4096 + 255) / 256, 256, 0, stream>>>(bufA, dw4, db4, recon);
}

// Round 2
// 5460.772 us; speedup vs baseline: 2.6407x; 2.6407x over previous
//
#include <hip/hip_runtime.h>
#include <hip/hip_bf16.h>
#include <math.h>

// ---------------------------------------------------------------------------
// FCSwitchedBetaVAE forward. NHWC intermediates, broadcast+float4 conv kernels,
// parity-decomposed deconvs, fused switch chains. f32 throughout.
// B=1024, C=3, L=10, D=192, K=10, S=10.
// ---------------------------------------------------------------------------

#define BATCH 1024

// ---------- weight transpose: w[(o*CIN+i)*16+tap] -> wt4[(tap*IG+ig)*COUT+o] ----
__global__ void transpose_w4(const float* __restrict__ w, float4* __restrict__ wt,
                             int CIN, int COUT) {
    int IG = CIN >> 2;
    int total = 16 * IG * COUT;
    int idx = blockIdx.x * 256 + threadIdx.x;
    if (idx >= total) return;
    int o = idx % COUT;
    int ig = (idx / COUT) % IG;
    int tap = idx / (COUT * IG);
    float4 v;
    v.x = w[((size_t)(o * CIN + ig * 4 + 0) << 4) + tap];
    v.y = w[((size_t)(o * CIN + ig * 4 + 1) << 4) + tap];
    v.z = w[((size_t)(o * CIN + ig * 4 + 2) << 4) + tap];
    v.w = w[((size_t)(o * CIN + ig * 4 + 3) << 4) + tap];
    wt[idx] = v;
}

// conv1 weights (CIN=3, COUT=32): wt[(tap*3+i)*32+o] = w[(o*3+i)*16+tap]
__global__ void transpose_w_c1(const float* __restrict__ w, float* __restrict__ wt) {
    int idx = blockIdx.x * 256 + threadIdx.x;
    if (idx >= 16 * 3 * 32) return;
    int o = idx % 32;
    int i = (idx / 32) % 3;
    int tap = idx / 96;
    wt[idx] = w[(o * 3 + i) * 16 + tap];
}

// ---------------- conv1: NCHW [B,3,64,64] -> NHWC [B,32,32,32ch] -----------
template<int PPT>
__global__ __launch_bounds__(256)
void conv1_k(const float* __restrict__ x, const float* __restrict__ wt,
             const float* __restrict__ bias, float* __restrict__ out) {
    constexpr int COUT = 32, HIN = 64, WIN = 64, HOUT = 32, WOUT = 32;
    constexpr int NXG = WOUT / PPT;
    const int tid = threadIdx.x;
    const int o = tid & 31;
    const int gl = tid >> 5;
    const int gg = blockIdx.x * 8 + gl;
    const int oxg = gg % NXG;
    int t1 = gg / NXG;
    const int oy = t1 % HOUT;
    const int n = t1 / HOUT;
    const int ox0 = oxg * PPT;
    float acc[PPT];
    const float bv = bias[o];
    #pragma unroll
    for (int q = 0; q < PPT; ++q) acc[q] = bv;
    const float* xb = x + (size_t)n * 3 * 4096;
    const int iy0 = 2 * oy - 1, ix00 = 2 * ox0 - 1;
    const bool interior = (ox0 >= 1) && (ox0 <= WOUT - PPT - 1);
    #pragma unroll
    for (int ky = 0; ky < 4; ++ky) {
        const int iy = iy0 + ky;
        if ((unsigned)iy >= (unsigned)HIN) continue;
        #pragma unroll
        for (int kx = 0; kx < 4; ++kx) {
            const int tap = ky * 4 + kx;
            const int ixb = ix00 + kx;
            #pragma unroll
            for (int i = 0; i < 3; ++i) {
                const float wv = wt[(tap * 3 + i) * 32 + o];
                const float* xr = xb + ((size_t)i * HIN + iy) * WIN;
                if (interior) {
                    #pragma unroll
                    for (int q = 0; q < PPT; ++q)
                        acc[q] = fmaf(xr[ixb + 2 * q], wv, acc[q]);
                } else {
                    #pragma unroll
                    for (int q = 0; q < PPT; ++q) {
                        const int ix = ixb + 2 * q;
                        if ((unsigned)ix < (unsigned)WIN)
                            acc[q] = fmaf(xr[ix], wv, acc[q]);
                    }
                }
            }
        }
    }
    float* orow = out + (((size_t)n * HOUT + oy) * WOUT + ox0) * COUT + o;
    #pragma unroll
    for (int q = 0; q < PPT; ++q) orow[q * COUT] = fmaxf(acc[q], 0.f);
}

// ---------------- generic conv: NHWC -> NHWC, stride 2, pad 1, k4 ----------
template<int CIN, int COUT, int HIN, int WIN, int PPT, bool RELU>
__global__ __launch_bounds__(256)
void conv_nhwc(const float* __restrict__ in, const float4* __restrict__ wt,
               const float* __restrict__ bias, float* __restrict__ out) {
    constexpr int HOUT = HIN / 2, WOUT = WIN / 2, IG = CIN / 4, G = 256 / COUT;
    constexpr int NXG = WOUT / PPT;
    const int tid = threadIdx.x;
    const int o = tid % COUT;
    const int gl = tid / COUT;
    const int gg = blockIdx.x * G + gl;
    const int oxg = gg % NXG;
    int t1 = gg / NXG;
    const int oy = t1 % HOUT;
    const int n = t1 / HOUT;
    const int ox0 = oxg * PPT;
    float acc[PPT];
    const float bv = bias[o];
    #pragma unroll
    for (int q = 0; q < PPT; ++q) acc[q] = bv;
    const float* ibase = in + (size_t)n * HIN * WIN * CIN;
    const int iy0 = 2 * oy - 1, ix00 = 2 * ox0 - 1;
    const bool interior = (ox0 >= 1) && (ox0 <= WOUT - PPT - 1);
    #pragma unroll
    for (int ky = 0; ky < 4; ++ky) {
        const int iy = iy0 + ky;
        if ((unsigned)iy >= (unsigned)HIN) continue;
        const float* irow = ibase + (size_t)iy * WIN * CIN;
        #pragma unroll
        for (int kx = 0; kx < 4; ++kx) {
            const int ixb = ix00 + kx;
            const float4* wrow = wt + (size_t)(ky * 4 + kx) * IG * COUT + o;
            if (interior) {
                for (int ig = 0; ig < IG; ++ig) {
                    const float4 wv = wrow[ig * COUT];
                    #pragma unroll
                    for (int q = 0; q < PPT; ++q) {
                        const float4 xv = *(const float4*)(irow + (size_t)(ixb + 2 * q) * CIN + ig * 4);
                        acc[q] = fmaf(xv.x, wv.x, acc[q]);
                        acc[q] = fmaf(xv.y, wv.y, acc[q]);
                        acc[q] = fmaf(xv.z, wv.z, acc[q]);
                        acc[q] = fmaf(xv.w, wv.w, acc[q]);
                    }
                }
            } else {
                for (int ig = 0; ig < IG; ++ig) {
                    const float4 wv = wrow[ig * COUT];
                    #pragma unroll
                    for (int q = 0; q < PPT; ++q) {
                        const int ix = ixb + 2 * q;
                        if ((unsigned)ix < (unsigned)WIN) {
                            const float4 xv = *(const float4*)(irow + (size_t)ix * CIN + ig * 4);
                            acc[q] = fmaf(xv.x, wv.x, acc[q]);
                            acc[q] = fmaf(xv.y, wv.y, acc[q]);
                            acc[q] = fmaf(xv.z, wv.z, acc[q]);
                            acc[q] = fmaf(xv.w, wv.w, acc[q]);
                        }
                    }
                }
            }
        }
    }
    float* orow = out + (((size_t)n * HOUT + oy) * WOUT + ox0) * COUT + o;
    #pragma unroll
    for (int q = 0; q < PPT; ++q) {
        float v = RELU ? fmaxf(acc[q], 0.f) : acc[q];
        orow[q * COUT] = v;
    }
}

// ------- generic deconv (k4,s2,'SAME'): NHWC -> NHWC, parity-decomposed ----
// out(oy,ox): taps ky=kyA+2a (kyA=oy&1), iy=iyA+a, iyA=((oy+kyA)>>1)-1; same for x.
// Thread owns PPT same-parity pixels (ox = 2*(j0+q)+px) so the tap is uniform.
template<int CIN, int COUT, int HIN, int WIN, int PPT, bool RELU>
__global__ __launch_bounds__(256)
void deconv_nhwc(const float* __restrict__ in, const float4* __restrict__ wt,
                 const float* __restrict__ bias, float* __restrict__ out) {
    constexpr int HOUT = 2 * HIN, WOUT = 2 * WIN, IG = CIN / 4, G = 256 / COUT;
    constexpr int NJ = WIN / PPT;
    const int tid = threadIdx.x;
    const int o = tid % COUT;
    const int gl = tid / COUT;
    const int gg = blockIdx.x * G + gl;
    const int jg = gg % NJ;
    int t1 = gg / NJ;
    const int px = t1 & 1;
    int t2 = t1 >> 1;
    const int oy = t2 % HOUT;
    const int n = t2 / HOUT;
    const int j0 = jg * PPT;
    const int kyA = oy & 1;
    const int iyA = ((oy + kyA) >> 1) - 1;
    const int ixA0 = j0 + px - 1;
    float acc[PPT];
    const float bv = bias[o];
    #pragma unroll
    for (int q = 0; q < PPT; ++q) acc[q] = bv;
    const float* ibase = in + (size_t)n * HIN * WIN * CIN;
    const bool interior = (ixA0 >= 0) && (ixA0 + PPT <= WIN - 1);
    #pragma unroll
    for (int a = 0; a < 2; ++a) {
        const int iy = iyA + a;
        if ((unsigned)iy >= (unsigned)HIN) continue;
        const int ky = kyA + 2 * a;
        const float* irow = ibase + (size_t)iy * WIN * CIN;
        #pragma unroll
        for (int bb = 0; bb < 2; ++bb) {
            const int kx = px + 2 * bb;
            const float4* wrow = wt + (size_t)(ky * 4 + kx) * IG * COUT + o;
            if (interior) {
                for (int ig = 0; ig < IG; ++ig) {
                    const float4 wv = wrow[ig * COUT];
                    #pragma unroll
                    for (int q = 0; q < PPT; ++q) {
                        const float4 xv = *(const float4*)(irow + (size_t)(ixA0 + q + bb) * CIN + ig * 4);
                        acc[q] = fmaf(xv.x, wv.x, acc[q]);
                        acc[q] = fmaf(xv.y, wv.y, acc[q]);
                        acc[q] = fmaf(xv.z, wv.z, acc[q]);
                        acc[q] = fmaf(xv.w, wv.w, acc[q]);
                    }
                }
            } else {
                for (int ig = 0; ig < IG; ++ig) {
                    const float4 wv = wrow[ig * COUT];
                    #pragma unroll
                    for (int q = 0; q < PPT; ++q) {
                        const int ix = ixA0 + q + bb;
                        if ((unsigned)ix < (unsigned)WIN) {
                            const float4 xv = *(const float4*)(irow + (size_t)ix * CIN + ig * 4);
                            acc[q] = fmaf(xv.x, wv.x, acc[q]);
                            acc[q] = fmaf(xv.y, wv.y, acc[q]);
                            acc[q] = fmaf(xv.z, wv.z, acc[q]);
                            acc[q] = fmaf(xv.w, wv.w, acc[q]);
                        }
                    }
                }
            }
        }
    }
    float* obase = out + (((size_t)n * HOUT + oy) * WOUT) * COUT + o;
    #pragma unroll
    for (int q = 0; q < PPT; ++q) {
        float v = RELU ? fmaxf(acc[q], 0.f) : acc[q];
        obase[(size_t)(2 * (j0 + q) + px) * COUT] = v;
    }
}

// ---- last deconv: NHWC [B,32,32,32ch] -> NCHW [B,3,64,64], no relu --------
__global__ __launch_bounds__(256)
void deconv_last(const float* __restrict__ in, const float4* __restrict__ wt,
                 const float* __restrict__ bias, float* __restrict__ out) {
    constexpr int CIN = 32, IG = 8, HIN = 32, WIN = 32;
    const int idx = blockIdx.x * 256 + threadIdx.x;   // B*64*64
    const int ox = idx & 63;
    const int oy = (idx >> 6) & 63;
    const int n = idx >> 12;
    const int kyA = oy & 1, kxA = ox & 1;
    const int iyA = ((oy + kyA) >> 1) - 1;
    const int ixA = ((ox + kxA) >> 1) - 1;
    float a0 = bias[0], a1 = bias[1], a2 = bias[2];
    const float* ibase = in + (size_t)n * HIN * WIN * CIN;
    #pragma unroll
    for (int a = 0; a < 2; ++a) {
        const int iy = iyA + a;
        if ((unsigned)iy >= (unsigned)HIN) continue;
        const int ky = kyA + 2 * a;
        const float* irow = ibase + (size_t)iy * WIN * CIN;
        #pragma unroll
        for (int bb = 0; bb < 2; ++bb) {
            const int kx = kxA + 2 * bb;
            const int ix = ixA + bb;
            const float4* wrow = wt + (size_t)(ky * 4 + kx) * IG * 3;
            const float4* xr = (const float4*)(irow + (size_t)ix * CIN);
            if ((unsigned)ix < (unsigned)WIN) {
                for (int ig = 0; ig < IG; ++ig) {
                    const float4 xv = xr[ig];
                    const float4 w0 = wrow[ig * 3 + 0];
                    const float4 w1 = wrow[ig * 3 + 1];
                    const float4 w2 = wrow[ig * 3 + 2];
                    a0 = fmaf(xv.x, w0.x, a0); a0 = fmaf(xv.y, w0.y, a0);
                    a0 = fmaf(xv.z, w0.z, a0); a0 = fmaf(xv.w, w0.w, a0);
                    a1 = fmaf(xv.x, w1.x, a1); a1 = fmaf(xv.y, w1.y, a1);
                    a1 = fmaf(xv.z, w1.z, a1); a1 = fmaf(xv.w, w1.w, a1);
                    a2 = fmaf(xv.x, w2.x, a2); a2 = fmaf(xv.y, w2.y, a2);
                    a2 = fmaf(xv.z, w2.z, a2); a2 = fmaf(xv.w, w2.w, a2);
                }
            }
        }
    }
    float* ob = out + (size_t)n * 3 * 4096 + (size_t)oy * 64 + ox;
    ob[0] = a0; ob[4096] = a1; ob[8192] = a2;
}

// ---------------- dense FC with optional index remaps ----------------------
template<int DIN, int DOUT, bool RELU_IN, bool RELU_OUT, bool REMAP_IN, bool REMAP_OUT>
__global__ __launch_bounds__(256)
void fc_kernel(const float* __restrict__ in, const float* __restrict__ w,
               const float* __restrict__ bias, float* __restrict__ out) {
    constexpr int TB = 4;
    __shared__ float a[TB][DIN];
    const int b0 = blockIdx.x * TB;
    for (int idx = threadIdx.x; idx < TB * DIN; idx += 256) {
        int r = idx / DIN, c = idx % DIN;
        float v = in[(size_t)(b0 + r) * DIN + c];
        if (RELU_IN) v = fmaxf(v, 0.f);
        int d = REMAP_IN ? ((c & 63) * 16 + (c >> 6)) : c;   // NHWC(p*64+ch) -> ch*16+p
        a[r][d] = v;
    }
    __syncthreads();
    for (int j = threadIdx.x; j < DOUT; j += 256) {
        float acc[TB];
        #pragma unroll
        for (int r = 0; r < TB; ++r) acc[r] = bias[j];
        for (int d = 0; d < DIN; ++d) {
            const float wv = w[(size_t)d * DOUT + j];
            #pragma unroll
            for (int r = 0; r < TB; ++r) acc[r] = fmaf(a[r][d], wv, acc[r]);
        }
        const int jo = REMAP_OUT ? (((j & 15) << 6) + (j >> 4)) : j;  // ch*16+p -> p*64+ch
        #pragma unroll
        for (int r = 0; r < TB; ++r) {
            float v = RELU_OUT ? fmaxf(acc[r], 0.f) : acc[r];
            out[(size_t)(b0 + r) * DOUT + jo] = v;
        }
    }
}

// ---------------- fused encoder switch chain (all 10 latents) --------------
__global__ __launch_bounds__(128)
void enc_switch_all(float* __restrict__ h,
                    const float* __restrict__ win_all, const float* __restrict__ bin_all,
                    const float* __restrict__ wout_all, const float* __restrict__ bout_all,
                    const float* __restrict__ wsw_all, const float* __restrict__ bsw_all,
                    const float* __restrict__ gn_all,
                    int* __restrict__ yidx, float* __restrict__ gateArr) {
    const int b = blockIdx.x, t = threadIdx.x;
    __shared__ float hold[192], r[192], hid[100], lg[10];
    __shared__ int s_yi; __shared__ float s_gate;
    for (int d = t; d < 192; d += 128) hold[d] = h[(size_t)b * 192 + d];
    for (int i = 0; i < 10; ++i) {
        const float* win = win_all + (size_t)i * 19200;
        const float* bin = bin_all + (size_t)i * 100;
        const float* wout = wout_all + (size_t)i * 19200;
        const float* bout = bout_all + (size_t)i * 1920;
        const float* wsw = wsw_all + (size_t)i * 100;
        const float* bsw = bsw_all + (size_t)i * 10;
        const float* gn = gn_all + (size_t)i * 10240;
        __syncthreads();
        for (int d = t; d < 192; d += 128) r[d] = fmaxf(hold[d], 0.f);
        __syncthreads();
        if (t < 100) {
            const int k = t / 10, s = t % 10;
            const float* wp = win + k * 1920 + s;
            float acc = bin[t];
            #pragma unroll 4
            for (int d = 0; d < 192; ++d) acc = fmaf(r[d], wp[d * 10], acc);
            hid[t] = acc;
        }
        __syncthreads();
        if (t < 10) {
            float acc = bsw[t];
            #pragma unroll
            for (int s = 0; s < 10; ++s) acc = fmaf(hid[t * 10 + s], wsw[t * 10 + s], acc);
            lg[t] = acc - logf(gn[(size_t)b * 10 + t] + 1e-20f);
        }
        __syncthreads();
        if (t == 0) {
            int bi = 0; float best = lg[0];
            #pragma unroll
            for (int k = 1; k < 10; ++k) if (lg[k] > best) { best = lg[k]; bi = k; }
            float sum = 0.f;
            #pragma unroll
            for (int k = 0; k < 10; ++k) sum += expf(lg[k] - best);
            const float ysoft = 1.0f / sum;
            s_yi = bi; s_gate = (1.0f - ysoft) + ysoft;
            yidx[i * 1024 + b] = bi; gateArr[i * 1024 + b] = s_gate;
        }
        __syncthreads();
        const int yi = s_yi; const float gate = s_gate;
        for (int d = t; d < 192; d += 128) {
            float acc = bout[yi * 192 + d];
            const float* wp = wout + yi * 1920 + d;
            #pragma unroll
            for (int s = 0; s < 10; ++s) acc = fmaf(hid[yi * 10 + s], wp[s * 192], acc);
            hold[d] += acc * gate;
        }
    }
    __syncthreads();
    for (int d = t; d < 192; d += 128) h[(size_t)b * 192 + d] = hold[d];
}

// ---------------- fused decoder switch chain -------------------------------
__global__ __launch_bounds__(128)
void dec_switch_all(float* __restrict__ h,
                    const float* __restrict__ win_all, const float* __restrict__ bin_all,
                    const float* __restrict__ wout_all, const float* __restrict__ bout_all,
                    const int* __restrict__ yidx, const float* __restrict__ gateArr) {
    const int b = blockIdx.x, t = threadIdx.x;
    __shared__ float hold[192], r[192], part[120], hid[10];
    for (int d = t; d < 192; d += 128) hold[d] = h[(size_t)b * 192 + d];
    for (int i = 0; i < 10; ++i) {
        const int yi = yidx[i * 1024 + b];
        const float gate = gateArr[i * 1024 + b];
        const float* win = win_all + (size_t)i * 19200 + yi * 1920;
        const float* bin = bin_all + (size_t)i * 100 + yi * 10;
        const float* wout = wout_all + (size_t)i * 19200 + yi * 1920;
        const float* bout = bout_all + (size_t)i * 1920 + yi * 192;
        __syncthreads();
        for (int d = t; d < 192; d += 128) r[d] = fmaxf(hold[d], 0.f);
        __syncthreads();
        if (t < 120) {
            const int s = t % 10, g = t / 10;
            float acc = 0.f;
            #pragma unroll
            for (int d = g * 16; d < g * 16 + 16; ++d) acc = fmaf(r[d], win[d * 10 + s], acc);
            part[t] = acc;
        }
        __syncthreads();
        if (t < 10) {
            float acc = bin[t];
            #pragma unroll
            for (int g = 0; g < 12; ++g) acc += part[g * 10 + t];
            hid[t] = acc;
        }
        __syncthreads();
        for (int d = t; d < 192; d += 128) {
            float acc = bout[d];
            #pragma unroll
            for (int s = 0; s < 10; ++s) acc = fmaf(hid[s], wout[s * 192 + d], acc);
            hold[d] += acc * gate;
        }
    }
    __syncthreads();
    for (int d = t; d < 192; d += 128) h[(size_t)b * 192 + d] = hold[d];
}

// ------- z stats + reparameterize + decoder input FC -----------------------
__global__ __launch_bounds__(192)
void zfcl_kernel(const float* __restrict__ h,
                 const float* __restrict__ mw, const float* __restrict__ mb,
                 const float* __restrict__ lw, const float* __restrict__ lb,
                 const float* __restrict__ zn,
                 const float* __restrict__ fw, const float* __restrict__ fb,
                 float* __restrict__ out_z, float* __restrict__ out_mean,
                 float* __restrict__ out_lv, float* __restrict__ dbuf) {
    const int b = blockIdx.x, t = threadIdx.x;
    __shared__ float r[192], pm[160], pl[160], zsh[10];
    for (int d = t; d < 192; d += 192) r[d] = fmaxf(h[(size_t)b * 192 + d], 0.f);
    __syncthreads();
    if (t < 160) {
        const int l = t % 10, g = t / 10;
        float am = 0.f, al = 0.f;
        #pragma unroll
        for (int d = g * 12; d < g * 12 + 12; ++d) {
            am = fmaf(r[d], mw[d * 10 + l], am);
            al = fmaf(r[d], lw[d * 10 + l], al);
        }
        pm[t] = am; pl[t] = al;
    }
    __syncthreads();
    if (t < 10) {
        float zm = mb[t], zl = lb[t];
        #pragma unroll
        for (int g = 0; g < 16; ++g) { zm += pm[g * 10 + t]; zl += pl[g * 10 + t]; }
        const float z = zn[(size_t)b * 10 + t] * expf(zl * 0.5f) + zm;
        out_mean[(size_t)b * 10 + t] = zm;
        out_lv[(size_t)b * 10 + t] = zl;
        out_z[(size_t)b * 10 + t] = z;
        zsh[t] = z;
    }
    __syncthreads();
    for (int d = t; d < 192; d += 192) {
        float acc = fb[d];
        #pragma unroll
        for (int l = 0; l < 10; ++l) acc = fmaf(zsh[l], fw[l * 192 + d], acc);
        dbuf[(size_t)b * 192 + d] = acc;
    }
}

// ---------------------------------------------------------------------------
extern "C" void kernel_launch(void* const* d_in, const int* in_sizes, int n_in,
                              void* d_out, int out_size, void* d_ws, size_t ws_size,
                              hipStream_t stream) {
    const float* x      = (const float*)d_in[0];
    const float* gnoise = (const float*)d_in[1];
    const float* znoise = (const float*)d_in[2];
    const float* cw1 = (const float*)d_in[3];  const float* cb1 = (const float*)d_in[4];
    const float* cw2 = (const float*)d_in[5];  const float* cb2 = (const float*)d_in[6];
    const float* cw3 = (const float*)d_in[7];  const float* cb3 = (const float*)d_in[8];
    const float* cw4 = (const float*)d_in[9];  const float* cb4 = (const float*)d_in[10];
    const float* fc_w = (const float*)d_in[11]; const float* fc_b = (const float*)d_in[12];
    const float* ein_w = (const float*)d_in[13]; const float* ein_b = (const float*)d_in[14];
    const float* eout_w = (const float*)d_in[15]; const float* eout_b = (const float*)d_in[16];
    const float* esw_w = (const float*)d_in[17]; const float* esw_b = (const float*)d_in[18];
    const float* mean_w = (const float*)d_in[19]; const float* mean_b = (const float*)d_in[20];
    const float* lv_w = (const float*)d_in[21]; const float* lv_b = (const float*)d_in[22];
    const float* fcl_w = (const float*)d_in[23]; const float* fcl_b = (const float*)d_in[24];
    const float* din_w = (const float*)d_in[25]; const float* din_b = (const float*)d_in[26];
    const float* dout_w = (const float*)d_in[27]; const float* dout_b = (const float*)d_in[28];
    const float* dfc_w = (const float*)d_in[29]; const float* dfc_b = (const float*)d_in[30];
    const float* dw1 = (const float*)d_in[31]; const float* db1 = (const float*)d_in[32];
    const float* dw2 = (const float*)d_in[33]; const float* db2 = (const float*)d_in[34];
    const float* dw3 = (const float*)d_in[35]; const float* db3 = (const float*)d_in[36];
    const float* dw4 = (const float*)d_in[37]; const float* db4 = (const float*)d_in[38];

    float* out = (float*)d_out;
    float* recon  = out;
    float* z_out  = out + 12582912;
    float* zm_out = z_out + 10240;
    float* zl_out = zm_out + 10240;

    char* ws = (char*)d_ws;
    float* bufA  = (float*)(ws);                    // 134 MB NHWC [B,32,32,32ch] (conv1/deconv3)
    float* bufD  = (float*)(ws);                    // 4 MB, aliased into dead bufA window
    float* bufB  = (float*)(ws + 134217728);        // 33.5 MB NHWC [B,16,16,32] (conv2/deconv2)
    float* bufC  = (float*)(ws + 167772160);        // 16.8 MB NHWC [B,8,8,64]  (conv3/deconv1)
    float* bufH  = (float*)(ws + 184549376);        // [B,192] encoder h
    float* bufD2 = (float*)(ws + 185335808);        // [B,192] decoder d
    int*   yidx  = (int*)  (ws + 186122240);        // [10,1024]
    float* gate  = (float*)(ws + 186163200);        // [10,1024]
    char*  wbase = ws + 186204160;
    float*  wt_c1 = (float*) (wbase);               //   6144 B
    float4* wt_c2 = (float4*)(wbase + 6144);        //  65536 B
    float4* wt_c3 = (float4*)(wbase + 71680);       // 131072 B
    float4* wt_c4 = (float4*)(wbase + 202752);      // 262144 B
    float4* wt_d1 = (float4*)(wbase + 464896);      // 262144 B
    float4* wt_d2 = (float4*)(wbase + 727040);      // 131072 B
    float4* wt_d3 = (float4*)(wbase + 858112);      //  65536 B
    float4* wt_d4 = (float4*)(wbase + 923648);      //   6144 B

    // ---- weight transposes ----
    transpose_w_c1<<<6, 256, 0, stream>>>(cw1, wt_c1);
    transpose_w4<<<(16*8*32 + 255)/256, 256, 0, stream>>>(cw2, wt_c2, 32, 32);
    transpose_w4<<<(16*8*64 + 255)/256, 256, 0, stream>>>(cw3, wt_c3, 32, 64);
    transpose_w4<<<(16*16*64 + 255)/256, 256, 0, stream>>>(cw4, wt_c4, 64, 64);
    transpose_w4<<<(16*16*64 + 255)/256, 256, 0, stream>>>(dw1, wt_d1, 64, 64);
    transpose_w4<<<(16*16*32 + 255)/256, 256, 0, stream>>>(dw2, wt_d2, 64, 32);
    transpose_w4<<<(16*8*32 + 255)/256, 256, 0, stream>>>(dw3, wt_d3, 32, 32);
    transpose_w4<<<(16*8*3 + 255)/256, 256, 0, stream>>>(dw4, wt_d4, 32, 3);

    // ---- encoder ----
    conv1_k<4><<<32768, 256, 0, stream>>>(x, wt_c1, cb1, bufA);
    conv_nhwc<32, 32, 32, 32, 4, true><<<8192, 256, 0, stream>>>(bufA, wt_c2, cb2, bufB);
    conv_nhwc<32, 64, 16, 16, 4, true><<<4096, 256, 0, stream>>>(bufB, wt_c3, cb3, bufC);
    conv_nhwc<64, 64, 8, 8, 4, true><<<1024, 256, 0, stream>>>(bufC, wt_c4, cb4, bufD);
    fc_kernel<1024, 192, false, false, true, false><<<256, 256, 0, stream>>>(bufD, fc_w, fc_b, bufH);
    enc_switch_all<<<1024, 128, 0, stream>>>(bufH, ein_w, ein_b, eout_w, eout_b,
                                             esw_w, esw_b, gnoise, yidx, gate);
    zfcl_kernel<<<1024, 192, 0, stream>>>(bufH, mean_w, mean_b, lv_w, lv_b,
                                          znoise, fcl_w, fcl_b,
                                          z_out, zm_out, zl_out, bufD2);
    dec_switch_all<<<1024, 128, 0, stream>>>(bufD2, din_w, din_b, dout_w, dout_b, yidx, gate);
    fc_kernel<192, 1024, true, true, false, true><<<256, 256, 0, stream>>>(bufD2, dfc_w, dfc_b, bufD);

    // ---- decoder deconvs ----
    deconv_nhwc<64, 64, 4, 4, 4, true><<<4096, 256, 0, stream>>>(bufD, wt_d1, db1, bufC);
    deconv_nhwc<64, 32, 8, 8, 4, true><<<8192, 256, 0, stream>>>(bufC, wt_d2, db2, bufB);
    deconv_nhwc<32, 32, 16, 16, 4, true><<<32768, 256, 0, stream>>>(bufB, wt_d3, db3, bufA);
    deconv_last<<<16384, 256, 0, stream>>>(bufA, wt_d4, db4, recon);
}

// Round 3
// 697.690 us; speedup vs baseline: 20.6688x; 7.8269x over previous
//
#include <hip/hip_runtime.h>
#include <hip/hip_bf16.h>
#include <math.h>

// ---------------------------------------------------------------------------
// FCSwitchedBetaVAE forward. Conv/deconv stack as implicit-GEMM on
// mfma_f32_16x16x32_bf16 (NHWC bf16 activations, f32 accum). FC/switch chain
// stays f32. B=1024, C=3, L=10, D=192, K=10, S=10.
// ---------------------------------------------------------------------------

#define BATCH 1024

using short8 = __attribute__((ext_vector_type(8))) short;
using f32x4  = __attribute__((ext_vector_type(4))) float;

__device__ __forceinline__ ushort f2bf(float f) {
    uint u = __float_as_uint(f);
    uint r = (u + 0x7fffu + ((u >> 16) & 1u)) >> 16;   // RNE
    return (ushort)r;
}
__device__ __forceinline__ float bf2f(ushort u) {
    return __uint_as_float(((uint)u) << 16);
}
constexpr int ilog2(int v) { return v <= 1 ? 0 : 1 + ilog2(v >> 1); }

// ------------------------- input pack: NCHW f32 -> NHWC4 bf16 --------------
__global__ __launch_bounds__(256)
void x_to_nhwc4(const float* __restrict__ x, ushort* __restrict__ xp) {
    int idx = blockIdx.x * 256 + threadIdx.x;       // B*4096
    int pix = idx & 4095; int n = idx >> 12;
    const float* xb = x + (size_t)n * 3 * 4096 + pix;
    ushort4 v;
    v.x = f2bf(xb[0]); v.y = f2bf(xb[4096]); v.z = f2bf(xb[8192]); v.w = 0;
    *(ushort4*)(xp + (size_t)idx * 4) = v;
}

// ------------------------- weight fragment prep ----------------------------
// conv frag [tap16][chunk][ntile][lane64][8]
__global__ void prep_conv_wfrag(const float* __restrict__ w, ushort* __restrict__ frag,
                                int CIN, int COUT) {
    int NCH = CIN / 32, NT = COUT / 16;
    int total = 16 * NCH * NT * 512;
    int idx = blockIdx.x * 256 + threadIdx.x;
    if (idx >= total) return;
    int j = idx & 7; int lane = (idx >> 3) & 63; int rest = idx >> 9;
    int ntile = rest % NT; rest /= NT;
    int ch = rest % NCH; int tap = rest / NCH;
    int o = ntile * 16 + (lane & 15);
    int i = ch * 32 + (lane >> 4) * 8 + j;
    frag[idx] = f2bf(w[((size_t)(o * CIN + i)) * 16 + tap]);
}
// deconv frag [cls4][tapidx4][chunk][ntile][lane64][8]
__global__ void prep_deconv_wfrag(const float* __restrict__ w, ushort* __restrict__ frag,
                                  int CIN, int COUT) {
    int NCH = CIN / 32, NT = COUT / 16;
    int total = 16 * NCH * NT * 512;
    int idx = blockIdx.x * 256 + threadIdx.x;
    if (idx >= total) return;
    int j = idx & 7; int lane = (idx >> 3) & 63; int rest = idx >> 9;
    int ntile = rest % NT; rest /= NT;
    int ch = rest % NCH; rest /= NCH;
    int tapidx = rest % 4; int cls = rest / 4;
    int py = cls >> 1, px = cls & 1, a = tapidx >> 1, b = tapidx & 1;
    int tap = (py + 2 * a) * 4 + (px + 2 * b);
    int o = ntile * 16 + (lane & 15);
    int i = ch * 32 + (lane >> 4) * 8 + j;
    frag[idx] = f2bf(w[((size_t)(o * CIN + i)) * 16 + tap]);
}
// conv1 frag [kstep2][ntile2][lane64][8]; K = tap*4 + c (c=3 is zero pad)
__global__ void prep_c1_wfrag(const float* __restrict__ w, ushort* __restrict__ frag) {
    int idx = blockIdx.x * 256 + threadIdx.x;
    if (idx >= 2 * 2 * 512) return;
    int j = idx & 7; int lane = (idx >> 3) & 63;
    int ntile = (idx >> 9) & 1; int s = idx >> 10;
    int o = ntile * 16 + (lane & 15);
    int kg = lane >> 4;
    int tap = s * 8 + kg * 2 + (j >> 2);
    int c = j & 3;
    frag[idx] = (c < 3) ? f2bf(w[((size_t)(o * 3 + c)) * 16 + tap]) : (ushort)0;
}
// deconv_last frag [cls4][tapidx4][lane64][8]; COUT 3 -> padded 16
__global__ void prep_dlast_wfrag(const float* __restrict__ w, ushort* __restrict__ frag) {
    int idx = blockIdx.x * 256 + threadIdx.x;
    if (idx >= 4 * 4 * 512) return;
    int j = idx & 7; int lane = (idx >> 3) & 63; int rest = idx >> 9;
    int tapidx = rest & 3; int cls = rest >> 2;
    int py = cls >> 1, px = cls & 1, a = tapidx >> 1, b = tapidx & 1;
    int tap = (py + 2 * a) * 4 + (px + 2 * b);
    int o = lane & 15;
    int i = (lane >> 4) * 8 + j;
    frag[idx] = (o < 3) ? f2bf(w[((size_t)(o * 32 + i)) * 16 + tap]) : (ushort)0;
}

// ------------------------- conv1 MFMA: xpad -> [B,32,32,32] ----------------
__global__ __launch_bounds__(256)
void conv1_mfma(const ushort* __restrict__ xp, const ushort* __restrict__ wfrag,
                const float* __restrict__ bias, ushort* __restrict__ out) {
    const int lane = threadIdx.x & 63;
    const int gw = (blockIdx.x << 2) + (threadIdx.x >> 6);
    const int ntile = gw & 1;
    const int mtile = gw >> 1;
    const int m = lane & 15, kg = lane >> 4;
    const int p = (mtile << 4) + m;
    const int ox = p & 31, oy = (p >> 5) & 31, n = p >> 10;
    const ushort* ib = xp + (((size_t)n) << 12) * 4;
    const int iy0 = 2 * oy - 1, ix0 = 2 * ox - 1;
    f32x4 acc = {0.f, 0.f, 0.f, 0.f};
    #pragma unroll
    for (int s = 0; s < 2; ++s) {
        short8 a;
        #pragma unroll
        for (int t = 0; t < 2; ++t) {
            const int tap = s * 8 + kg * 2 + t;
            const int ky = tap >> 2, kx = tap & 3;
            const int iy = iy0 + ky, ix = ix0 + kx;
            ushort4 half = {0, 0, 0, 0};
            if ((unsigned)iy < 64u && (unsigned)ix < 64u)
                half = *(const ushort4*)(ib + (size_t)((iy << 6) + ix) * 4);
            a[4 * t + 0] = (short)half.x; a[4 * t + 1] = (short)half.y;
            a[4 * t + 2] = (short)half.z; a[4 * t + 3] = (short)half.w;
        }
        const short8 b = *(const short8*)(wfrag + ((s * 2 + ntile) << 9) + lane * 8);
        acc = __builtin_amdgcn_mfma_f32_16x16x32_bf16(a, b, acc, 0, 0, 0);
    }
    const int och = (ntile << 4) + m;
    const float bv = bias[och];
    ushort* ob = out + (size_t)((mtile << 4) + (kg << 2)) * 32 + och;
    #pragma unroll
    for (int r = 0; r < 4; ++r) ob[r * 32] = f2bf(fmaxf(acc[r] + bv, 0.f));
}

// ------------------------- generic conv MFMA (s2,p1,k4) --------------------
template<int CIN, int COUT, int HIN, int WIN, bool RELU>
__global__ __launch_bounds__(256)
void conv_mfma(const ushort* __restrict__ in, const ushort* __restrict__ wfrag,
               const float* __restrict__ bias, ushort* __restrict__ out) {
    constexpr int HOUT = HIN / 2, WOUT = WIN / 2, NCH = CIN / 32, NT = COUT / 16;
    constexpr int LW = ilog2(WOUT), LH = ilog2(HOUT);
    const int lane = threadIdx.x & 63;
    const int gw = (blockIdx.x << 2) + (threadIdx.x >> 6);
    const int ntile = gw % NT;
    const int mtile = gw / NT;
    const int m = lane & 15, kg = lane >> 4;
    const int p = (mtile << 4) + m;
    const int ox = p & (WOUT - 1), oy = (p >> LW) & (HOUT - 1), n = p >> (LW + LH);
    const ushort* ibase = in + (size_t)n * (HIN * WIN * CIN);
    const int iy0 = 2 * oy - 1, ix0 = 2 * ox - 1;
    f32x4 acc = {0.f, 0.f, 0.f, 0.f};
    const ushort* wl = wfrag + ((size_t)ntile << 9) + lane * 8;
    #pragma unroll
    for (int ky = 0; ky < 4; ++ky) {
        const int iy = iy0 + ky;
        const bool vy = (unsigned)iy < (unsigned)HIN;
        #pragma unroll
        for (int kx = 0; kx < 4; ++kx) {
            const int ix = ix0 + kx;
            const bool v = vy && ((unsigned)ix < (unsigned)WIN);
            const int tap = ky * 4 + kx;
            #pragma unroll
            for (int ch = 0; ch < NCH; ++ch) {
                short8 a = {0, 0, 0, 0, 0, 0, 0, 0};
                if (v) a = *(const short8*)(ibase + (size_t)(iy * WIN + ix) * CIN + ch * 32 + kg * 8);
                const short8 b = *(const short8*)(wl + ((size_t)((tap * NCH + ch) * NT) << 9));
                acc = __builtin_amdgcn_mfma_f32_16x16x32_bf16(a, b, acc, 0, 0, 0);
            }
        }
    }
    const int och = (ntile << 4) + m;
    const float bv = bias[och];
    ushort* ob = out + (size_t)((mtile << 4) + (kg << 2)) * COUT + och;
    #pragma unroll
    for (int r = 0; r < 4; ++r) {
        float vv = acc[r] + bv;
        if (RELU) vv = fmaxf(vv, 0.f);
        ob[r * COUT] = f2bf(vv);
    }
}

// --------------- generic deconv MFMA (k4,s2,'SAME'), parity classes --------
template<int CIN, int COUT, int HIN, int WIN, bool RELU>
__global__ __launch_bounds__(256)
void deconv_mfma(const ushort* __restrict__ in, const ushort* __restrict__ wfrag,
                 const float* __restrict__ bias, ushort* __restrict__ out) {
    constexpr int HOUT = 2 * HIN, WOUT = 2 * WIN, NCH = CIN / 32, NT = COUT / 16;
    constexpr int LW = ilog2(WIN), LH = ilog2(HIN);
    constexpr int MT = (BATCH * HIN * WIN) >> 4;
    const int lane = threadIdx.x & 63;
    int gw = (blockIdx.x << 2) + (threadIdx.x >> 6);
    const int ntile = gw % NT; gw /= NT;
    const int mtile = gw % MT; const int cls = gw / MT;
    const int py = cls >> 1, px = cls & 1;
    const int m = lane & 15, kg = lane >> 4;
    const int q = (mtile << 4) + m;
    const int oxh = q & (WIN - 1), oyh = (q >> LW) & (HIN - 1), n = q >> (LW + LH);
    const ushort* ibase = in + (size_t)n * (HIN * WIN * CIN);
    f32x4 acc = {0.f, 0.f, 0.f, 0.f};
    const ushort* wl = wfrag + ((size_t)(cls * 4 * NCH * NT + ntile) << 9) + lane * 8;
    #pragma unroll
    for (int a2 = 0; a2 < 2; ++a2) {
        const int iy = oyh + py - 1 + a2;
        const bool vy = (unsigned)iy < (unsigned)HIN;
        #pragma unroll
        for (int b2 = 0; b2 < 2; ++b2) {
            const int ix = oxh + px - 1 + b2;
            const bool v = vy && ((unsigned)ix < (unsigned)WIN);
            const int tapidx = a2 * 2 + b2;
            #pragma unroll
            for (int ch = 0; ch < NCH; ++ch) {
                short8 a = {0, 0, 0, 0, 0, 0, 0, 0};
                if (v) a = *(const short8*)(ibase + (size_t)(iy * WIN + ix) * CIN + ch * 32 + kg * 8);
                const short8 b = *(const short8*)(wl + ((size_t)((tapidx * NCH + ch) * NT) << 9));
                acc = __builtin_amdgcn_mfma_f32_16x16x32_bf16(a, b, acc, 0, 0, 0);
            }
        }
    }
    const int och = (ntile << 4) + m;
    const float bv = bias[och];
    #pragma unroll
    for (int r = 0; r < 4; ++r) {
        const int qq = (mtile << 4) + (kg << 2) + r;
        const int oxh2 = qq & (WIN - 1), oyh2 = (qq >> LW) & (HIN - 1), n2 = qq >> (LW + LH);
        const int oy = 2 * oyh2 + py, ox = 2 * oxh2 + px;
        float vv = acc[r] + bv;
        if (RELU) vv = fmaxf(vv, 0.f);
        out[(size_t)((n2 * HOUT + oy) * WOUT + ox) * COUT + och] = f2bf(vv);
    }
}

// --------------- last deconv MFMA: [B,32,32,32]bf16 -> NCHW f32 [B,3,64,64] -
__global__ __launch_bounds__(256)
void deconv_last_mfma(const ushort* __restrict__ in, const ushort* __restrict__ wfrag,
                      const float* __restrict__ bias, float* __restrict__ out) {
    const int lane = threadIdx.x & 63;
    const int gw = (blockIdx.x << 2) + (threadIdx.x >> 6);
    const int mtile = gw & 65535;
    const int cls = gw >> 16;
    const int py = cls >> 1, px = cls & 1;
    const int m = lane & 15, kg = lane >> 4;
    const int q = (mtile << 4) + m;
    const int oxh = q & 31, oyh = (q >> 5) & 31, n = q >> 10;
    const ushort* ib = in + (((size_t)n) << 10) * 32;
    f32x4 acc = {0.f, 0.f, 0.f, 0.f};
    const ushort* wl = wfrag + ((size_t)cls << 11) + lane * 8;
    #pragma unroll
    for (int a2 = 0; a2 < 2; ++a2) {
        const int iy = oyh + py - 1 + a2;
        const bool vy = (unsigned)iy < 32u;
        #pragma unroll
        for (int b2 = 0; b2 < 2; ++b2) {
            const int ix = oxh + px - 1 + b2;
            const bool v = vy && ((unsigned)ix < 32u);
            short8 a = {0, 0, 0, 0, 0, 0, 0, 0};
            if (v) a = *(const short8*)(ib + (size_t)((iy << 5) + ix) * 32 + kg * 8);
            const short8 b = *(const short8*)(wl + ((a2 * 2 + b2) << 9));
            acc = __builtin_amdgcn_mfma_f32_16x16x32_bf16(a, b, acc, 0, 0, 0);
        }
    }
    const int och = m;
    if (och < 3) {
        const float bv = bias[och];
        #pragma unroll
        for (int r = 0; r < 4; ++r) {
            const int qq = (mtile << 4) + (kg << 2) + r;
            const int oxh2 = qq & 31, oyh2 = (qq >> 5) & 31, n2 = qq >> 10;
            const int oy = 2 * oyh2 + py, ox = 2 * oxh2 + px;
            out[(size_t)n2 * 12288 + och * 4096 + oy * 64 + ox] = acc[r] + bv;
        }
    }
}

// ---------------- dense FC with optional remaps / bf16 IO ------------------
template<int DIN, int DOUT, bool RELU_IN, bool RELU_OUT, bool REMAP_IN, bool REMAP_OUT,
         bool IN_BF16, bool OUT_BF16>
__global__ __launch_bounds__(256)
void fc_kernel(const void* __restrict__ inv, const float* __restrict__ w,
               const float* __restrict__ bias, void* __restrict__ outv) {
    constexpr int TB = 4;
    __shared__ float a[TB][DIN];
    const int b0 = blockIdx.x * TB;
    for (int idx = threadIdx.x; idx < TB * DIN; idx += 256) {
        int r = idx / DIN, c = idx % DIN;
        float v = IN_BF16 ? bf2f(((const ushort*)inv)[(size_t)(b0 + r) * DIN + c])
                          : ((const float*)inv)[(size_t)(b0 + r) * DIN + c];
        if (RELU_IN) v = fmaxf(v, 0.f);
        int d = REMAP_IN ? ((c & 63) * 16 + (c >> 6)) : c;   // NHWC(p*64+ch) -> ch*16+p
        a[r][d] = v;
    }
    __syncthreads();
    for (int j = threadIdx.x; j < DOUT; j += 256) {
        float acc[TB];
        #pragma unroll
        for (int r = 0; r < TB; ++r) acc[r] = bias[j];
        for (int d = 0; d < DIN; ++d) {
            const float wv = w[(size_t)d * DOUT + j];
            #pragma unroll
            for (int r = 0; r < TB; ++r) acc[r] = fmaf(a[r][d], wv, acc[r]);
        }
        const int jo = REMAP_OUT ? (((j & 15) << 6) + (j >> 4)) : j;  // ch*16+p -> p*64+ch
        #pragma unroll
        for (int r = 0; r < TB; ++r) {
            float v = RELU_OUT ? fmaxf(acc[r], 0.f) : acc[r];
            if (OUT_BF16) ((ushort*)outv)[(size_t)(b0 + r) * DOUT + jo] = f2bf(v);
            else ((float*)outv)[(size_t)(b0 + r) * DOUT + jo] = v;
        }
    }
}

// ---------------- fused encoder switch chain (all 10 latents) --------------
__global__ __launch_bounds__(128)
void enc_switch_all(float* __restrict__ h,
                    const float* __restrict__ win_all, const float* __restrict__ bin_all,
                    const float* __restrict__ wout_all, const float* __restrict__ bout_all,
                    const float* __restrict__ wsw_all, const float* __restrict__ bsw_all,
                    const float* __restrict__ gn_all,
                    int* __restrict__ yidx, float* __restrict__ gateArr) {
    const int b = blockIdx.x, t = threadIdx.x;
    __shared__ float hold[192], r[192], hid[100], lg[10];
    __shared__ int s_yi; __shared__ float s_gate;
    for (int d = t; d < 192; d += 128) hold[d] = h[(size_t)b * 192 + d];
    for (int i = 0; i < 10; ++i) {
        const float* win = win_all + (size_t)i * 19200;
        const float* bin = bin_all + (size_t)i * 100;
        const float* wout = wout_all + (size_t)i * 19200;
        const float* bout = bout_all + (size_t)i * 1920;
        const float* wsw = wsw_all + (size_t)i * 100;
        const float* bsw = bsw_all + (size_t)i * 10;
        const float* gn = gn_all + (size_t)i * 10240;
        __syncthreads();
        for (int d = t; d < 192; d += 128) r[d] = fmaxf(hold[d], 0.f);
        __syncthreads();
        if (t < 100) {
            const int k = t / 10, s = t % 10;
            const float* wp = win + k * 1920 + s;
            float acc = bin[t];
            #pragma unroll 4
            for (int d = 0; d < 192; ++d) acc = fmaf(r[d], wp[d * 10], acc);
            hid[t] = acc;
        }
        __syncthreads();
        if (t < 10) {
            float acc = bsw[t];
            #pragma unroll
            for (int s = 0; s < 10; ++s) acc = fmaf(hid[t * 10 + s], wsw[t * 10 + s], acc);
            lg[t] = acc - logf(gn[(size_t)b * 10 + t] + 1e-20f);
        }
        __syncthreads();
        if (t == 0) {
            int bi = 0; float best = lg[0];
            #pragma unroll
            for (int k = 1; k < 10; ++k) if (lg[k] > best) { best = lg[k]; bi = k; }
            float sum = 0.f;
            #pragma unroll
            for (int k = 0; k < 10; ++k) sum += expf(lg[k] - best);
            const float ysoft = 1.0f / sum;
            s_yi = bi; s_gate = (1.0f - ysoft) + ysoft;
            yidx[i * 1024 + b] = bi; gateArr[i * 1024 + b] = s_gate;
        }
        __syncthreads();
        const int yi = s_yi; const float gate = s_gate;
        for (int d = t; d < 192; d += 128) {
            float acc = bout[yi * 192 + d];
            const float* wp = wout + yi * 1920 + d;
            #pragma unroll
            for (int s = 0; s < 10; ++s) acc = fmaf(hid[yi * 10 + s], wp[s * 192], acc);
            hold[d] += acc * gate;
        }
    }
    __syncthreads();
    for (int d = t; d < 192; d += 128) h[(size_t)b * 192 + d] = hold[d];
}

// ---------------- fused decoder switch chain -------------------------------
__global__ __launch_bounds__(128)
void dec_switch_all(float* __restrict__ h,
                    const float* __restrict__ win_all, const float* __restrict__ bin_all,
                    const float* __restrict__ wout_all, const float* __restrict__ bout_all,
                    const int* __restrict__ yidx, const float* __restrict__ gateArr) {
    const int b = blockIdx.x, t = threadIdx.x;
    __shared__ float hold[192], r[192], part[120], hid[10];
    for (int d = t; d < 192; d += 128) hold[d] = h[(size_t)b * 192 + d];
    for (int i = 0; i < 10; ++i) {
        const int yi = yidx[i * 1024 + b];
        const float gate = gateArr[i * 1024 + b];
        const float* win = win_all + (size_t)i * 19200 + yi * 1920;
        const float* bin = bin_all + (size_t)i * 100 + yi * 10;
        const float* wout = wout_all + (size_t)i * 19200 + yi * 1920;
        const float* bout = bout_all + (size_t)i * 1920 + yi * 192;
        __syncthreads();
        for (int d = t; d < 192; d += 128) r[d] = fmaxf(hold[d], 0.f);
        __syncthreads();
        if (t < 120) {
            const int s = t % 10, g = t / 10;
            float acc = 0.f;
            #pragma unroll
            for (int d = g * 16; d < g * 16 + 16; ++d) acc = fmaf(r[d], win[d * 10 + s], acc);
            part[t] = acc;
        }
        __syncthreads();
        if (t < 10) {
            float acc = bin[t];
            #pragma unroll
            for (int g = 0; g < 12; ++g) acc += part[g * 10 + t];
            hid[t] = acc;
        }
        __syncthreads();
        for (int d = t; d < 192; d += 128) {
            float acc = bout[d];
            #pragma unroll
            for (int s = 0; s < 10; ++s) acc = fmaf(hid[s], wout[s * 192 + d], acc);
            hold[d] += acc * gate;
        }
    }
    __syncthreads();
    for (int d = t; d < 192; d += 128) h[(size_t)b * 192 + d] = hold[d];
}

// ------- z stats + reparameterize + decoder input FC -----------------------
__global__ __launch_bounds__(192)
void zfcl_kernel(const float* __restrict__ h,
                 const float* __restrict__ mw, const float* __restrict__ mb,
                 const float* __restrict__ lw, const float* __restrict__ lb,
                 const float* __restrict__ zn,
                 const float* __restrict__ fw, const float* __restrict__ fb,
                 float* __restrict__ out_z, float* __restrict__ out_mean,
                 float* __restrict__ out_lv, float* __restrict__ dbuf) {
    const int b = blockIdx.x, t = threadIdx.x;
    __shared__ float r[192], pm[160], pl[160], zsh[10];
    for (int d = t; d < 192; d += 192) r[d] = fmaxf(h[(size_t)b * 192 + d], 0.f);
    __syncthreads();
    if (t < 160) {
        const int l = t % 10, g = t / 10;
        float am = 0.f, al = 0.f;
        #pragma unroll
        for (int d = g * 12; d < g * 12 + 12; ++d) {
            am = fmaf(r[d], mw[d * 10 + l], am);
            al = fmaf(r[d], lw[d * 10 + l], al);
        }
        pm[t] = am; pl[t] = al;
    }
    __syncthreads();
    if (t < 10) {
        float zm = mb[t], zl = lb[t];
        #pragma unroll
        for (int g = 0; g < 16; ++g) { zm += pm[g * 10 + t]; zl += pl[g * 10 + t]; }
        const float z = zn[(size_t)b * 10 + t] * expf(zl * 0.5f) + zm;
        out_mean[(size_t)b * 10 + t] = zm;
        out_lv[(size_t)b * 10 + t] = zl;
        out_z[(size_t)b * 10 + t] = z;
        zsh[t] = z;
    }
    __syncthreads();
    for (int d = t; d < 192; d += 192) {
        float acc = fb[d];
        #pragma unroll
        for (int l = 0; l < 10; ++l) acc = fmaf(zsh[l], fw[l * 192 + d], acc);
        dbuf[(size_t)b * 192 + d] = acc;
    }
}

// ---------------------------------------------------------------------------
extern "C" void kernel_launch(void* const* d_in, const int* in_sizes, int n_in,
                              void* d_out, int out_size, void* d_ws, size_t ws_size,
                              hipStream_t stream) {
    const float* x      = (const float*)d_in[0];
    const float* gnoise = (const float*)d_in[1];
    const float* znoise = (const float*)d_in[2];
    const float* cw1 = (const float*)d_in[3];  const float* cb1 = (const float*)d_in[4];
    const float* cw2 = (const float*)d_in[5];  const float* cb2 = (const float*)d_in[6];
    const float* cw3 = (const float*)d_in[7];  const float* cb3 = (const float*)d_in[8];
    const float* cw4 = (const float*)d_in[9];  const float* cb4 = (const float*)d_in[10];
    const float* fc_w = (const float*)d_in[11]; const float* fc_b = (const float*)d_in[12];
    const float* ein_w = (const float*)d_in[13]; const float* ein_b = (const float*)d_in[14];
    const float* eout_w = (const float*)d_in[15]; const float* eout_b = (const float*)d_in[16];
    const float* esw_w = (const float*)d_in[17]; const float* esw_b = (const float*)d_in[18];
    const float* mean_w = (const float*)d_in[19]; const float* mean_b = (const float*)d_in[20];
    const float* lv_w = (const float*)d_in[21]; const float* lv_b = (const float*)d_in[22];
    const float* fcl_w = (const float*)d_in[23]; const float* fcl_b = (const float*)d_in[24];
    const float* din_w = (const float*)d_in[25]; const float* din_b = (const float*)d_in[26];
    const float* dout_w = (const float*)d_in[27]; const float* dout_b = (const float*)d_in[28];
    const float* dfc_w = (const float*)d_in[29]; const float* dfc_b = (const float*)d_in[30];
    const float* dw1 = (const float*)d_in[31]; const float* db1 = (const float*)d_in[32];
    const float* dw2 = (const float*)d_in[33]; const float* db2 = (const float*)d_in[34];
    const float* dw3 = (const float*)d_in[35]; const float* db3 = (const float*)d_in[36];
    const float* dw4 = (const float*)d_in[37]; const float* db4 = (const float*)d_in[38];

    float* out = (float*)d_out;
    float* recon  = out;
    float* z_out  = out + 12582912;
    float* zm_out = z_out + 10240;
    float* zl_out = zm_out + 10240;

    char* ws = (char*)d_ws;
    ushort* xpad  = (ushort*)(ws);                  // [B,64,64,4]  33.5 MB
    ushort* bufA  = (ushort*)(ws + 33554432);       // [B,32,32,32] 67 MB
    ushort* bufB  = (ushort*)(ws + 100663296);      // [B,16,16,32] 16.8 MB
    ushort* bufC  = (ushort*)(ws + 117440512);      // [B,8,8,64]   8.4 MB
    ushort* bufD  = (ushort*)(ws + 125829120);      // [B,4,4,64]   2.1 MB
    float*  bufH  = (float*) (ws + 127926272);      // [B,192]
    float*  bufD2 = (float*) (ws + 128712704);      // [B,192]
    int*    yidx  = (int*)   (ws + 129499136);
    float*  gate  = (float*) (ws + 129540096);
    char*   fb    = ws + 129581056;
    ushort* c1g = (ushort*)(fb);                    //   4096 B
    ushort* c2g = (ushort*)(fb + 4096);             //  32768 B
    ushort* c3g = (ushort*)(fb + 36864);            //  65536 B
    ushort* c4g = (ushort*)(fb + 102400);           // 131072 B
    ushort* d1g = (ushort*)(fb + 233472);           // 131072 B
    ushort* d2g = (ushort*)(fb + 364544);           //  65536 B
    ushort* d3g = (ushort*)(fb + 430080);           //  32768 B
    ushort* d4g = (ushort*)(fb + 462848);           //  16384 B

    // ---- packs ----
    x_to_nhwc4<<<16384, 256, 0, stream>>>(x, xpad);
    prep_c1_wfrag<<<8, 256, 0, stream>>>(cw1, c1g);
    prep_conv_wfrag<<<64, 256, 0, stream>>>(cw2, c2g, 32, 32);
    prep_conv_wfrag<<<128, 256, 0, stream>>>(cw3, c3g, 32, 64);
    prep_conv_wfrag<<<256, 256, 0, stream>>>(cw4, c4g, 64, 64);
    prep_deconv_wfrag<<<256, 256, 0, stream>>>(dw1, d1g, 64, 64);
    prep_deconv_wfrag<<<128, 256, 0, stream>>>(dw2, d2g, 64, 32);
    prep_deconv_wfrag<<<64, 256, 0, stream>>>(dw3, d3g, 32, 32);
    prep_dlast_wfrag<<<32, 256, 0, stream>>>(dw4, d4g);

    // ---- encoder ----
    conv1_mfma<<<32768, 256, 0, stream>>>(xpad, c1g, cb1, bufA);
    conv_mfma<32, 32, 32, 32, true><<<8192, 256, 0, stream>>>(bufA, c2g, cb2, bufB);
    conv_mfma<32, 64, 16, 16, true><<<4096, 256, 0, stream>>>(bufB, c3g, cb3, bufC);
    conv_mfma<64, 64, 8, 8, true><<<1024, 256, 0, stream>>>(bufC, c4g, cb4, bufD);
    fc_kernel<1024, 192, false, false, true, false, true, false>
        <<<256, 256, 0, stream>>>(bufD, fc_w, fc_b, bufH);
    enc_switch_all<<<1024, 128, 0, stream>>>(bufH, ein_w, ein_b, eout_w, eout_b,
                                             esw_w, esw_b, gnoise, yidx, gate);
    zfcl_kernel<<<1024, 192, 0, stream>>>(bufH, mean_w, mean_b, lv_w, lv_b,
                                          znoise, fcl_w, fcl_b,
                                          z_out, zm_out, zl_out, bufD2);
    dec_switch_all<<<1024, 128, 0, stream>>>(bufD2, din_w, din_b, dout_w, dout_b, yidx, gate);
    fc_kernel<192, 1024, true, true, false, true, false, true>
        <<<256, 256, 0, stream>>>(bufD2, dfc_w, dfc_b, bufD);

    // ---- decoder deconvs ----
    deconv_mfma<64, 64, 4, 4, true><<<4096, 256, 0, stream>>>(bufD, d1g, db1, bufC);
    deconv_mfma<64, 32, 8, 8, true><<<8192, 256, 0, stream>>>(bufC, d2g, db2, bufB);
    deconv_mfma<32, 32, 16, 16, true><<<32768, 256, 0, stream>>>(bufB, d3g, db3, bufA);
    deconv_last_mfma<<<65536, 256, 0, stream>>>(bufA, d4g, db4, recon);
}

// Round 4
// 566.117 us; speedup vs baseline: 25.4725x; 1.2324x over previous
//
#include <hip/hip_runtime.h>
#include <hip/hip_bf16.h>
#include <math.h>

// ---------------------------------------------------------------------------
// FCSwitchedBetaVAE forward. Conv/deconv stack as implicit-GEMM on
// mfma_f32_16x16x32_bf16 (NHWC bf16 activations, f32 accum). Switch chains:
// one block per batch row, coalesced weight access (transposed enc win),
// 256 threads with split-reduction ILP. B=1024, C=3, L=10, D=192, K=10, S=10.
// ---------------------------------------------------------------------------

#define BATCH 1024

using short8 = __attribute__((ext_vector_type(8))) short;
using f32x4  = __attribute__((ext_vector_type(4))) float;

__device__ __forceinline__ ushort f2bf(float f) {
    uint u = __float_as_uint(f);
    uint r = (u + 0x7fffu + ((u >> 16) & 1u)) >> 16;   // RNE
    return (ushort)r;
}
__device__ __forceinline__ float bf2f(ushort u) {
    return __uint_as_float(((uint)u) << 16);
}
constexpr int ilog2(int v) { return v <= 1 ? 0 : 1 + ilog2(v >> 1); }

// ------------------------- input pack: NCHW f32 -> NHWC4 bf16 --------------
__global__ __launch_bounds__(256)
void x_to_nhwc4(const float* __restrict__ x, ushort* __restrict__ xp) {
    int idx = blockIdx.x * 256 + threadIdx.x;       // B*4096
    int pix = idx & 4095; int n = idx >> 12;
    const float* xb = x + (size_t)n * 3 * 4096 + pix;
    ushort4 v;
    v.x = f2bf(xb[0]); v.y = f2bf(xb[4096]); v.z = f2bf(xb[8192]); v.w = 0;
    *(ushort4*)(xp + (size_t)idx * 4) = v;
}

// ------------------------- weight fragment prep ----------------------------
// conv frag [tap16][chunk][ntile][lane64][8]
__global__ void prep_conv_wfrag(const float* __restrict__ w, ushort* __restrict__ frag,
                                int CIN, int COUT) {
    int NCH = CIN / 32, NT = COUT / 16;
    int total = 16 * NCH * NT * 512;
    int idx = blockIdx.x * 256 + threadIdx.x;
    if (idx >= total) return;
    int j = idx & 7; int lane = (idx >> 3) & 63; int rest = idx >> 9;
    int ntile = rest % NT; rest /= NT;
    int ch = rest % NCH; int tap = rest / NCH;
    int o = ntile * 16 + (lane & 15);
    int i = ch * 32 + (lane >> 4) * 8 + j;
    frag[idx] = f2bf(w[((size_t)(o * CIN + i)) * 16 + tap]);
}
// deconv frag [cls4][tapidx4][chunk][ntile][lane64][8]
__global__ void prep_deconv_wfrag(const float* __restrict__ w, ushort* __restrict__ frag,
                                  int CIN, int COUT) {
    int NCH = CIN / 32, NT = COUT / 16;
    int total = 16 * NCH * NT * 512;
    int idx = blockIdx.x * 256 + threadIdx.x;
    if (idx >= total) return;
    int j = idx & 7; int lane = (idx >> 3) & 63; int rest = idx >> 9;
    int ntile = rest % NT; rest /= NT;
    int ch = rest % NCH; rest /= NCH;
    int tapidx = rest % 4; int cls = rest / 4;
    int py = cls >> 1, px = cls & 1, a = tapidx >> 1, b = tapidx & 1;
    int tap = (py + 2 * a) * 4 + (px + 2 * b);
    int o = ntile * 16 + (lane & 15);
    int i = ch * 32 + (lane >> 4) * 8 + j;
    frag[idx] = f2bf(w[((size_t)(o * CIN + i)) * 16 + tap]);
}
// conv1 frag [kstep2][ntile2][lane64][8]; K = tap*4 + c (c=3 is zero pad)
__global__ void prep_c1_wfrag(const float* __restrict__ w, ushort* __restrict__ frag) {
    int idx = blockIdx.x * 256 + threadIdx.x;
    if (idx >= 2 * 2 * 512) return;
    int j = idx & 7; int lane = (idx >> 3) & 63;
    int ntile = (idx >> 9) & 1; int s = idx >> 10;
    int o = ntile * 16 + (lane & 15);
    int kg = lane >> 4;
    int tap = s * 8 + kg * 2 + (j >> 2);
    int c = j & 3;
    frag[idx] = (c < 3) ? f2bf(w[((size_t)(o * 3 + c)) * 16 + tap]) : (ushort)0;
}
// deconv_last frag [cls4][tapidx4][lane64][8]; COUT 3 -> padded 16
__global__ void prep_dlast_wfrag(const float* __restrict__ w, ushort* __restrict__ frag) {
    int idx = blockIdx.x * 256 + threadIdx.x;
    if (idx >= 4 * 4 * 512) return;
    int j = idx & 7; int lane = (idx >> 3) & 63; int rest = idx >> 9;
    int tapidx = rest & 3; int cls = rest >> 2;
    int py = cls >> 1, px = cls & 1, a = tapidx >> 1, b = tapidx & 1;
    int tap = (py + 2 * a) * 4 + (px + 2 * b);
    int o = lane & 15;
    int i = (lane >> 4) * 8 + j;
    frag[idx] = (o < 3) ? f2bf(w[((size_t)(o * 32 + i)) * 16 + tap]) : (ushort)0;
}
// encoder switch win transpose: ein_w [L,K,D,S] -> winT [L,D,K*S]
__global__ void prep_encwT(const float* __restrict__ w, float* __restrict__ wt) {
    int idx = blockIdx.x * 256 + threadIdx.x;
    if (idx >= 10 * 192 * 100) return;
    int ks = idx % 100;
    int d = (idx / 100) % 192;
    int l = idx / 19200;
    int k = ks / 10, s = ks % 10;
    wt[idx] = w[(size_t)l * 19200 + k * 1920 + d * 10 + s];
}

// ------------------------- conv1 MFMA: xpad -> [B,32,32,32] ----------------
__global__ __launch_bounds__(256)
void conv1_mfma(const ushort* __restrict__ xp, const ushort* __restrict__ wfrag,
                const float* __restrict__ bias, ushort* __restrict__ out) {
    const int lane = threadIdx.x & 63;
    const int gw = (blockIdx.x << 2) + (threadIdx.x >> 6);
    const int ntile = gw & 1;
    const int mtile = gw >> 1;
    const int m = lane & 15, kg = lane >> 4;
    const int p = (mtile << 4) + m;
    const int ox = p & 31, oy = (p >> 5) & 31, n = p >> 10;
    const ushort* ib = xp + (((size_t)n) << 12) * 4;
    const int iy0 = 2 * oy - 1, ix0 = 2 * ox - 1;
    f32x4 acc = {0.f, 0.f, 0.f, 0.f};
    #pragma unroll
    for (int s = 0; s < 2; ++s) {
        short8 a;
        #pragma unroll
        for (int t = 0; t < 2; ++t) {
            const int tap = s * 8 + kg * 2 + t;
            const int ky = tap >> 2, kx = tap & 3;
            const int iy = iy0 + ky, ix = ix0 + kx;
            ushort4 half = {0, 0, 0, 0};
            if ((unsigned)iy < 64u && (unsigned)ix < 64u)
                half = *(const ushort4*)(ib + (size_t)((iy << 6) + ix) * 4);
            a[4 * t + 0] = (short)half.x; a[4 * t + 1] = (short)half.y;
            a[4 * t + 2] = (short)half.z; a[4 * t + 3] = (short)half.w;
        }
        const short8 b = *(const short8*)(wfrag + ((s * 2 + ntile) << 9) + lane * 8);
        acc = __builtin_amdgcn_mfma_f32_16x16x32_bf16(a, b, acc, 0, 0, 0);
    }
    const int och = (ntile << 4) + m;
    const float bv = bias[och];
    ushort* ob = out + (size_t)((mtile << 4) + (kg << 2)) * 32 + och;
    #pragma unroll
    for (int r = 0; r < 4; ++r) ob[r * 32] = f2bf(fmaxf(acc[r] + bv, 0.f));
}

// ------------------------- generic conv MFMA (s2,p1,k4) --------------------
template<int CIN, int COUT, int HIN, int WIN, bool RELU>
__global__ __launch_bounds__(256)
void conv_mfma(const ushort* __restrict__ in, const ushort* __restrict__ wfrag,
               const float* __restrict__ bias, ushort* __restrict__ out) {
    constexpr int HOUT = HIN / 2, WOUT = WIN / 2, NCH = CIN / 32, NT = COUT / 16;
    constexpr int LW = ilog2(WOUT), LH = ilog2(HOUT);
    const int lane = threadIdx.x & 63;
    const int gw = (blockIdx.x << 2) + (threadIdx.x >> 6);
    const int ntile = gw % NT;
    const int mtile = gw / NT;
    const int m = lane & 15, kg = lane >> 4;
    const int p = (mtile << 4) + m;
    const int ox = p & (WOUT - 1), oy = (p >> LW) & (HOUT - 1), n = p >> (LW + LH);
    const ushort* ibase = in + (size_t)n * (HIN * WIN * CIN);
    const int iy0 = 2 * oy - 1, ix0 = 2 * ox - 1;
    f32x4 acc = {0.f, 0.f, 0.f, 0.f};
    const ushort* wl = wfrag + ((size_t)ntile << 9) + lane * 8;
    #pragma unroll
    for (int ky = 0; ky < 4; ++ky) {
        const int iy = iy0 + ky;
        const bool vy = (unsigned)iy < (unsigned)HIN;
        #pragma unroll
        for (int kx = 0; kx < 4; ++kx) {
            const int ix = ix0 + kx;
            const bool v = vy && ((unsigned)ix < (unsigned)WIN);
            const int tap = ky * 4 + kx;
            #pragma unroll
            for (int ch = 0; ch < NCH; ++ch) {
                short8 a = {0, 0, 0, 0, 0, 0, 0, 0};
                if (v) a = *(const short8*)(ibase + (size_t)(iy * WIN + ix) * CIN + ch * 32 + kg * 8);
                const short8 b = *(const short8*)(wl + ((size_t)((tap * NCH + ch) * NT) << 9));
                acc = __builtin_amdgcn_mfma_f32_16x16x32_bf16(a, b, acc, 0, 0, 0);
            }
        }
    }
    const int och = (ntile << 4) + m;
    const float bv = bias[och];
    ushort* ob = out + (size_t)((mtile << 4) + (kg << 2)) * COUT + och;
    #pragma unroll
    for (int r = 0; r < 4; ++r) {
        float vv = acc[r] + bv;
        if (RELU) vv = fmaxf(vv, 0.f);
        ob[r * COUT] = f2bf(vv);
    }
}

// --------------- generic deconv MFMA (k4,s2,'SAME'), parity classes --------
template<int CIN, int COUT, int HIN, int WIN, bool RELU>
__global__ __launch_bounds__(256)
void deconv_mfma(const ushort* __restrict__ in, const ushort* __restrict__ wfrag,
                 const float* __restrict__ bias, ushort* __restrict__ out) {
    constexpr int HOUT = 2 * HIN, WOUT = 2 * WIN, NCH = CIN / 32, NT = COUT / 16;
    constexpr int LW = ilog2(WIN), LH = ilog2(HIN);
    constexpr int MT = (BATCH * HIN * WIN) >> 4;
    const int lane = threadIdx.x & 63;
    int gw = (blockIdx.x << 2) + (threadIdx.x >> 6);
    const int ntile = gw % NT; gw /= NT;
    const int mtile = gw % MT; const int cls = gw / MT;
    const int py = cls >> 1, px = cls & 1;
    const int m = lane & 15, kg = lane >> 4;
    const int q = (mtile << 4) + m;
    const int oxh = q & (WIN - 1), oyh = (q >> LW) & (HIN - 1), n = q >> (LW + LH);
    const ushort* ibase = in + (size_t)n * (HIN * WIN * CIN);
    f32x4 acc = {0.f, 0.f, 0.f, 0.f};
    const ushort* wl = wfrag + ((size_t)(cls * 4 * NCH * NT + ntile) << 9) + lane * 8;
    #pragma unroll
    for (int a2 = 0; a2 < 2; ++a2) {
        const int iy = oyh + py - 1 + a2;
        const bool vy = (unsigned)iy < (unsigned)HIN;
        #pragma unroll
        for (int b2 = 0; b2 < 2; ++b2) {
            const int ix = oxh + px - 1 + b2;
            const bool v = vy && ((unsigned)ix < (unsigned)WIN);
            const int tapidx = a2 * 2 + b2;
            #pragma unroll
            for (int ch = 0; ch < NCH; ++ch) {
                short8 a = {0, 0, 0, 0, 0, 0, 0, 0};
                if (v) a = *(const short8*)(ibase + (size_t)(iy * WIN + ix) * CIN + ch * 32 + kg * 8);
                const short8 b = *(const short8*)(wl + ((size_t)((tapidx * NCH + ch) * NT) << 9));
                acc = __builtin_amdgcn_mfma_f32_16x16x32_bf16(a, b, acc, 0, 0, 0);
            }
        }
    }
    const int och = (ntile << 4) + m;
    const float bv = bias[och];
    #pragma unroll
    for (int r = 0; r < 4; ++r) {
        const int qq = (mtile << 4) + (kg << 2) + r;
        const int oxh2 = qq & (WIN - 1), oyh2 = (qq >> LW) & (HIN - 1), n2 = qq >> (LW + LH);
        const int oy = 2 * oyh2 + py, ox = 2 * oxh2 + px;
        float vv = acc[r] + bv;
        if (RELU) vv = fmaxf(vv, 0.f);
        out[(size_t)((n2 * HOUT + oy) * WOUT + ox) * COUT + och] = f2bf(vv);
    }
}

// --------------- last deconv MFMA: [B,32,32,32]bf16 -> NCHW f32 [B,3,64,64] -
__global__ __launch_bounds__(256)
void deconv_last_mfma(const ushort* __restrict__ in, const ushort* __restrict__ wfrag,
                      const float* __restrict__ bias, float* __restrict__ out) {
    const int lane = threadIdx.x & 63;
    const int gw = (blockIdx.x << 2) + (threadIdx.x >> 6);
    const int mtile = gw & 65535;
    const int cls = gw >> 16;
    const int py = cls >> 1, px = cls & 1;
    const int m = lane & 15, kg = lane >> 4;
    const int q = (mtile << 4) + m;
    const int oxh = q & 31, oyh = (q >> 5) & 31, n = q >> 10;
    const ushort* ib = in + (((size_t)n) << 10) * 32;
    f32x4 acc = {0.f, 0.f, 0.f, 0.f};
    const ushort* wl = wfrag + ((size_t)cls << 11) + lane * 8;
    #pragma unroll
    for (int a2 = 0; a2 < 2; ++a2) {
        const int iy = oyh + py - 1 + a2;
        const bool vy = (unsigned)iy < 32u;
        #pragma unroll
        for (int b2 = 0; b2 < 2; ++b2) {
            const int ix = oxh + px - 1 + b2;
            const bool v = vy && ((unsigned)ix < 32u);
            short8 a = {0, 0, 0, 0, 0, 0, 0, 0};
            if (v) a = *(const short8*)(ib + (size_t)((iy << 5) + ix) * 32 + kg * 8);
            const short8 b = *(const short8*)(wl + ((a2 * 2 + b2) << 9));
            acc = __builtin_amdgcn_mfma_f32_16x16x32_bf16(a, b, acc, 0, 0, 0);
        }
    }
    const int och = m;
    if (och < 3) {
        const float bv = bias[och];
        #pragma unroll
        for (int r = 0; r < 4; ++r) {
            const int qq = (mtile << 4) + (kg << 2) + r;
            const int oxh2 = qq & 31, oyh2 = (qq >> 5) & 31, n2 = qq >> 10;
            const int oy = 2 * oyh2 + py, ox = 2 * oxh2 + px;
            out[(size_t)n2 * 12288 + och * 4096 + oy * 64 + ox] = acc[r] + bv;
        }
    }
}

// ---------------- dense FC with optional remaps / bf16 IO ------------------
template<int DIN, int DOUT, bool RELU_IN, bool RELU_OUT, bool REMAP_IN, bool REMAP_OUT,
         bool IN_BF16, bool OUT_BF16>
__global__ __launch_bounds__(256)
void fc_kernel(const void* __restrict__ inv, const float* __restrict__ w,
               const float* __restrict__ bias, void* __restrict__ outv) {
    constexpr int TB = 4;
    __shared__ float a[TB][DIN];
    const int b0 = blockIdx.x * TB;
    for (int idx = threadIdx.x; idx < TB * DIN; idx += 256) {
        int r = idx / DIN, c = idx % DIN;
        float v = IN_BF16 ? bf2f(((const ushort*)inv)[(size_t)(b0 + r) * DIN + c])
                          : ((const float*)inv)[(size_t)(b0 + r) * DIN + c];
        if (RELU_IN) v = fmaxf(v, 0.f);
        int d = REMAP_IN ? ((c & 63) * 16 + (c >> 6)) : c;   // NHWC(p*64+ch) -> ch*16+p
        a[r][d] = v;
    }
    __syncthreads();
    for (int j = threadIdx.x; j < DOUT; j += 256) {
        float acc[TB];
        #pragma unroll
        for (int r = 0; r < TB; ++r) acc[r] = bias[j];
        for (int d = 0; d < DIN; ++d) {
            const float wv = w[(size_t)d * DOUT + j];
            #pragma unroll
            for (int r = 0; r < TB; ++r) acc[r] = fmaf(a[r][d], wv, acc[r]);
        }
        const int jo = REMAP_OUT ? (((j & 15) << 6) + (j >> 4)) : j;  // ch*16+p -> p*64+ch
        #pragma unroll
        for (int r = 0; r < TB; ++r) {
            float v = RELU_OUT ? fmaxf(acc[r], 0.f) : acc[r];
            if (OUT_BF16) ((ushort*)outv)[(size_t)(b0 + r) * DOUT + jo] = f2bf(v);
            else ((float*)outv)[(size_t)(b0 + r) * DOUT + jo] = v;
        }
    }
}

// ---------------- fused encoder switch chain (coalesced, 256 thr/row) ------
__global__ __launch_bounds__(256)
void enc_switch_all(float* __restrict__ h,
                    const float* __restrict__ winT_all,  // [L,192,100] (prepped)
                    const float* __restrict__ bin_all,   // [L,100]
                    const float* __restrict__ wout_all,  // [L,K,10,192]
                    const float* __restrict__ bout_all,  // [L,K,192]
                    const float* __restrict__ wsw_all,   // [L,K,10]
                    const float* __restrict__ bsw_all,   // [L,K]
                    const float* __restrict__ gn_all,    // [L,B,10]
                    int* __restrict__ yidx, float* __restrict__ gateArr) {
    const int b = blockIdx.x, t = threadIdx.x;
    __shared__ float hold[192], r[192], part[200], hid[100], lg[10];
    __shared__ int s_yi; __shared__ float s_gate;
    if (t < 192) { float v = h[(size_t)b * 192 + t]; hold[t] = v; r[t] = fmaxf(v, 0.f); }
    for (int i = 0; i < 10; ++i) {
        __syncthreads();   // r ready
        if (t < 200) {
            const int ks = (t < 100) ? t : t - 100;
            const int half = (t < 100) ? 0 : 1;
            const float* wp = winT_all + (size_t)i * 19200 + half * 9600 + ks;
            const float* rp = r + half * 96;
            float a0 = 0.f, a1 = 0.f, a2 = 0.f, a3 = 0.f;
            #pragma unroll
            for (int dd = 0; dd < 96; dd += 4) {
                a0 = fmaf(rp[dd + 0], wp[(dd + 0) * 100], a0);
                a1 = fmaf(rp[dd + 1], wp[(dd + 1) * 100], a1);
                a2 = fmaf(rp[dd + 2], wp[(dd + 2) * 100], a2);
                a3 = fmaf(rp[dd + 3], wp[(dd + 3) * 100], a3);
            }
            part[t] = (a0 + a1) + (a2 + a3);
        }
        __syncthreads();
        if (t < 100) hid[t] = part[t] + part[t + 100] + bin_all[i * 100 + t];
        __syncthreads();
        if (t < 10) {
            const float* wsw = wsw_all + i * 100 + t * 10;
            float acc = bsw_all[i * 10 + t];
            #pragma unroll
            for (int s = 0; s < 10; ++s) acc = fmaf(hid[t * 10 + s], wsw[s], acc);
            lg[t] = acc - logf(gn_all[(size_t)i * 10240 + b * 10 + t] + 1e-20f);
        }
        __syncthreads();
        if (t == 0) {
            int bi = 0; float best = lg[0];
            #pragma unroll
            for (int k = 1; k < 10; ++k) if (lg[k] > best) { best = lg[k]; bi = k; }
            float sum = 0.f;
            #pragma unroll
            for (int k = 0; k < 10; ++k) sum += expf(lg[k] - best);
            const float ysoft = 1.0f / sum;
            s_yi = bi; s_gate = (1.0f - ysoft) + ysoft;
            yidx[i * 1024 + b] = bi; gateArr[i * 1024 + b] = s_gate;
        }
        __syncthreads();
        const int yi = s_yi; const float gate = s_gate;
        if (t < 192) {
            const float* wp = wout_all + (size_t)i * 19200 + yi * 1920 + t;
            float acc = bout_all[i * 1920 + yi * 192 + t];
            #pragma unroll
            for (int s = 0; s < 10; ++s) acc = fmaf(hid[yi * 10 + s], wp[s * 192], acc);
            float nv = hold[t] + acc * gate;
            hold[t] = nv; r[t] = fmaxf(nv, 0.f);
        }
    }
    __syncthreads();
    if (t < 192) h[(size_t)b * 192 + t] = hold[t];
}

// ---------------- fused decoder switch chain (240-wide hid) ----------------
__global__ __launch_bounds__(256)
void dec_switch_all(float* __restrict__ h,
                    const float* __restrict__ win_all,   // [L,K,192,10]
                    const float* __restrict__ bin_all,   // [L,K,10]
                    const float* __restrict__ wout_all,  // [L,K,10,192]
                    const float* __restrict__ bout_all,  // [L,K,192]
                    const int* __restrict__ yidx, const float* __restrict__ gateArr) {
    const int b = blockIdx.x, t = threadIdx.x;
    __shared__ float hold[192], r[192], part[240], hid[10];
    if (t < 192) { float v = h[(size_t)b * 192 + t]; hold[t] = v; r[t] = fmaxf(v, 0.f); }
    for (int i = 0; i < 10; ++i) {
        const int yi = yidx[i * 1024 + b];
        const float gate = gateArr[i * 1024 + b];
        __syncthreads();   // r ready
        if (t < 240) {
            const int s = t % 10, g = t / 10;     // 24 groups x 8 d's
            const float* wp = win_all + (size_t)i * 19200 + yi * 1920 + s;
            const int d0 = g * 8;
            float a0 = 0.f, a1 = 0.f;
            #pragma unroll
            for (int dd = 0; dd < 8; dd += 2) {
                a0 = fmaf(r[d0 + dd + 0], wp[(d0 + dd + 0) * 10], a0);
                a1 = fmaf(r[d0 + dd + 1], wp[(d0 + dd + 1) * 10], a1);
            }
            part[t] = a0 + a1;
        }
        __syncthreads();
        if (t < 10) {
            float acc = bin_all[i * 100 + yi * 10 + t];
            #pragma unroll
            for (int g = 0; g < 24; ++g) acc += part[g * 10 + t];
            hid[t] = acc;
        }
        __syncthreads();
        if (t < 192) {
            const float* wp = wout_all + (size_t)i * 19200 + yi * 1920 + t;
            float acc = bout_all[i * 1920 + yi * 192 + t];
            #pragma unroll
            for (int s = 0; s < 10; ++s) acc = fmaf(hid[s], wp[s * 192], acc);
            float nv = hold[t] + acc * gate;
            hold[t] = nv; r[t] = fmaxf(nv, 0.f);
        }
    }
    __syncthreads();
    if (t < 192) h[(size_t)b * 192 + t] = hold[t];
}

// ------- z stats + reparameterize + decoder input FC -----------------------
__global__ __launch_bounds__(192)
void zfcl_kernel(const float* __restrict__ h,
                 const float* __restrict__ mw, const float* __restrict__ mb,
                 const float* __restrict__ lw, const float* __restrict__ lb,
                 const float* __restrict__ zn,
                 const float* __restrict__ fw, const float* __restrict__ fb,
                 float* __restrict__ out_z, float* __restrict__ out_mean,
                 float* __restrict__ out_lv, float* __restrict__ dbuf) {
    const int b = blockIdx.x, t = threadIdx.x;
    __shared__ float r[192], pm[160], pl[160], zsh[10];
    for (int d = t; d < 192; d += 192) r[d] = fmaxf(h[(size_t)b * 192 + d], 0.f);
    __syncthreads();
    if (t < 160) {
        const int l = t % 10, g = t / 10;
        float am = 0.f, al = 0.f;
        #pragma unroll
        for (int d = g * 12; d < g * 12 + 12; ++d) {
            am = fmaf(r[d], mw[d * 10 + l], am);
            al = fmaf(r[d], lw[d * 10 + l], al);
        }
        pm[t] = am; pl[t] = al;
    }
    __syncthreads();
    if (t < 10) {
        float zm = mb[t], zl = lb[t];
        #pragma unroll
        for (int g = 0; g < 16; ++g) { zm += pm[g * 10 + t]; zl += pl[g * 10 + t]; }
        const float z = zn[(size_t)b * 10 + t] * expf(zl * 0.5f) + zm;
        out_mean[(size_t)b * 10 + t] = zm;
        out_lv[(size_t)b * 10 + t] = zl;
        out_z[(size_t)b * 10 + t] = z;
        zsh[t] = z;
    }
    __syncthreads();
    for (int d = t; d < 192; d += 192) {
        float acc = fb[d];
        #pragma unroll
        for (int l = 0; l < 10; ++l) acc = fmaf(zsh[l], fw[l * 192 + d], acc);
        dbuf[(size_t)b * 192 + d] = acc;
    }
}

// ---------------------------------------------------------------------------
extern "C" void kernel_launch(void* const* d_in, const int* in_sizes, int n_in,
                              void* d_out, int out_size, void* d_ws, size_t ws_size,
                              hipStream_t stream) {
    const float* x      = (const float*)d_in[0];
    const float* gnoise = (const float*)d_in[1];
    const float* znoise = (const float*)d_in[2];
    const float* cw1 = (const float*)d_in[3];  const float* cb1 = (const float*)d_in[4];
    const float* cw2 = (const float*)d_in[5];  const float* cb2 = (const float*)d_in[6];
    const float* cw3 = (const float*)d_in[7];  const float* cb3 = (const float*)d_in[8];
    const float* cw4 = (const float*)d_in[9];  const float* cb4 = (const float*)d_in[10];
    const float* fc_w = (const float*)d_in[11]; const float* fc_b = (const float*)d_in[12];
    const float* ein_w = (const float*)d_in[13]; const float* ein_b = (const float*)d_in[14];
    const float* eout_w = (const float*)d_in[15]; const float* eout_b = (const float*)d_in[16];
    const float* esw_w = (const float*)d_in[17]; const float* esw_b = (const float*)d_in[18];
    const float* mean_w = (const float*)d_in[19]; const float* mean_b = (const float*)d_in[20];
    const float* lv_w = (const float*)d_in[21]; const float* lv_b = (const float*)d_in[22];
    const float* fcl_w = (const float*)d_in[23]; const float* fcl_b = (const float*)d_in[24];
    const float* din_w = (const float*)d_in[25]; const float* din_b = (const float*)d_in[26];
    const float* dout_w = (const float*)d_in[27]; const float* dout_b = (const float*)d_in[28];
    const float* dfc_w = (const float*)d_in[29]; const float* dfc_b = (const float*)d_in[30];
    const float* dw1 = (const float*)d_in[31]; const float* db1 = (const float*)d_in[32];
    const float* dw2 = (const float*)d_in[33]; const float* db2 = (const float*)d_in[34];
    const float* dw3 = (const float*)d_in[35]; const float* db3 = (const float*)d_in[36];
    const float* dw4 = (const float*)d_in[37]; const float* db4 = (const float*)d_in[38];

    float* out = (float*)d_out;
    float* recon  = out;
    float* z_out  = out + 12582912;
    float* zm_out = z_out + 10240;
    float* zl_out = zm_out + 10240;

    char* ws = (char*)d_ws;
    ushort* xpad  = (ushort*)(ws);                  // [B,64,64,4]  33.5 MB
    ushort* bufA  = (ushort*)(ws + 33554432);       // [B,32,32,32] 67 MB
    ushort* bufB  = (ushort*)(ws + 100663296);      // [B,16,16,32] 16.8 MB
    ushort* bufC  = (ushort*)(ws + 117440512);      // [B,8,8,64]   8.4 MB
    ushort* bufD  = (ushort*)(ws + 125829120);      // [B,4,4,64]   2.1 MB
    float*  bufH  = (float*) (ws + 127926272);      // [B,192]
    float*  bufD2 = (float*) (ws + 128712704);      // [B,192]
    int*    yidx  = (int*)   (ws + 129499136);
    float*  gate  = (float*) (ws + 129540096);
    char*   fb    = ws + 129581056;
    ushort* c1g = (ushort*)(fb);                    //   4096 B
    ushort* c2g = (ushort*)(fb + 4096);             //  32768 B
    ushort* c3g = (ushort*)(fb + 36864);            //  65536 B
    ushort* c4g = (ushort*)(fb + 102400);           // 131072 B
    ushort* d1g = (ushort*)(fb + 233472);           // 131072 B
    ushort* d2g = (ushort*)(fb + 364544);           //  65536 B
    ushort* d3g = (ushort*)(fb + 430080);           //  32768 B
    ushort* d4g = (ushort*)(fb + 462848);           //  16384 B
    float*  encwT = (float*)(fb + 479232);          // 768000 B [L,192,100]

    // ---- packs ----
    x_to_nhwc4<<<16384, 256, 0, stream>>>(x, xpad);
    prep_c1_wfrag<<<8, 256, 0, stream>>>(cw1, c1g);
    prep_conv_wfrag<<<64, 256, 0, stream>>>(cw2, c2g, 32, 32);
    prep_conv_wfrag<<<128, 256, 0, stream>>>(cw3, c3g, 32, 64);
    prep_conv_wfrag<<<256, 256, 0, stream>>>(cw4, c4g, 64, 64);
    prep_deconv_wfrag<<<256, 256, 0, stream>>>(dw1, d1g, 64, 64);
    prep_deconv_wfrag<<<128, 256, 0, stream>>>(dw2, d2g, 64, 32);
    prep_deconv_wfrag<<<64, 256, 0, stream>>>(dw3, d3g, 32, 32);
    prep_dlast_wfrag<<<32, 256, 0, stream>>>(dw4, d4g);
    prep_encwT<<<750, 256, 0, stream>>>(ein_w, encwT);

    // ---- encoder ----
    conv1_mfma<<<32768, 256, 0, stream>>>(xpad, c1g, cb1, bufA);
    conv_mfma<32, 32, 32, 32, true><<<8192, 256, 0, stream>>>(bufA, c2g, cb2, bufB);
    conv_mfma<32, 64, 16, 16, true><<<4096, 256, 0, stream>>>(bufB, c3g, cb3, bufC);
    conv_mfma<64, 64, 8, 8, true><<<1024, 256, 0, stream>>>(bufC, c4g, cb4, bufD);
    fc_kernel<1024, 192, false, false, true, false, true, false>
        <<<256, 256, 0, stream>>>(bufD, fc_w, fc_b, bufH);
    enc_switch_all<<<1024, 256, 0, stream>>>(bufH, encwT, ein_b, eout_w, eout_b,
                                             esw_w, esw_b, gnoise, yidx, gate);
    zfcl_kernel<<<1024, 192, 0, stream>>>(bufH, mean_w, mean_b, lv_w, lv_b,
                                          znoise, fcl_w, fcl_b,
                                          z_out, zm_out, zl_out, bufD2);
    dec_switch_all<<<1024, 256, 0, stream>>>(bufD2, din_w, din_b, dout_w, dout_b, yidx, gate);
    fc_kernel<192, 1024, true, true, false, true, false, true>
        <<<256, 256, 0, stream>>>(bufD2, dfc_w, dfc_b, bufD);

    // ---- decoder deconvs ----
    deconv_mfma<64, 64, 4, 4, true><<<4096, 256, 0, stream>>>(bufD, d1g, db1, bufC);
    deconv_mfma<64, 32, 8, 8, true><<<8192, 256, 0, stream>>>(bufC, d2g, db2, bufB);
    deconv_mfma<32, 32, 16, 16, true><<<32768, 256, 0, stream>>>(bufB, d3g, db3, bufA);
    deconv_last_mfma<<<65536, 256, 0, stream>>>(bufA, d4g, db4, recon);
}

// Round 5
// 491.422 us; speedup vs baseline: 29.3442x; 1.1520x over previous
//
#include <hip/hip_runtime.h>
#include <hip/hip_bf16.h>
#include <math.h>

// ---------------------------------------------------------------------------
// FCSwitchedBetaVAE forward. Conv/deconv stack as implicit-GEMM on
// mfma_f32_16x16x32_bf16 (NHWC bf16 activations, f32 accum). Deconvs fuse all
// 4 parity classes per thread (single input pass, dense 2x2 writes).
// B=1024, C=3, L=10, D=192, K=10, S=10.
// ---------------------------------------------------------------------------

#define BATCH 1024

using short8 = __attribute__((ext_vector_type(8))) short;
using f32x4  = __attribute__((ext_vector_type(4))) float;

__device__ __forceinline__ ushort f2bf(float f) {
    uint u = __float_as_uint(f);
    uint r = (u + 0x7fffu + ((u >> 16) & 1u)) >> 16;   // RNE
    return (ushort)r;
}
__device__ __forceinline__ float bf2f(ushort u) {
    return __uint_as_float(((uint)u) << 16);
}
constexpr int ilog2(int v) { return v <= 1 ? 0 : 1 + ilog2(v >> 1); }

// ------------------------- input pack: NCHW f32 -> NHWC4 bf16 --------------
__global__ __launch_bounds__(256)
void x_to_nhwc4(const float* __restrict__ x, ushort* __restrict__ xp) {
    int idx = blockIdx.x * 256 + threadIdx.x;       // B*4096
    int pix = idx & 4095; int n = idx >> 12;
    const float* xb = x + (size_t)n * 3 * 4096 + pix;
    ushort4 v;
    v.x = f2bf(xb[0]); v.y = f2bf(xb[4096]); v.z = f2bf(xb[8192]); v.w = 0;
    *(ushort4*)(xp + (size_t)idx * 4) = v;
}

// ------------------------- weight fragment prep ----------------------------
// conv frag [tap16][chunk][ntile][lane64][8]
__global__ void prep_conv_wfrag(const float* __restrict__ w, ushort* __restrict__ frag,
                                int CIN, int COUT) {
    int NCH = CIN / 32, NT = COUT / 16;
    int total = 16 * NCH * NT * 512;
    int idx = blockIdx.x * 256 + threadIdx.x;
    if (idx >= total) return;
    int j = idx & 7; int lane = (idx >> 3) & 63; int rest = idx >> 9;
    int ntile = rest % NT; rest /= NT;
    int ch = rest % NCH; int tap = rest / NCH;
    int o = ntile * 16 + (lane & 15);
    int i = ch * 32 + (lane >> 4) * 8 + j;
    frag[idx] = f2bf(w[((size_t)(o * CIN + i)) * 16 + tap]);
}
// deconv frag [cls4][tapidx4][chunk][ntile][lane64][8]
__global__ void prep_deconv_wfrag(const float* __restrict__ w, ushort* __restrict__ frag,
                                  int CIN, int COUT) {
    int NCH = CIN / 32, NT = COUT / 16;
    int total = 16 * NCH * NT * 512;
    int idx = blockIdx.x * 256 + threadIdx.x;
    if (idx >= total) return;
    int j = idx & 7; int lane = (idx >> 3) & 63; int rest = idx >> 9;
    int ntile = rest % NT; rest /= NT;
    int ch = rest % NCH; rest /= NCH;
    int tapidx = rest % 4; int cls = rest / 4;
    int py = cls >> 1, px = cls & 1, a = tapidx >> 1, b = tapidx & 1;
    int tap = (py + 2 * a) * 4 + (px + 2 * b);
    int o = ntile * 16 + (lane & 15);
    int i = ch * 32 + (lane >> 4) * 8 + j;
    frag[idx] = f2bf(w[((size_t)(o * CIN + i)) * 16 + tap]);
}
// conv1 frag [kstep2][ntile2][lane64][8]; K = tap*4 + c (c=3 is zero pad)
__global__ void prep_c1_wfrag(const float* __restrict__ w, ushort* __restrict__ frag) {
    int idx = blockIdx.x * 256 + threadIdx.x;
    if (idx >= 2 * 2 * 512) return;
    int j = idx & 7; int lane = (idx >> 3) & 63;
    int ntile = (idx >> 9) & 1; int s = idx >> 10;
    int o = ntile * 16 + (lane & 15);
    int kg = lane >> 4;
    int tap = s * 8 + kg * 2 + (j >> 2);
    int c = j & 3;
    frag[idx] = (c < 3) ? f2bf(w[((size_t)(o * 3 + c)) * 16 + tap]) : (ushort)0;
}
// deconv_last frag [cls4][tapidx4][lane64][8]; COUT 3 -> padded 16
__global__ void prep_dlast_wfrag(const float* __restrict__ w, ushort* __restrict__ frag) {
    int idx = blockIdx.x * 256 + threadIdx.x;
    if (idx >= 4 * 4 * 512) return;
    int j = idx & 7; int lane = (idx >> 3) & 63; int rest = idx >> 9;
    int tapidx = rest & 3; int cls = rest >> 2;
    int py = cls >> 1, px = cls & 1, a = tapidx >> 1, b = tapidx & 1;
    int tap = (py + 2 * a) * 4 + (px + 2 * b);
    int o = lane & 15;
    int i = (lane >> 4) * 8 + j;
    frag[idx] = (o < 3) ? f2bf(w[((size_t)(o * 32 + i)) * 16 + tap]) : (ushort)0;
}
// encoder switch win transpose: ein_w [L,K,D,S] -> winT [L,D,K*S]
__global__ void prep_encwT(const float* __restrict__ w, float* __restrict__ wt) {
    int idx = blockIdx.x * 256 + threadIdx.x;
    if (idx >= 10 * 192 * 100) return;
    int ks = idx % 100;
    int d = (idx / 100) % 192;
    int l = idx / 19200;
    int k = ks / 10, s = ks % 10;
    wt[idx] = w[(size_t)l * 19200 + k * 1920 + d * 10 + s];
}

// ------------------------- conv1 MFMA: xpad -> [B,32,32,32] ----------------
__global__ __launch_bounds__(256)
void conv1_mfma(const ushort* __restrict__ xp, const ushort* __restrict__ wfrag,
                const float* __restrict__ bias, ushort* __restrict__ out) {
    const int lane = threadIdx.x & 63;
    const int gw = (blockIdx.x << 2) + (threadIdx.x >> 6);
    const int ntile = gw & 1;
    const int mtile = gw >> 1;
    const int m = lane & 15, kg = lane >> 4;
    const int p = (mtile << 4) + m;
    const int ox = p & 31, oy = (p >> 5) & 31, n = p >> 10;
    const ushort* ib = xp + (((size_t)n) << 12) * 4;
    const int iy0 = 2 * oy - 1, ix0 = 2 * ox - 1;
    f32x4 acc = {0.f, 0.f, 0.f, 0.f};
    #pragma unroll
    for (int s = 0; s < 2; ++s) {
        short8 a;
        #pragma unroll
        for (int t = 0; t < 2; ++t) {
            const int tap = s * 8 + kg * 2 + t;
            const int ky = tap >> 2, kx = tap & 3;
            const int iy = iy0 + ky, ix = ix0 + kx;
            ushort4 half = {0, 0, 0, 0};
            if ((unsigned)iy < 64u && (unsigned)ix < 64u)
                half = *(const ushort4*)(ib + (size_t)((iy << 6) + ix) * 4);
            a[4 * t + 0] = (short)half.x; a[4 * t + 1] = (short)half.y;
            a[4 * t + 2] = (short)half.z; a[4 * t + 3] = (short)half.w;
        }
        const short8 b = *(const short8*)(wfrag + ((s * 2 + ntile) << 9) + lane * 8);
        acc = __builtin_amdgcn_mfma_f32_16x16x32_bf16(a, b, acc, 0, 0, 0);
    }
    const int och = (ntile << 4) + m;
    const float bv = bias[och];
    ushort* ob = out + (size_t)((mtile << 4) + (kg << 2)) * 32 + och;
    #pragma unroll
    for (int r = 0; r < 4; ++r) ob[r * 32] = f2bf(fmaxf(acc[r] + bv, 0.f));
}

// ------------------------- generic conv MFMA (s2,p1,k4) --------------------
template<int CIN, int COUT, int HIN, int WIN, bool RELU>
__global__ __launch_bounds__(256)
void conv_mfma(const ushort* __restrict__ in, const ushort* __restrict__ wfrag,
               const float* __restrict__ bias, ushort* __restrict__ out) {
    constexpr int HOUT = HIN / 2, WOUT = WIN / 2, NCH = CIN / 32, NT = COUT / 16;
    constexpr int LW = ilog2(WOUT), LH = ilog2(HOUT);
    const int lane = threadIdx.x & 63;
    const int gw = (blockIdx.x << 2) + (threadIdx.x >> 6);
    const int ntile = gw % NT;
    const int mtile = gw / NT;
    const int m = lane & 15, kg = lane >> 4;
    const int p = (mtile << 4) + m;
    const int ox = p & (WOUT - 1), oy = (p >> LW) & (HOUT - 1), n = p >> (LW + LH);
    const ushort* ibase = in + (size_t)n * (HIN * WIN * CIN);
    const int iy0 = 2 * oy - 1, ix0 = 2 * ox - 1;
    f32x4 acc = {0.f, 0.f, 0.f, 0.f};
    const ushort* wl = wfrag + ((size_t)ntile << 9) + lane * 8;
    #pragma unroll
    for (int ky = 0; ky < 4; ++ky) {
        const int iy = iy0 + ky;
        const bool vy = (unsigned)iy < (unsigned)HIN;
        #pragma unroll
        for (int kx = 0; kx < 4; ++kx) {
            const int ix = ix0 + kx;
            const bool v = vy && ((unsigned)ix < (unsigned)WIN);
            const int tap = ky * 4 + kx;
            #pragma unroll
            for (int ch = 0; ch < NCH; ++ch) {
                short8 a = {0, 0, 0, 0, 0, 0, 0, 0};
                if (v) a = *(const short8*)(ibase + (size_t)(iy * WIN + ix) * CIN + ch * 32 + kg * 8);
                const short8 b = *(const short8*)(wl + ((size_t)((tap * NCH + ch) * NT) << 9));
                acc = __builtin_amdgcn_mfma_f32_16x16x32_bf16(a, b, acc, 0, 0, 0);
            }
        }
    }
    const int och = (ntile << 4) + m;
    const float bv = bias[och];
    ushort* ob = out + (size_t)((mtile << 4) + (kg << 2)) * COUT + och;
    #pragma unroll
    for (int r = 0; r < 4; ++r) {
        float vv = acc[r] + bv;
        if (RELU) vv = fmaxf(vv, 0.f);
        ob[r * COUT] = f2bf(vv);
    }
}

// ------ deconv MFMA (k4,s2,'SAME'), ALL 4 parity classes fused per thread ---
// For class (py,px), tap (a,b): input neighbor (dy,dx) = (py+a-1, px+b-1).
// Union over classes/taps = 3x3 neighborhood, loaded once.
template<int CIN, int COUT, int HIN, int WIN, bool RELU>
__global__ __launch_bounds__(256)
void deconv_mfma_fused(const ushort* __restrict__ in, const ushort* __restrict__ wfrag,
                       const float* __restrict__ bias, ushort* __restrict__ out) {
    constexpr int HOUT = 2 * HIN, WOUT = 2 * WIN, NCH = CIN / 32, NT = COUT / 16;
    constexpr int LW = ilog2(WIN), LH = ilog2(HIN);
    const int lane = threadIdx.x & 63;
    const int gw = (blockIdx.x << 2) + (threadIdx.x >> 6);
    const int ntile = gw % NT;
    const int mtile = gw / NT;
    const int m = lane & 15, kg = lane >> 4;
    const int q = (mtile << 4) + m;
    const int oxh = q & (WIN - 1), oyh = (q >> LW) & (HIN - 1), n = q >> (LW + LH);
    const ushort* ibase = in + (size_t)n * (HIN * WIN * CIN);
    f32x4 acc[4] = {{0,0,0,0},{0,0,0,0},{0,0,0,0},{0,0,0,0}};
    const ushort* wl = wfrag + ((size_t)ntile << 9) + lane * 8;
    #pragma unroll
    for (int ch = 0; ch < NCH; ++ch) {
        short8 nb[3][3];
        #pragma unroll
        for (int dy = 0; dy < 3; ++dy) {
            const int iy = oyh + dy - 1;
            const bool vy = (unsigned)iy < (unsigned)HIN;
            #pragma unroll
            for (int dx = 0; dx < 3; ++dx) {
                const int ix = oxh + dx - 1;
                short8 a = {0, 0, 0, 0, 0, 0, 0, 0};
                if (vy && (unsigned)ix < (unsigned)WIN)
                    a = *(const short8*)(ibase + (size_t)(iy * WIN + ix) * CIN + ch * 32 + kg * 8);
                nb[dy][dx] = a;
            }
        }
        #pragma unroll
        for (int cls = 0; cls < 4; ++cls) {
            const int py = cls >> 1, px = cls & 1;
            #pragma unroll
            for (int ti = 0; ti < 4; ++ti) {
                const int a2 = ti >> 1, b2 = ti & 1;
                const short8 b = *(const short8*)(wl + ((size_t)(((cls * 4 + ti) * NCH + ch) * NT) << 9));
                acc[cls] = __builtin_amdgcn_mfma_f32_16x16x32_bf16(nb[py + a2][px + b2], b, acc[cls], 0, 0, 0);
            }
        }
    }
    const int och = (ntile << 4) + m;
    const float bv = bias[och];
    #pragma unroll
    for (int cls = 0; cls < 4; ++cls) {
        const int py = cls >> 1, px = cls & 1;
        #pragma unroll
        for (int r = 0; r < 4; ++r) {
            const int qq = (mtile << 4) + (kg << 2) + r;
            const int oxh2 = qq & (WIN - 1), oyh2 = (qq >> LW) & (HIN - 1), n2 = qq >> (LW + LH);
            const int oy = 2 * oyh2 + py, ox = 2 * oxh2 + px;
            float vv = acc[cls][r] + bv;
            if (RELU) vv = fmaxf(vv, 0.f);
            out[(size_t)((n2 * HOUT + oy) * WOUT + ox) * COUT + och] = f2bf(vv);
        }
    }
}

// ---- last deconv, 4 classes fused: [B,32,32,32]bf16 -> NCHW f32 [B,3,64,64]
__global__ __launch_bounds__(256)
void deconv_last_fused(const ushort* __restrict__ in, const ushort* __restrict__ wfrag,
                       const float* __restrict__ bias, float* __restrict__ out) {
    const int lane = threadIdx.x & 63;
    const int mtile = (blockIdx.x << 2) + (threadIdx.x >> 6);
    const int m = lane & 15, kg = lane >> 4;
    const int q = (mtile << 4) + m;
    const int oxh = q & 31, oyh = (q >> 5) & 31, n = q >> 10;
    const ushort* ib = in + (((size_t)n) << 10) * 32;
    f32x4 acc[4] = {{0,0,0,0},{0,0,0,0},{0,0,0,0},{0,0,0,0}};
    const ushort* wl = wfrag + lane * 8;
    short8 nb[3][3];
    #pragma unroll
    for (int dy = 0; dy < 3; ++dy) {
        const int iy = oyh + dy - 1;
        const bool vy = (unsigned)iy < 32u;
        #pragma unroll
        for (int dx = 0; dx < 3; ++dx) {
            const int ix = oxh + dx - 1;
            short8 a = {0, 0, 0, 0, 0, 0, 0, 0};
            if (vy && (unsigned)ix < 32u)
                a = *(const short8*)(ib + (size_t)((iy << 5) + ix) * 32 + kg * 8);
            nb[dy][dx] = a;
        }
    }
    #pragma unroll
    for (int cls = 0; cls < 4; ++cls) {
        const int py = cls >> 1, px = cls & 1;
        #pragma unroll
        for (int ti = 0; ti < 4; ++ti) {
            const int a2 = ti >> 1, b2 = ti & 1;
            const short8 b = *(const short8*)(wl + ((cls * 4 + ti) << 9));
            acc[cls] = __builtin_amdgcn_mfma_f32_16x16x32_bf16(nb[py + a2][px + b2], b, acc[cls], 0, 0, 0);
        }
    }
    if (m < 3) {
        const float bv = bias[m];
        #pragma unroll
        for (int r = 0; r < 4; ++r) {
            const int qq = (mtile << 4) + (kg << 2) + r;
            const int oxh2 = qq & 31, oyh2 = (qq >> 5) & 31, n2 = qq >> 10;
            float* ob = out + (size_t)n2 * 12288 + m * 4096 + 2 * oxh2;
            #pragma unroll
            for (int py = 0; py < 2; ++py) {
                float2 v = {acc[py * 2 + 0][r] + bv, acc[py * 2 + 1][r] + bv};
                *(float2*)(ob + (2 * oyh2 + py) * 64) = v;
            }
        }
    }
}

// ---------------- dense FC with optional remaps / bf16 IO ------------------
template<int DIN, int DOUT, bool RELU_IN, bool RELU_OUT, bool REMAP_IN, bool REMAP_OUT,
         bool IN_BF16, bool OUT_BF16>
__global__ __launch_bounds__(256)
void fc_kernel(const void* __restrict__ inv, const float* __restrict__ w,
               const float* __restrict__ bias, void* __restrict__ outv) {
    constexpr int TB = 4;
    __shared__ float a[TB][DIN];
    const int b0 = blockIdx.x * TB;
    for (int idx = threadIdx.x; idx < TB * DIN; idx += 256) {
        int r = idx / DIN, c = idx % DIN;
        float v = IN_BF16 ? bf2f(((const ushort*)inv)[(size_t)(b0 + r) * DIN + c])
                          : ((const float*)inv)[(size_t)(b0 + r) * DIN + c];
        if (RELU_IN) v = fmaxf(v, 0.f);
        int d = REMAP_IN ? ((c & 63) * 16 + (c >> 6)) : c;   // NHWC(p*64+ch) -> ch*16+p
        a[r][d] = v;
    }
    __syncthreads();
    for (int j = threadIdx.x; j < DOUT; j += 256) {
        float acc[TB];
        #pragma unroll
        for (int r = 0; r < TB; ++r) acc[r] = bias[j];
        for (int d = 0; d < DIN; ++d) {
            const float wv = w[(size_t)d * DOUT + j];
            #pragma unroll
            for (int r = 0; r < TB; ++r) acc[r] = fmaf(a[r][d], wv, acc[r]);
        }
        const int jo = REMAP_OUT ? (((j & 15) << 6) + (j >> 4)) : j;  // ch*16+p -> p*64+ch
        #pragma unroll
        for (int r = 0; r < TB; ++r) {
            float v = RELU_OUT ? fmaxf(acc[r], 0.f) : acc[r];
            if (OUT_BF16) ((ushort*)outv)[(size_t)(b0 + r) * DOUT + jo] = f2bf(v);
            else ((float*)outv)[(size_t)(b0 + r) * DOUT + jo] = v;
        }
    }
}

// ---------------- fused encoder switch chain (coalesced, 256 thr/row) ------
__global__ __launch_bounds__(256)
void enc_switch_all(float* __restrict__ h,
                    const float* __restrict__ winT_all,  // [L,192,100] (prepped)
                    const float* __restrict__ bin_all,   // [L,100]
                    const float* __restrict__ wout_all,  // [L,K,10,192]
                    const float* __restrict__ bout_all,  // [L,K,192]
                    const float* __restrict__ wsw_all,   // [L,K,10]
                    const float* __restrict__ bsw_all,   // [L,K]
                    const float* __restrict__ gn_all,    // [L,B,10]
                    int* __restrict__ yidx, float* __restrict__ gateArr) {
    const int b = blockIdx.x, t = threadIdx.x;
    __shared__ float hold[192], r[192], part[200], hid[100], lg[10];
    __shared__ int s_yi; __shared__ float s_gate;
    if (t < 192) { float v = h[(size_t)b * 192 + t]; hold[t] = v; r[t] = fmaxf(v, 0.f); }
    for (int i = 0; i < 10; ++i) {
        __syncthreads();   // r ready
        if (t < 200) {
            const int ks = (t < 100) ? t : t - 100;
            const int half = (t < 100) ? 0 : 1;
            const float* wp = winT_all + (size_t)i * 19200 + half * 9600 + ks;
            const float* rp = r + half * 96;
            float a0 = 0.f, a1 = 0.f, a2 = 0.f, a3 = 0.f;
            #pragma unroll
            for (int dd = 0; dd < 96; dd += 4) {
                a0 = fmaf(rp[dd + 0], wp[(dd + 0) * 100], a0);
                a1 = fmaf(rp[dd + 1], wp[(dd + 1) * 100], a1);
                a2 = fmaf(rp[dd + 2], wp[(dd + 2) * 100], a2);
                a3 = fmaf(rp[dd + 3], wp[(dd + 3) * 100], a3);
            }
            part[t] = (a0 + a1) + (a2 + a3);
        }
        __syncthreads();
        if (t < 100) hid[t] = part[t] + part[t + 100] + bin_all[i * 100 + t];
        __syncthreads();
        if (t < 10) {
            const float* wsw = wsw_all + i * 100 + t * 10;
            float acc = bsw_all[i * 10 + t];
            #pragma unroll
            for (int s = 0; s < 10; ++s) acc = fmaf(hid[t * 10 + s], wsw[s], acc);
            lg[t] = acc - logf(gn_all[(size_t)i * 10240 + b * 10 + t] + 1e-20f);
        }
        __syncthreads();
        if (t == 0) {
            int bi = 0; float best = lg[0];
            #pragma unroll
            for (int k = 1; k < 10; ++k) if (lg[k] > best) { best = lg[k]; bi = k; }
            float sum = 0.f;
            #pragma unroll
            for (int k = 0; k < 10; ++k) sum += expf(lg[k] - best);
            const float ysoft = 1.0f / sum;
            s_yi = bi; s_gate = (1.0f - ysoft) + ysoft;
            yidx[i * 1024 + b] = bi; gateArr[i * 1024 + b] = s_gate;
        }
        __syncthreads();
        const int yi = s_yi; const float gate = s_gate;
        if (t < 192) {
            const float* wp = wout_all + (size_t)i * 19200 + yi * 1920 + t;
            float acc = bout_all[i * 1920 + yi * 192 + t];
            #pragma unroll
            for (int s = 0; s < 10; ++s) acc = fmaf(hid[yi * 10 + s], wp[s * 192], acc);
            float nv = hold[t] + acc * gate;
            hold[t] = nv; r[t] = fmaxf(nv, 0.f);
        }
    }
    __syncthreads();
    if (t < 192) h[(size_t)b * 192 + t] = hold[t];
}

// ---------------- fused decoder switch chain (240-wide hid) ----------------
__global__ __launch_bounds__(256)
void dec_switch_all(float* __restrict__ h,
                    const float* __restrict__ win_all,   // [L,K,192,10]
                    const float* __restrict__ bin_all,   // [L,K,10]
                    const float* __restrict__ wout_all,  // [L,K,10,192]
                    const float* __restrict__ bout_all,  // [L,K,192]
                    const int* __restrict__ yidx, const float* __restrict__ gateArr) {
    const int b = blockIdx.x, t = threadIdx.x;
    __shared__ float hold[192], r[192], part[240], hid[10];
    if (t < 192) { float v = h[(size_t)b * 192 + t]; hold[t] = v; r[t] = fmaxf(v, 0.f); }
    for (int i = 0; i < 10; ++i) {
        const int yi = yidx[i * 1024 + b];
        const float gate = gateArr[i * 1024 + b];
        __syncthreads();   // r ready
        if (t < 240) {
            const int s = t % 10, g = t / 10;     // 24 groups x 8 d's
            const float* wp = win_all + (size_t)i * 19200 + yi * 1920 + s;
            const int d0 = g * 8;
            float a0 = 0.f, a1 = 0.f;
            #pragma unroll
            for (int dd = 0; dd < 8; dd += 2) {
                a0 = fmaf(r[d0 + dd + 0], wp[(d0 + dd + 0) * 10], a0);
                a1 = fmaf(r[d0 + dd + 1], wp[(d0 + dd + 1) * 10], a1);
            }
            part[t] = a0 + a1;
        }
        __syncthreads();
        if (t < 10) {
            float acc = bin_all[i * 100 + yi * 10 + t];
            #pragma unroll
            for (int g = 0; g < 24; ++g) acc += part[g * 10 + t];
            hid[t] = acc;
        }
        __syncthreads();
        if (t < 192) {
            const float* wp = wout_all + (size_t)i * 19200 + yi * 1920 + t;
            float acc = bout_all[i * 1920 + yi * 192 + t];
            #pragma unroll
            for (int s = 0; s < 10; ++s) acc = fmaf(hid[s], wp[s * 192], acc);
            float nv = hold[t] + acc * gate;
            hold[t] = nv; r[t] = fmaxf(nv, 0.f);
        }
    }
    __syncthreads();
    if (t < 192) h[(size_t)b * 192 + t] = hold[t];
}

// ------- z stats + reparameterize + decoder input FC -----------------------
__global__ __launch_bounds__(192)
void zfcl_kernel(const float* __restrict__ h,
                 const float* __restrict__ mw, const float* __restrict__ mb,
                 const float* __restrict__ lw, const float* __restrict__ lb,
                 const float* __restrict__ zn,
                 const float* __restrict__ fw, const float* __restrict__ fb,
                 float* __restrict__ out_z, float* __restrict__ out_mean,
                 float* __restrict__ out_lv, float* __restrict__ dbuf) {
    const int b = blockIdx.x, t = threadIdx.x;
    __shared__ float r[192], pm[160], pl[160], zsh[10];
    for (int d = t; d < 192; d += 192) r[d] = fmaxf(h[(size_t)b * 192 + d], 0.f);
    __syncthreads();
    if (t < 160) {
        const int l = t % 10, g = t / 10;
        float am = 0.f, al = 0.f;
        #pragma unroll
        for (int d = g * 12; d < g * 12 + 12; ++d) {
            am = fmaf(r[d], mw[d * 10 + l], am);
            al = fmaf(r[d], lw[d * 10 + l], al);
        }
        pm[t] = am; pl[t] = al;
    }
    __syncthreads();
    if (t < 10) {
        float zm = mb[t], zl = lb[t];
        #pragma unroll
        for (int g = 0; g < 16; ++g) { zm += pm[g * 10 + t]; zl += pl[g * 10 + t]; }
        const float z = zn[(size_t)b * 10 + t] * expf(zl * 0.5f) + zm;
        out_mean[(size_t)b * 10 + t] = zm;
        out_lv[(size_t)b * 10 + t] = zl;
        out_z[(size_t)b * 10 + t] = z;
        zsh[t] = z;
    }
    __syncthreads();
    for (int d = t; d < 192; d += 192) {
        float acc = fb[d];
        #pragma unroll
        for (int l = 0; l < 10; ++l) acc = fmaf(zsh[l], fw[l * 192 + d], acc);
        dbuf[(size_t)b * 192 + d] = acc;
    }
}

// ---------------------------------------------------------------------------
extern "C" void kernel_launch(void* const* d_in, const int* in_sizes, int n_in,
                              void* d_out, int out_size, void* d_ws, size_t ws_size,
                              hipStream_t stream) {
    const float* x      = (const float*)d_in[0];
    const float* gnoise = (const float*)d_in[1];
    const float* znoise = (const float*)d_in[2];
    const float* cw1 = (const float*)d_in[3];  const float* cb1 = (const float*)d_in[4];
    const float* cw2 = (const float*)d_in[5];  const float* cb2 = (const float*)d_in[6];
    const float* cw3 = (const float*)d_in[7];  const float* cb3 = (const float*)d_in[8];
    const float* cw4 = (const float*)d_in[9];  const float* cb4 = (const float*)d_in[10];
    const float* fc_w = (const float*)d_in[11]; const float* fc_b = (const float*)d_in[12];
    const float* ein_w = (const float*)d_in[13]; const float* ein_b = (const float*)d_in[14];
    const float* eout_w = (const float*)d_in[15]; const float* eout_b = (const float*)d_in[16];
    const float* esw_w = (const float*)d_in[17]; const float* esw_b = (const float*)d_in[18];
    const float* mean_w = (const float*)d_in[19]; const float* mean_b = (const float*)d_in[20];
    const float* lv_w = (const float*)d_in[21]; const float* lv_b = (const float*)d_in[22];
    const float* fcl_w = (const float*)d_in[23]; const float* fcl_b = (const float*)d_in[24];
    const float* din_w = (const float*)d_in[25]; const float* din_b = (const float*)d_in[26];
    const float* dout_w = (const float*)d_in[27]; const float* dout_b = (const float*)d_in[28];
    const float* dfc_w = (const float*)d_in[29]; const float* dfc_b = (const float*)d_in[30];
    const float* dw1 = (const float*)d_in[31]; const float* db1 = (const float*)d_in[32];
    const float* dw2 = (const float*)d_in[33]; const float* db2 = (const float*)d_in[34];
    const float* dw3 = (const float*)d_in[35]; const float* db3 = (const float*)d_in[36];
    const float* dw4 = (const float*)d_in[37]; const float* db4 = (const float*)d_in[38];

    float* out = (float*)d_out;
    float* recon  = out;
    float* z_out  = out + 12582912;
    float* zm_out = z_out + 10240;
    float* zl_out = zm_out + 10240;

    char* ws = (char*)d_ws;
    ushort* xpad  = (ushort*)(ws);                  // [B,64,64,4]  33.5 MB
    ushort* bufA  = (ushort*)(ws + 33554432);       // [B,32,32,32] 67 MB
    ushort* bufB  = (ushort*)(ws + 100663296);      // [B,16,16,32] 16.8 MB
    ushort* bufC  = (ushort*)(ws + 117440512);      // [B,8,8,64]   8.4 MB
    ushort* bufD  = (ushort*)(ws + 125829120);      // [B,4,4,64]   2.1 MB
    float*  bufH  = (float*) (ws + 127926272);      // [B,192]
    float*  bufD2 = (float*) (ws + 128712704);      // [B,192]
    int*    yidx  = (int*)   (ws + 129499136);
    float*  gate  = (float*) (ws + 129540096);
    char*   fb    = ws + 129581056;
    ushort* c1g = (ushort*)(fb);                    //   4096 B
    ushort* c2g = (ushort*)(fb + 4096);             //  32768 B
    ushort* c3g = (ushort*)(fb + 36864);            //  65536 B
    ushort* c4g = (ushort*)(fb + 102400);           // 131072 B
    ushort* d1g = (ushort*)(fb + 233472);           // 131072 B
    ushort* d2g = (ushort*)(fb + 364544);           //  65536 B
    ushort* d3g = (ushort*)(fb + 430080);           //  32768 B
    ushort* d4g = (ushort*)(fb + 462848);           //  16384 B
    float*  encwT = (float*)(fb + 479232);          // 768000 B [L,192,100]

    // ---- packs ----
    x_to_nhwc4<<<16384, 256, 0, stream>>>(x, xpad);
    prep_c1_wfrag<<<8, 256, 0, stream>>>(cw1, c1g);
    prep_conv_wfrag<<<64, 256, 0, stream>>>(cw2, c2g, 32, 32);
    prep_conv_wfrag<<<128, 256, 0, stream>>>(cw3, c3g, 32, 64);
    prep_conv_wfrag<<<256, 256, 0, stream>>>(cw4, c4g, 64, 64);
    prep_deconv_wfrag<<<256, 256, 0, stream>>>(dw1, d1g, 64, 64);
    prep_deconv_wfrag<<<128, 256, 0, stream>>>(dw2, d2g, 64, 32);
    prep_deconv_wfrag<<<64, 256, 0, stream>>>(dw3, d3g, 32, 32);
    prep_dlast_wfrag<<<32, 256, 0, stream>>>(dw4, d4g);
    prep_encwT<<<750, 256, 0, stream>>>(ein_w, encwT);

    // ---- encoder ----
    conv1_mfma<<<32768, 256, 0, stream>>>(xpad, c1g, cb1, bufA);
    conv_mfma<32, 32, 32, 32, true><<<8192, 256, 0, stream>>>(bufA, c2g, cb2, bufB);
    conv_mfma<32, 64, 16, 16, true><<<4096, 256, 0, stream>>>(bufB, c3g, cb3, bufC);
    conv_mfma<64, 64, 8, 8, true><<<1024, 256, 0, stream>>>(bufC, c4g, cb4, bufD);
    fc_kernel<1024, 192, false, false, true, false, true, false>
        <<<256, 256, 0, stream>>>(bufD, fc_w, fc_b, bufH);
    enc_switch_all<<<1024, 256, 0, stream>>>(bufH, encwT, ein_b, eout_w, eout_b,
                                             esw_w, esw_b, gnoise, yidx, gate);
    zfcl_kernel<<<1024, 192, 0, stream>>>(bufH, mean_w, mean_b, lv_w, lv_b,
                                          znoise, fcl_w, fcl_b,
                                          z_out, zm_out, zl_out, bufD2);
    dec_switch_all<<<1024, 256, 0, stream>>>(bufD2, din_w, din_b, dout_w, dout_b, yidx, gate);
    fc_kernel<192, 1024, true, true, false, true, false, true>
        <<<256, 256, 0, stream>>>(bufD2, dfc_w, dfc_b, bufD);

    // ---- decoder deconvs (4 parity classes fused per thread) ----
    deconv_mfma_fused<64, 64, 4, 4, true><<<1024, 256, 0, stream>>>(bufD, d1g, db1, bufC);
    deconv_mfma_fused<64, 32, 8, 8, true><<<2048, 256, 0, stream>>>(bufC, d2g, db2, bufB);
    deconv_mfma_fused<32, 32, 16, 16, true><<<8192, 256, 0, stream>>>(bufB, d3g, db3, bufA);
    deconv_last_fused<<<16384, 256, 0, stream>>>(bufA, d4g, db4, recon);
}

// Round 6
// 430.886 us; speedup vs baseline: 33.4668x; 1.1405x over previous
//
#include <hip/hip_runtime.h>
#include <hip/hip_bf16.h>
#include <math.h>

// ---------------------------------------------------------------------------
// FCSwitchedBetaVAE forward. Conv/deconv stack as implicit-GEMM on
// mfma_f32_16x16x32_bf16 (NHWC bf16 activations, f32 accum). Deconvs fuse all
// 4 parity classes per thread; waves compute 2 output-channel tiles (NTW=2);
// last deconv uses an LDS-staged dense NCHW epilogue.
// B=1024, C=3, L=10, D=192, K=10, S=10.
// ---------------------------------------------------------------------------

#define BATCH 1024

using short8 = __attribute__((ext_vector_type(8))) short;
using f32x4  = __attribute__((ext_vector_type(4))) float;

__device__ __forceinline__ ushort f2bf(float f) {
    uint u = __float_as_uint(f);
    uint r = (u + 0x7fffu + ((u >> 16) & 1u)) >> 16;   // RNE
    return (ushort)r;
}
__device__ __forceinline__ float bf2f(ushort u) {
    return __uint_as_float(((uint)u) << 16);
}
constexpr int ilog2(int v) { return v <= 1 ? 0 : 1 + ilog2(v >> 1); }

// ------------------------- input pack: NCHW f32 -> NHWC4 bf16 --------------
__global__ __launch_bounds__(256)
void x_to_nhwc4(const float* __restrict__ x, ushort* __restrict__ xp) {
    int idx = blockIdx.x * 256 + threadIdx.x;       // B*4096
    int pix = idx & 4095; int n = idx >> 12;
    const float* xb = x + (size_t)n * 3 * 4096 + pix;
    ushort4 v;
    v.x = f2bf(xb[0]); v.y = f2bf(xb[4096]); v.z = f2bf(xb[8192]); v.w = 0;
    *(ushort4*)(xp + (size_t)idx * 4) = v;
}

// ------------------------- weight fragment prep ----------------------------
// conv frag [tap16][chunk][ntile][lane64][8]
__global__ void prep_conv_wfrag(const float* __restrict__ w, ushort* __restrict__ frag,
                                int CIN, int COUT) {
    int NCH = CIN / 32, NT = COUT / 16;
    int total = 16 * NCH * NT * 512;
    int idx = blockIdx.x * 256 + threadIdx.x;
    if (idx >= total) return;
    int j = idx & 7; int lane = (idx >> 3) & 63; int rest = idx >> 9;
    int ntile = rest % NT; rest /= NT;
    int ch = rest % NCH; int tap = rest / NCH;
    int o = ntile * 16 + (lane & 15);
    int i = ch * 32 + (lane >> 4) * 8 + j;
    frag[idx] = f2bf(w[((size_t)(o * CIN + i)) * 16 + tap]);
}
// deconv frag [cls4][tapidx4][chunk][ntile][lane64][8]
__global__ void prep_deconv_wfrag(const float* __restrict__ w, ushort* __restrict__ frag,
                                  int CIN, int COUT) {
    int NCH = CIN / 32, NT = COUT / 16;
    int total = 16 * NCH * NT * 512;
    int idx = blockIdx.x * 256 + threadIdx.x;
    if (idx >= total) return;
    int j = idx & 7; int lane = (idx >> 3) & 63; int rest = idx >> 9;
    int ntile = rest % NT; rest /= NT;
    int ch = rest % NCH; rest /= NCH;
    int tapidx = rest % 4; int cls = rest / 4;
    int py = cls >> 1, px = cls & 1, a = tapidx >> 1, b = tapidx & 1;
    int tap = (py + 2 * a) * 4 + (px + 2 * b);
    int o = ntile * 16 + (lane & 15);
    int i = ch * 32 + (lane >> 4) * 8 + j;
    frag[idx] = f2bf(w[((size_t)(o * CIN + i)) * 16 + tap]);
}
// conv1 frag [kstep2][ntile2][lane64][8]; K = tap*4 + c (c=3 is zero pad)
__global__ void prep_c1_wfrag(const float* __restrict__ w, ushort* __restrict__ frag) {
    int idx = blockIdx.x * 256 + threadIdx.x;
    if (idx >= 2 * 2 * 512) return;
    int j = idx & 7; int lane = (idx >> 3) & 63;
    int ntile = (idx >> 9) & 1; int s = idx >> 10;
    int o = ntile * 16 + (lane & 15);
    int kg = lane >> 4;
    int tap = s * 8 + kg * 2 + (j >> 2);
    int c = j & 3;
    frag[idx] = (c < 3) ? f2bf(w[((size_t)(o * 3 + c)) * 16 + tap]) : (ushort)0;
}
// deconv_last frag [cls4][tapidx4][lane64][8]; COUT 3 -> padded 16
__global__ void prep_dlast_wfrag(const float* __restrict__ w, ushort* __restrict__ frag) {
    int idx = blockIdx.x * 256 + threadIdx.x;
    if (idx >= 4 * 4 * 512) return;
    int j = idx & 7; int lane = (idx >> 3) & 63; int rest = idx >> 9;
    int tapidx = rest & 3; int cls = rest >> 2;
    int py = cls >> 1, px = cls & 1, a = tapidx >> 1, b = tapidx & 1;
    int tap = (py + 2 * a) * 4 + (px + 2 * b);
    int o = lane & 15;
    int i = (lane >> 4) * 8 + j;
    frag[idx] = (o < 3) ? f2bf(w[((size_t)(o * 32 + i)) * 16 + tap]) : (ushort)0;
}
// encoder switch win transpose: ein_w [L,K,D,S] -> winT [L,D,K*S]
__global__ void prep_encwT(const float* __restrict__ w, float* __restrict__ wt) {
    int idx = blockIdx.x * 256 + threadIdx.x;
    if (idx >= 10 * 192 * 100) return;
    int ks = idx % 100;
    int d = (idx / 100) % 192;
    int l = idx / 19200;
    int k = ks / 10, s = ks % 10;
    wt[idx] = w[(size_t)l * 19200 + k * 1920 + d * 10 + s];
}

// ----------- conv1 MFMA, both ntiles per wave: xpad -> [B,32,32,32] --------
__global__ __launch_bounds__(256)
void conv1_mfma(const ushort* __restrict__ xp, const ushort* __restrict__ wfrag,
                const float* __restrict__ bias, ushort* __restrict__ out) {
    const int lane = threadIdx.x & 63;
    const int mtile = (blockIdx.x << 2) + (threadIdx.x >> 6);
    const int m = lane & 15, kg = lane >> 4;
    const int p = (mtile << 4) + m;
    const int ox = p & 31, oy = (p >> 5) & 31, n = p >> 10;
    const ushort* ib = xp + (((size_t)n) << 12) * 4;
    const int iy0 = 2 * oy - 1, ix0 = 2 * ox - 1;
    f32x4 acc[2] = {{0,0,0,0},{0,0,0,0}};
    #pragma unroll
    for (int s = 0; s < 2; ++s) {
        short8 a;
        #pragma unroll
        for (int t = 0; t < 2; ++t) {
            const int tap = s * 8 + kg * 2 + t;
            const int ky = tap >> 2, kx = tap & 3;
            const int iy = iy0 + ky, ix = ix0 + kx;
            ushort4 half = {0, 0, 0, 0};
            if ((unsigned)iy < 64u && (unsigned)ix < 64u)
                half = *(const ushort4*)(ib + (size_t)((iy << 6) + ix) * 4);
            a[4 * t + 0] = (short)half.x; a[4 * t + 1] = (short)half.y;
            a[4 * t + 2] = (short)half.z; a[4 * t + 3] = (short)half.w;
        }
        #pragma unroll
        for (int nt = 0; nt < 2; ++nt) {
            const short8 b = *(const short8*)(wfrag + ((s * 2 + nt) << 9) + lane * 8);
            acc[nt] = __builtin_amdgcn_mfma_f32_16x16x32_bf16(a, b, acc[nt], 0, 0, 0);
        }
    }
    ushort* ob = out + (size_t)((mtile << 4) + (kg << 2)) * 32;
    #pragma unroll
    for (int nt = 0; nt < 2; ++nt) {
        const int och = (nt << 4) + m;
        const float bv = bias[och];
        #pragma unroll
        for (int r = 0; r < 4; ++r) ob[r * 32 + och] = f2bf(fmaxf(acc[nt][r] + bv, 0.f));
    }
}

// ------------- generic conv MFMA (s2,p1,k4), NTW ntiles per wave -----------
template<int CIN, int COUT, int HIN, int WIN, int NTW, bool RELU>
__global__ __launch_bounds__(256)
void conv_mfma(const ushort* __restrict__ in, const ushort* __restrict__ wfrag,
               const float* __restrict__ bias, ushort* __restrict__ out) {
    constexpr int HOUT = HIN / 2, WOUT = WIN / 2, NCH = CIN / 32, NT = COUT / 16;
    constexpr int NTG = NT / NTW;
    constexpr int LW = ilog2(WOUT), LH = ilog2(HOUT);
    const int lane = threadIdx.x & 63;
    const int gw = (blockIdx.x << 2) + (threadIdx.x >> 6);
    const int ntg = gw % NTG;
    const int mtile = gw / NTG;
    const int m = lane & 15, kg = lane >> 4;
    const int p = (mtile << 4) + m;
    const int ox = p & (WOUT - 1), oy = (p >> LW) & (HOUT - 1), n = p >> (LW + LH);
    const ushort* ibase = in + (size_t)n * (HIN * WIN * CIN);
    const int iy0 = 2 * oy - 1, ix0 = 2 * ox - 1;
    f32x4 acc[NTW];
    #pragma unroll
    for (int nt = 0; nt < NTW; ++nt) acc[nt] = (f32x4){0, 0, 0, 0};
    const ushort* wl = wfrag + ((size_t)(ntg * NTW) << 9) + lane * 8;
    #pragma unroll
    for (int ky = 0; ky < 4; ++ky) {
        const int iy = iy0 + ky;
        const bool vy = (unsigned)iy < (unsigned)HIN;
        #pragma unroll
        for (int kx = 0; kx < 4; ++kx) {
            const int ix = ix0 + kx;
            const bool v = vy && ((unsigned)ix < (unsigned)WIN);
            const int tap = ky * 4 + kx;
            #pragma unroll
            for (int ch = 0; ch < NCH; ++ch) {
                short8 a = {0, 0, 0, 0, 0, 0, 0, 0};
                if (v) a = *(const short8*)(ibase + (size_t)(iy * WIN + ix) * CIN + ch * 32 + kg * 8);
                #pragma unroll
                for (int nt = 0; nt < NTW; ++nt) {
                    const short8 b = *(const short8*)(wl + ((size_t)((tap * NCH + ch) * NT + nt) << 9));
                    acc[nt] = __builtin_amdgcn_mfma_f32_16x16x32_bf16(a, b, acc[nt], 0, 0, 0);
                }
            }
        }
    }
    ushort* ob = out + (size_t)((mtile << 4) + (kg << 2)) * COUT;
    #pragma unroll
    for (int nt = 0; nt < NTW; ++nt) {
        const int och = ((ntg * NTW + nt) << 4) + m;
        const float bv = bias[och];
        #pragma unroll
        for (int r = 0; r < 4; ++r) {
            float vv = acc[nt][r] + bv;
            if (RELU) vv = fmaxf(vv, 0.f);
            ob[r * COUT + och] = f2bf(vv);
        }
    }
}

// ------ deconv MFMA, 4 parity classes + NTW ntiles fused per thread --------
template<int CIN, int COUT, int HIN, int WIN, int NTW, bool RELU>
__global__ __launch_bounds__(256)
void deconv_mfma_fused(const ushort* __restrict__ in, const ushort* __restrict__ wfrag,
                       const float* __restrict__ bias, ushort* __restrict__ out) {
    constexpr int HOUT = 2 * HIN, WOUT = 2 * WIN, NCH = CIN / 32, NT = COUT / 16;
    constexpr int NTG = NT / NTW;
    constexpr int LW = ilog2(WIN), LH = ilog2(HIN);
    const int lane = threadIdx.x & 63;
    const int gw = (blockIdx.x << 2) + (threadIdx.x >> 6);
    const int ntg = gw % NTG;
    const int mtile = gw / NTG;
    const int m = lane & 15, kg = lane >> 4;
    const int q = (mtile << 4) + m;
    const int oxh = q & (WIN - 1), oyh = (q >> LW) & (HIN - 1), n = q >> (LW + LH);
    const ushort* ibase = in + (size_t)n * (HIN * WIN * CIN);
    f32x4 acc[4][NTW];
    #pragma unroll
    for (int c = 0; c < 4; ++c)
        #pragma unroll
        for (int nt = 0; nt < NTW; ++nt) acc[c][nt] = (f32x4){0, 0, 0, 0};
    const ushort* wl = wfrag + ((size_t)(ntg * NTW) << 9) + lane * 8;
    #pragma unroll
    for (int ch = 0; ch < NCH; ++ch) {
        short8 nb[3][3];
        #pragma unroll
        for (int dy = 0; dy < 3; ++dy) {
            const int iy = oyh + dy - 1;
            const bool vy = (unsigned)iy < (unsigned)HIN;
            #pragma unroll
            for (int dx = 0; dx < 3; ++dx) {
                const int ix = oxh + dx - 1;
                short8 a = {0, 0, 0, 0, 0, 0, 0, 0};
                if (vy && (unsigned)ix < (unsigned)WIN)
                    a = *(const short8*)(ibase + (size_t)(iy * WIN + ix) * CIN + ch * 32 + kg * 8);
                nb[dy][dx] = a;
            }
        }
        #pragma unroll
        for (int cls = 0; cls < 4; ++cls) {
            const int py = cls >> 1, px = cls & 1;
            #pragma unroll
            for (int ti = 0; ti < 4; ++ti) {
                const int a2 = ti >> 1, b2 = ti & 1;
                #pragma unroll
                for (int nt = 0; nt < NTW; ++nt) {
                    const short8 b = *(const short8*)(wl + ((size_t)(((cls * 4 + ti) * NCH + ch) * NT + nt) << 9));
                    acc[cls][nt] = __builtin_amdgcn_mfma_f32_16x16x32_bf16(nb[py + a2][px + b2], b, acc[cls][nt], 0, 0, 0);
                }
            }
        }
    }
    #pragma unroll
    for (int nt = 0; nt < NTW; ++nt) {
        const int och = ((ntg * NTW + nt) << 4) + m;
        const float bv = bias[och];
        #pragma unroll
        for (int cls = 0; cls < 4; ++cls) {
            const int py = cls >> 1, px = cls & 1;
            #pragma unroll
            for (int r = 0; r < 4; ++r) {
                const int qq = (mtile << 4) + (kg << 2) + r;
                const int oxh2 = qq & (WIN - 1), oyh2 = (qq >> LW) & (HIN - 1), n2 = qq >> (LW + LH);
                const int oy = 2 * oyh2 + py, ox = 2 * oxh2 + px;
                float vv = acc[cls][nt][r] + bv;
                if (RELU) vv = fmaxf(vv, 0.f);
                out[(size_t)((n2 * HOUT + oy) * WOUT + ox) * COUT + och] = f2bf(vv);
            }
        }
    }
}

// ---- last deconv, 4 classes fused, LDS-staged dense NCHW f32 epilogue -----
// Block = 64 half-pixels (2 input rows) -> 3ch x 4rows x 64cols output slab.
__global__ __launch_bounds__(256)
void deconv_last_fused(const ushort* __restrict__ in, const ushort* __restrict__ wfrag,
                       const float* __restrict__ bias, float* __restrict__ out) {
    __shared__ float sbuf[3][4][64];
    const int lane = threadIdx.x & 63;
    const int w = threadIdx.x >> 6;
    const int mtile = (blockIdx.x << 2) + w;
    const int m = lane & 15, kg = lane >> 4;
    const int q = (mtile << 4) + m;
    const int oxh = q & 31, oyh = (q >> 5) & 31, n = q >> 10;
    const ushort* ib = in + (((size_t)n) << 10) * 32;
    f32x4 acc[4] = {{0,0,0,0},{0,0,0,0},{0,0,0,0},{0,0,0,0}};
    const ushort* wl = wfrag + lane * 8;
    short8 nb[3][3];
    #pragma unroll
    for (int dy = 0; dy < 3; ++dy) {
        const int iy = oyh + dy - 1;
        const bool vy = (unsigned)iy < 32u;
        #pragma unroll
        for (int dx = 0; dx < 3; ++dx) {
            const int ix = oxh + dx - 1;
            short8 a = {0, 0, 0, 0, 0, 0, 0, 0};
            if (vy && (unsigned)ix < 32u)
                a = *(const short8*)(ib + (size_t)((iy << 5) + ix) * 32 + kg * 8);
            nb[dy][dx] = a;
        }
    }
    #pragma unroll
    for (int cls = 0; cls < 4; ++cls) {
        const int py = cls >> 1, px = cls & 1;
        #pragma unroll
        for (int ti = 0; ti < 4; ++ti) {
            const int a2 = ti >> 1, b2 = ti & 1;
            const short8 b = *(const short8*)(wl + ((cls * 4 + ti) << 9));
            acc[cls] = __builtin_amdgcn_mfma_f32_16x16x32_bf16(nb[py + a2][px + b2], b, acc[cls], 0, 0, 0);
        }
    }
    if (m < 3) {
        const float bv = bias[m];
        #pragma unroll
        for (int cls = 0; cls < 4; ++cls) {
            const int py = cls >> 1, px = cls & 1;
            #pragma unroll
            for (int r = 0; r < 4; ++r) {
                const int lq = (w << 4) + (kg << 2) + r;           // [0,64)
                const int oyl = ((lq >> 5) << 1) + py;             // [0,4)
                const int oxl = ((lq & 31) << 1) + px;             // [0,64)
                sbuf[m][oyl][oxl] = acc[cls][r] + bv;
            }
        }
    }
    __syncthreads();
    const int t = threadIdx.x;
    if (t < 192) {
        const int c = t >> 6, rw = (t >> 4) & 3, x4 = t & 15;
        const float4 v = *(const float4*)&sbuf[c][rw][x4 << 2];
        const int nb2 = blockIdx.x >> 4, rp = blockIdx.x & 15;
        *(float4*)(out + (size_t)nb2 * 12288 + c * 4096 + (rp * 4 + rw) * 64 + (x4 << 2)) = v;
    }
}

// ---------------- dense FC with optional remaps / bf16 IO ------------------
template<int DIN, int DOUT, bool RELU_IN, bool RELU_OUT, bool REMAP_IN, bool REMAP_OUT,
         bool IN_BF16, bool OUT_BF16>
__global__ __launch_bounds__(256)
void fc_kernel(const void* __restrict__ inv, const float* __restrict__ w,
               const float* __restrict__ bias, void* __restrict__ outv) {
    constexpr int TB = 4;
    __shared__ float a[TB][DIN];
    const int b0 = blockIdx.x * TB;
    for (int idx = threadIdx.x; idx < TB * DIN; idx += 256) {
        int r = idx / DIN, c = idx % DIN;
        float v = IN_BF16 ? bf2f(((const ushort*)inv)[(size_t)(b0 + r) * DIN + c])
                          : ((const float*)inv)[(size_t)(b0 + r) * DIN + c];
        if (RELU_IN) v = fmaxf(v, 0.f);
        int d = REMAP_IN ? ((c & 63) * 16 + (c >> 6)) : c;   // NHWC(p*64+ch) -> ch*16+p
        a[r][d] = v;
    }
    __syncthreads();
    for (int j = threadIdx.x; j < DOUT; j += 256) {
        float acc[TB];
        #pragma unroll
        for (int r = 0; r < TB; ++r) acc[r] = bias[j];
        for (int d = 0; d < DIN; ++d) {
            const float wv = w[(size_t)d * DOUT + j];
            #pragma unroll
            for (int r = 0; r < TB; ++r) acc[r] = fmaf(a[r][d], wv, acc[r]);
        }
        const int jo = REMAP_OUT ? (((j & 15) << 6) + (j >> 4)) : j;  // ch*16+p -> p*64+ch
        #pragma unroll
        for (int r = 0; r < TB; ++r) {
            float v = RELU_OUT ? fmaxf(acc[r], 0.f) : acc[r];
            if (OUT_BF16) ((ushort*)outv)[(size_t)(b0 + r) * DOUT + jo] = f2bf(v);
            else ((float*)outv)[(size_t)(b0 + r) * DOUT + jo] = v;
        }
    }
}

// ---------------- fused encoder switch chain (coalesced, 256 thr/row) ------
__global__ __launch_bounds__(256)
void enc_switch_all(float* __restrict__ h,
                    const float* __restrict__ winT_all,  // [L,192,100] (prepped)
                    const float* __restrict__ bin_all,   // [L,100]
                    const float* __restrict__ wout_all,  // [L,K,10,192]
                    const float* __restrict__ bout_all,  // [L,K,192]
                    const float* __restrict__ wsw_all,   // [L,K,10]
                    const float* __restrict__ bsw_all,   // [L,K]
                    const float* __restrict__ gn_all,    // [L,B,10]
                    int* __restrict__ yidx, float* __restrict__ gateArr) {
    const int b = blockIdx.x, t = threadIdx.x;
    __shared__ float hold[192], r[192], part[200], hid[100], lg[10];
    __shared__ int s_yi; __shared__ float s_gate;
    if (t < 192) { float v = h[(size_t)b * 192 + t]; hold[t] = v; r[t] = fmaxf(v, 0.f); }
    for (int i = 0; i < 10; ++i) {
        __syncthreads();   // r ready
        if (t < 200) {
            const int ks = (t < 100) ? t : t - 100;
            const int half = (t < 100) ? 0 : 1;
            const float* wp = winT_all + (size_t)i * 19200 + half * 9600 + ks;
            const float* rp = r + half * 96;
            float a0 = 0.f, a1 = 0.f, a2 = 0.f, a3 = 0.f;
            #pragma unroll
            for (int dd = 0; dd < 96; dd += 4) {
                a0 = fmaf(rp[dd + 0], wp[(dd + 0) * 100], a0);
                a1 = fmaf(rp[dd + 1], wp[(dd + 1) * 100], a1);
                a2 = fmaf(rp[dd + 2], wp[(dd + 2) * 100], a2);
                a3 = fmaf(rp[dd + 3], wp[(dd + 3) * 100], a3);
            }
            part[t] = (a0 + a1) + (a2 + a3);
        }
        __syncthreads();
        if (t < 100) hid[t] = part[t] + part[t + 100] + bin_all[i * 100 + t];
        __syncthreads();
        if (t < 10) {
            const float* wsw = wsw_all + i * 100 + t * 10;
            float acc = bsw_all[i * 10 + t];
            #pragma unroll
            for (int s = 0; s < 10; ++s) acc = fmaf(hid[t * 10 + s], wsw[s], acc);
            lg[t] = acc - logf(gn_all[(size_t)i * 10240 + b * 10 + t] + 1e-20f);
        }
        __syncthreads();
        if (t == 0) {
            int bi = 0; float best = lg[0];
            #pragma unroll
            for (int k = 1; k < 10; ++k) if (lg[k] > best) { best = lg[k]; bi = k; }
            float sum = 0.f;
            #pragma unroll
            for (int k = 0; k < 10; ++k) sum += expf(lg[k] - best);
            const float ysoft = 1.0f / sum;
            s_yi = bi; s_gate = (1.0f - ysoft) + ysoft;
            yidx[i * 1024 + b] = bi; gateArr[i * 1024 + b] = s_gate;
        }
        __syncthreads();
        const int yi = s_yi; const float gate = s_gate;
        if (t < 192) {
            const float* wp = wout_all + (size_t)i * 19200 + yi * 1920 + t;
            float acc = bout_all[i * 1920 + yi * 192 + t];
            #pragma unroll
            for (int s = 0; s < 10; ++s) acc = fmaf(hid[yi * 10 + s], wp[s * 192], acc);
            float nv = hold[t] + acc * gate;
            hold[t] = nv; r[t] = fmaxf(nv, 0.f);
        }
    }
    __syncthreads();
    if (t < 192) h[(size_t)b * 192 + t] = hold[t];
}

// ---------------- fused decoder switch chain (240-wide hid) ----------------
__global__ __launch_bounds__(256)
void dec_switch_all(float* __restrict__ h,
                    const float* __restrict__ win_all,   // [L,K,192,10]
                    const float* __restrict__ bin_all,   // [L,K,10]
                    const float* __restrict__ wout_all,  // [L,K,10,192]
                    const float* __restrict__ bout_all,  // [L,K,192]
                    const int* __restrict__ yidx, const float* __restrict__ gateArr) {
    const int b = blockIdx.x, t = threadIdx.x;
    __shared__ float hold[192], r[192], part[240], hid[10];
    if (t < 192) { float v = h[(size_t)b * 192 + t]; hold[t] = v; r[t] = fmaxf(v, 0.f); }
    for (int i = 0; i < 10; ++i) {
        const int yi = yidx[i * 1024 + b];
        const float gate = gateArr[i * 1024 + b];
        __syncthreads();   // r ready
        if (t < 240) {
            const int s = t % 10, g = t / 10;     // 24 groups x 8 d's
            const float* wp = win_all + (size_t)i * 19200 + yi * 1920 + s;
            const int d0 = g * 8;
            float a0 = 0.f, a1 = 0.f;
            #pragma unroll
            for (int dd = 0; dd < 8; dd += 2) {
                a0 = fmaf(r[d0 + dd + 0], wp[(d0 + dd + 0) * 10], a0);
                a1 = fmaf(r[d0 + dd + 1], wp[(d0 + dd + 1) * 10], a1);
            }
            part[t] = a0 + a1;
        }
        __syncthreads();
        if (t < 10) {
            float acc = bin_all[i * 100 + yi * 10 + t];
            #pragma unroll
            for (int g = 0; g < 24; ++g) acc += part[g * 10 + t];
            hid[t] = acc;
        }
        __syncthreads();
        if (t < 192) {
            const float* wp = wout_all + (size_t)i * 19200 + yi * 1920 + t;
            float acc = bout_all[i * 1920 + yi * 192 + t];
            #pragma unroll
            for (int s = 0; s < 10; ++s) acc = fmaf(hid[s], wp[s * 192], acc);
            float nv = hold[t] + acc * gate;
            hold[t] = nv; r[t] = fmaxf(nv, 0.f);
        }
    }
    __syncthreads();
    if (t < 192) h[(size_t)b * 192 + t] = hold[t];
}

// ------- z stats + reparameterize + decoder input FC -----------------------
__global__ __launch_bounds__(192)
void zfcl_kernel(const float* __restrict__ h,
                 const float* __restrict__ mw, const float* __restrict__ mb,
                 const float* __restrict__ lw, const float* __restrict__ lb,
                 const float* __restrict__ zn,
                 const float* __restrict__ fw, const float* __restrict__ fb,
                 float* __restrict__ out_z, float* __restrict__ out_mean,
                 float* __restrict__ out_lv, float* __restrict__ dbuf) {
    const int b = blockIdx.x, t = threadIdx.x;
    __shared__ float r[192], pm[160], pl[160], zsh[10];
    for (int d = t; d < 192; d += 192) r[d] = fmaxf(h[(size_t)b * 192 + d], 0.f);
    __syncthreads();
    if (t < 160) {
        const int l = t % 10, g = t / 10;
        float am = 0.f, al = 0.f;
        #pragma unroll
        for (int d = g * 12; d < g * 12 + 12; ++d) {
            am = fmaf(r[d], mw[d * 10 + l], am);
            al = fmaf(r[d], lw[d * 10 + l], al);
        }
        pm[t] = am; pl[t] = al;
    }
    __syncthreads();
    if (t < 10) {
        float zm = mb[t], zl = lb[t];
        #pragma unroll
        for (int g = 0; g < 16; ++g) { zm += pm[g * 10 + t]; zl += pl[g * 10 + t]; }
        const float z = zn[(size_t)b * 10 + t] * expf(zl * 0.5f) + zm;
        out_mean[(size_t)b * 10 + t] = zm;
        out_lv[(size_t)b * 10 + t] = zl;
        out_z[(size_t)b * 10 + t] = z;
        zsh[t] = z;
    }
    __syncthreads();
    for (int d = t; d < 192; d += 192) {
        float acc = fb[d];
        #pragma unroll
        for (int l = 0; l < 10; ++l) acc = fmaf(zsh[l], fw[l * 192 + d], acc);
        dbuf[(size_t)b * 192 + d] = acc;
    }
}

// ---------------------------------------------------------------------------
extern "C" void kernel_launch(void* const* d_in, const int* in_sizes, int n_in,
                              void* d_out, int out_size, void* d_ws, size_t ws_size,
                              hipStream_t stream) {
    const float* x      = (const float*)d_in[0];
    const float* gnoise = (const float*)d_in[1];
    const float* znoise = (const float*)d_in[2];
    const float* cw1 = (const float*)d_in[3];  const float* cb1 = (const float*)d_in[4];
    const float* cw2 = (const float*)d_in[5];  const float* cb2 = (const float*)d_in[6];
    const float* cw3 = (const float*)d_in[7];  const float* cb3 = (const float*)d_in[8];
    const float* cw4 = (const float*)d_in[9];  const float* cb4 = (const float*)d_in[10];
    const float* fc_w = (const float*)d_in[11]; const float* fc_b = (const float*)d_in[12];
    const float* ein_w = (const float*)d_in[13]; const float* ein_b = (const float*)d_in[14];
    const float* eout_w = (const float*)d_in[15]; const float* eout_b = (const float*)d_in[16];
    const float* esw_w = (const float*)d_in[17]; const float* esw_b = (const float*)d_in[18];
    const float* mean_w = (const float*)d_in[19]; const float* mean_b = (const float*)d_in[20];
    const float* lv_w = (const float*)d_in[21]; const float* lv_b = (const float*)d_in[22];
    const float* fcl_w = (const float*)d_in[23]; const float* fcl_b = (const float*)d_in[24];
    const float* din_w = (const float*)d_in[25]; const float* din_b = (const float*)d_in[26];
    const float* dout_w = (const float*)d_in[27]; const float* dout_b = (const float*)d_in[28];
    const float* dfc_w = (const float*)d_in[29]; const float* dfc_b = (const float*)d_in[30];
    const float* dw1 = (const float*)d_in[31]; const float* db1 = (const float*)d_in[32];
    const float* dw2 = (const float*)d_in[33]; const float* db2 = (const float*)d_in[34];
    const float* dw3 = (const float*)d_in[35]; const float* db3 = (const float*)d_in[36];
    const float* dw4 = (const float*)d_in[37]; const float* db4 = (const float*)d_in[38];

    float* out = (float*)d_out;
    float* recon  = out;
    float* z_out  = out + 12582912;
    float* zm_out = z_out + 10240;
    float* zl_out = zm_out + 10240;

    char* ws = (char*)d_ws;
    ushort* xpad  = (ushort*)(ws);                  // [B,64,64,4]  33.5 MB
    ushort* bufA  = (ushort*)(ws + 33554432);       // [B,32,32,32] 67 MB
    ushort* bufB  = (ushort*)(ws + 100663296);      // [B,16,16,32] 16.8 MB
    ushort* bufC  = (ushort*)(ws + 117440512);      // [B,8,8,64]   8.4 MB
    ushort* bufD  = (ushort*)(ws + 125829120);      // [B,4,4,64]   2.1 MB
    float*  bufH  = (float*) (ws + 127926272);      // [B,192]
    float*  bufD2 = (float*) (ws + 128712704);      // [B,192]
    int*    yidx  = (int*)   (ws + 129499136);
    float*  gate  = (float*) (ws + 129540096);
    char*   fb    = ws + 129581056;
    ushort* c1g = (ushort*)(fb);                    //   4096 B
    ushort* c2g = (ushort*)(fb + 4096);             //  32768 B
    ushort* c3g = (ushort*)(fb + 36864);            //  65536 B
    ushort* c4g = (ushort*)(fb + 102400);           // 131072 B
    ushort* d1g = (ushort*)(fb + 233472);           // 131072 B
    ushort* d2g = (ushort*)(fb + 364544);           //  65536 B
    ushort* d3g = (ushort*)(fb + 430080);           //  32768 B
    ushort* d4g = (ushort*)(fb + 462848);           //  16384 B
    float*  encwT = (float*)(fb + 479232);          // 768000 B [L,192,100]

    // ---- packs ----
    x_to_nhwc4<<<16384, 256, 0, stream>>>(x, xpad);
    prep_c1_wfrag<<<8, 256, 0, stream>>>(cw1, c1g);
    prep_conv_wfrag<<<64, 256, 0, stream>>>(cw2, c2g, 32, 32);
    prep_conv_wfrag<<<128, 256, 0, stream>>>(cw3, c3g, 32, 64);
    prep_conv_wfrag<<<256, 256, 0, stream>>>(cw4, c4g, 64, 64);
    prep_deconv_wfrag<<<256, 256, 0, stream>>>(dw1, d1g, 64, 64);
    prep_deconv_wfrag<<<128, 256, 0, stream>>>(dw2, d2g, 64, 32);
    prep_deconv_wfrag<<<64, 256, 0, stream>>>(dw3, d3g, 32, 32);
    prep_dlast_wfrag<<<32, 256, 0, stream>>>(dw4, d4g);
    prep_encwT<<<750, 256, 0, stream>>>(ein_w, encwT);

    // ---- encoder ----
    conv1_mfma<<<16384, 256, 0, stream>>>(xpad, c1g, cb1, bufA);
    conv_mfma<32, 32, 32, 32, 2, true><<<4096, 256, 0, stream>>>(bufA, c2g, cb2, bufB);
    conv_mfma<32, 64, 16, 16, 2, true><<<2048, 256, 0, stream>>>(bufB, c3g, cb3, bufC);
    conv_mfma<64, 64, 8, 8, 2, true><<<512, 256, 0, stream>>>(bufC, c4g, cb4, bufD);
    fc_kernel<1024, 192, false, false, true, false, true, false>
        <<<256, 256, 0, stream>>>(bufD, fc_w, fc_b, bufH);
    enc_switch_all<<<1024, 256, 0, stream>>>(bufH, encwT, ein_b, eout_w, eout_b,
                                             esw_w, esw_b, gnoise, yidx, gate);
    zfcl_kernel<<<1024, 192, 0, stream>>>(bufH, mean_w, mean_b, lv_w, lv_b,
                                          znoise, fcl_w, fcl_b,
                                          z_out, zm_out, zl_out, bufD2);
    dec_switch_all<<<1024, 256, 0, stream>>>(bufD2, din_w, din_b, dout_w, dout_b, yidx, gate);
    fc_kernel<192, 1024, true, true, false, true, false, true>
        <<<256, 256, 0, stream>>>(bufD2, dfc_w, dfc_b, bufD);

    // ---- decoder deconvs (4 parity classes + 2 ntiles fused per thread) ----
    deconv_mfma_fused<64, 64, 4, 4, 2, true><<<512, 256, 0, stream>>>(bufD, d1g, db1, bufC);
    deconv_mfma_fused<64, 32, 8, 8, 2, true><<<1024, 256, 0, stream>>>(bufC, d2g, db2, bufB);
    deconv_mfma_fused<32, 32, 16, 16, 2, true><<<4096, 256, 0, stream>>>(bufB, d3g, db3, bufA);
    deconv_last_fused<<<16384, 256, 0, stream>>>(bufA, d4g, db4, recon);
}

// Round 7
// 415.262 us; speedup vs baseline: 34.7260x; 1.0376x over previous
//
#include <hip/hip_runtime.h>
#include <hip/hip_bf16.h>
#include <math.h>

// ---------------------------------------------------------------------------
// FCSwitchedBetaVAE forward. Conv/deconv stack as implicit-GEMM on
// mfma_f32_16x16x32_bf16 (NHWC bf16 activations, f32 accum). Deconvs fuse all
// 4 parity classes per thread; waves carry multiple m-tiles / n-tiles for
// latency hiding. B=1024, C=3, L=10, D=192, K=10, S=10.
// ---------------------------------------------------------------------------

#define BATCH 1024

using short8 = __attribute__((ext_vector_type(8))) short;
using f32x4  = __attribute__((ext_vector_type(4))) float;

__device__ __forceinline__ ushort f2bf(float f) {
    uint u = __float_as_uint(f);
    uint r = (u + 0x7fffu + ((u >> 16) & 1u)) >> 16;   // RNE
    return (ushort)r;
}
__device__ __forceinline__ float bf2f(ushort u) {
    return __uint_as_float(((uint)u) << 16);
}
constexpr int ilog2(int v) { return v <= 1 ? 0 : 1 + ilog2(v >> 1); }

// ------------------------- input pack: NCHW f32 -> NHWC4 bf16 --------------
__global__ __launch_bounds__(256)
void x_to_nhwc4(const float* __restrict__ x, ushort* __restrict__ xp) {
    int idx = blockIdx.x * 256 + threadIdx.x;       // B*4096
    int pix = idx & 4095; int n = idx >> 12;
    const float* xb = x + (size_t)n * 3 * 4096 + pix;
    ushort4 v;
    v.x = f2bf(xb[0]); v.y = f2bf(xb[4096]); v.z = f2bf(xb[8192]); v.w = 0;
    *(ushort4*)(xp + (size_t)idx * 4) = v;
}

// ------------------------- weight fragment prep ----------------------------
// conv frag [tap16][chunk][ntile][lane64][8]
__global__ void prep_conv_wfrag(const float* __restrict__ w, ushort* __restrict__ frag,
                                int CIN, int COUT) {
    int NCH = CIN / 32, NT = COUT / 16;
    int total = 16 * NCH * NT * 512;
    int idx = blockIdx.x * 256 + threadIdx.x;
    if (idx >= total) return;
    int j = idx & 7; int lane = (idx >> 3) & 63; int rest = idx >> 9;
    int ntile = rest % NT; rest /= NT;
    int ch = rest % NCH; int tap = rest / NCH;
    int o = ntile * 16 + (lane & 15);
    int i = ch * 32 + (lane >> 4) * 8 + j;
    frag[idx] = f2bf(w[((size_t)(o * CIN + i)) * 16 + tap]);
}
// deconv frag [cls4][tapidx4][chunk][ntile][lane64][8]
__global__ void prep_deconv_wfrag(const float* __restrict__ w, ushort* __restrict__ frag,
                                  int CIN, int COUT) {
    int NCH = CIN / 32, NT = COUT / 16;
    int total = 16 * NCH * NT * 512;
    int idx = blockIdx.x * 256 + threadIdx.x;
    if (idx >= total) return;
    int j = idx & 7; int lane = (idx >> 3) & 63; int rest = idx >> 9;
    int ntile = rest % NT; rest /= NT;
    int ch = rest % NCH; rest /= NCH;
    int tapidx = rest % 4; int cls = rest / 4;
    int py = cls >> 1, px = cls & 1, a = tapidx >> 1, b = tapidx & 1;
    int tap = (py + 2 * a) * 4 + (px + 2 * b);
    int o = ntile * 16 + (lane & 15);
    int i = ch * 32 + (lane >> 4) * 8 + j;
    frag[idx] = f2bf(w[((size_t)(o * CIN + i)) * 16 + tap]);
}
// conv1 frag [kstep2][ntile2][lane64][8]; K = tap*4 + c (c=3 is zero pad)
__global__ void prep_c1_wfrag(const float* __restrict__ w, ushort* __restrict__ frag) {
    int idx = blockIdx.x * 256 + threadIdx.x;
    if (idx >= 2 * 2 * 512) return;
    int j = idx & 7; int lane = (idx >> 3) & 63;
    int ntile = (idx >> 9) & 1; int s = idx >> 10;
    int o = ntile * 16 + (lane & 15);
    int kg = lane >> 4;
    int tap = s * 8 + kg * 2 + (j >> 2);
    int c = j & 3;
    frag[idx] = (c < 3) ? f2bf(w[((size_t)(o * 3 + c)) * 16 + tap]) : (ushort)0;
}
// deconv_last frag [cls4][tapidx4][lane64][8]; COUT 3 -> padded 16
__global__ void prep_dlast_wfrag(const float* __restrict__ w, ushort* __restrict__ frag) {
    int idx = blockIdx.x * 256 + threadIdx.x;
    if (idx >= 4 * 4 * 512) return;
    int j = idx & 7; int lane = (idx >> 3) & 63; int rest = idx >> 9;
    int tapidx = rest & 3; int cls = rest >> 2;
    int py = cls >> 1, px = cls & 1, a = tapidx >> 1, b = tapidx & 1;
    int tap = (py + 2 * a) * 4 + (px + 2 * b);
    int o = lane & 15;
    int i = (lane >> 4) * 8 + j;
    frag[idx] = (o < 3) ? f2bf(w[((size_t)(o * 32 + i)) * 16 + tap]) : (ushort)0;
}
// encoder switch win transpose: ein_w [L,K,D,S] -> winT [L,D,K*S]
__global__ void prep_encwT(const float* __restrict__ w, float* __restrict__ wt) {
    int idx = blockIdx.x * 256 + threadIdx.x;
    if (idx >= 10 * 192 * 100) return;
    int ks = idx % 100;
    int d = (idx / 100) % 192;
    int l = idx / 19200;
    int k = ks / 10, s = ks % 10;
    wt[idx] = w[(size_t)l * 19200 + k * 1920 + d * 10 + s];
}

// -------- conv1 MFMA, 4 mtiles + 2 ntiles per wave: xpad -> [B,32,32,32] ---
__global__ __launch_bounds__(256)
void conv1_mfma(const ushort* __restrict__ xp, const ushort* __restrict__ wfrag,
                const float* __restrict__ bias, ushort* __restrict__ out) {
    const int lane = threadIdx.x & 63;
    const int mt0 = (((blockIdx.x << 2) + (threadIdx.x >> 6)) << 2);
    const int m = lane & 15, kg = lane >> 4;
    // preload 4 B-fragments (s x ntile)
    short8 bf[4];
    #pragma unroll
    for (int f = 0; f < 4; ++f)
        bf[f] = *(const short8*)(wfrag + (f << 9) + lane * 8);
    // preload 16 A-gathers (4 mtiles x 2 ksteps x 2 taps)
    short8 av[4][2];
    #pragma unroll
    for (int j = 0; j < 4; ++j) {
        const int p = ((mt0 + j) << 4) + m;
        const int ox = p & 31, oy = (p >> 5) & 31, n = p >> 10;
        const ushort* ib = xp + ((size_t)n << 14);
        const int iy0 = 2 * oy - 1, ix0 = 2 * ox - 1;
        #pragma unroll
        for (int s = 0; s < 2; ++s) {
            short8 a;
            #pragma unroll
            for (int t = 0; t < 2; ++t) {
                const int tap = s * 8 + kg * 2 + t;
                const int ky = tap >> 2, kx = tap & 3;
                const int iy = iy0 + ky, ix = ix0 + kx;
                ushort4 half = {0, 0, 0, 0};
                if ((unsigned)iy < 64u && (unsigned)ix < 64u)
                    half = *(const ushort4*)(ib + (size_t)((iy << 6) + ix) * 4);
                a[4 * t + 0] = (short)half.x; a[4 * t + 1] = (short)half.y;
                a[4 * t + 2] = (short)half.z; a[4 * t + 3] = (short)half.w;
            }
            av[j][s] = a;
        }
    }
    f32x4 acc[4][2];
    #pragma unroll
    for (int j = 0; j < 4; ++j)
        #pragma unroll
        for (int nt = 0; nt < 2; ++nt) acc[j][nt] = (f32x4){0, 0, 0, 0};
    #pragma unroll
    for (int j = 0; j < 4; ++j)
        #pragma unroll
        for (int s = 0; s < 2; ++s)
            #pragma unroll
            for (int nt = 0; nt < 2; ++nt)
                acc[j][nt] = __builtin_amdgcn_mfma_f32_16x16x32_bf16(av[j][s], bf[s * 2 + nt], acc[j][nt], 0, 0, 0);
    #pragma unroll
    for (int j = 0; j < 4; ++j) {
        ushort* ob = out + (size_t)(((mt0 + j) << 4) + (kg << 2)) * 32;
        #pragma unroll
        for (int nt = 0; nt < 2; ++nt) {
            const int och = (nt << 4) + m;
            const float bv = bias[och];
            #pragma unroll
            for (int r = 0; r < 4; ++r) ob[r * 32 + och] = f2bf(fmaxf(acc[j][nt][r] + bv, 0.f));
        }
    }
}

// ------------- generic conv MFMA (s2,p1,k4), NTW ntiles per wave -----------
template<int CIN, int COUT, int HIN, int WIN, int NTW, bool RELU>
__global__ __launch_bounds__(256)
void conv_mfma(const ushort* __restrict__ in, const ushort* __restrict__ wfrag,
               const float* __restrict__ bias, ushort* __restrict__ out) {
    constexpr int HOUT = HIN / 2, WOUT = WIN / 2, NCH = CIN / 32, NT = COUT / 16;
    constexpr int NTG = NT / NTW;
    constexpr int LW = ilog2(WOUT), LH = ilog2(HOUT);
    const int lane = threadIdx.x & 63;
    const int gw = (blockIdx.x << 2) + (threadIdx.x >> 6);
    const int ntg = gw % NTG;
    const int mtile = gw / NTG;
    const int m = lane & 15, kg = lane >> 4;
    const int p = (mtile << 4) + m;
    const int ox = p & (WOUT - 1), oy = (p >> LW) & (HOUT - 1), n = p >> (LW + LH);
    const ushort* ibase = in + (size_t)n * (HIN * WIN * CIN);
    const int iy0 = 2 * oy - 1, ix0 = 2 * ox - 1;
    f32x4 acc[NTW];
    #pragma unroll
    for (int nt = 0; nt < NTW; ++nt) acc[nt] = (f32x4){0, 0, 0, 0};
    const ushort* wl = wfrag + ((size_t)(ntg * NTW) << 9) + lane * 8;
    #pragma unroll
    for (int ky = 0; ky < 4; ++ky) {
        const int iy = iy0 + ky;
        const bool vy = (unsigned)iy < (unsigned)HIN;
        #pragma unroll
        for (int kx = 0; kx < 4; ++kx) {
            const int ix = ix0 + kx;
            const bool v = vy && ((unsigned)ix < (unsigned)WIN);
            const int tap = ky * 4 + kx;
            #pragma unroll
            for (int ch = 0; ch < NCH; ++ch) {
                short8 a = {0, 0, 0, 0, 0, 0, 0, 0};
                if (v) a = *(const short8*)(ibase + (size_t)(iy * WIN + ix) * CIN + ch * 32 + kg * 8);
                #pragma unroll
                for (int nt = 0; nt < NTW; ++nt) {
                    const short8 b = *(const short8*)(wl + ((size_t)((tap * NCH + ch) * NT + nt) << 9));
                    acc[nt] = __builtin_amdgcn_mfma_f32_16x16x32_bf16(a, b, acc[nt], 0, 0, 0);
                }
            }
        }
    }
    ushort* ob = out + (size_t)((mtile << 4) + (kg << 2)) * COUT;
    #pragma unroll
    for (int nt = 0; nt < NTW; ++nt) {
        const int och = ((ntg * NTW + nt) << 4) + m;
        const float bv = bias[och];
        #pragma unroll
        for (int r = 0; r < 4; ++r) {
            float vv = acc[nt][r] + bv;
            if (RELU) vv = fmaxf(vv, 0.f);
            ob[r * COUT + och] = f2bf(vv);
        }
    }
}

// ------ deconv MFMA, 4 parity classes + NTW ntiles fused per thread --------
template<int CIN, int COUT, int HIN, int WIN, int NTW, bool RELU>
__global__ __launch_bounds__(256)
void deconv_mfma_fused(const ushort* __restrict__ in, const ushort* __restrict__ wfrag,
                       const float* __restrict__ bias, ushort* __restrict__ out) {
    constexpr int HOUT = 2 * HIN, WOUT = 2 * WIN, NCH = CIN / 32, NT = COUT / 16;
    constexpr int NTG = NT / NTW;
    constexpr int LW = ilog2(WIN), LH = ilog2(HIN);
    const int lane = threadIdx.x & 63;
    const int gw = (blockIdx.x << 2) + (threadIdx.x >> 6);
    const int ntg = gw % NTG;
    const int mtile = gw / NTG;
    const int m = lane & 15, kg = lane >> 4;
    const int q = (mtile << 4) + m;
    const int oxh = q & (WIN - 1), oyh = (q >> LW) & (HIN - 1), n = q >> (LW + LH);
    const ushort* ibase = in + (size_t)n * (HIN * WIN * CIN);
    f32x4 acc[4][NTW];
    #pragma unroll
    for (int c = 0; c < 4; ++c)
        #pragma unroll
        for (int nt = 0; nt < NTW; ++nt) acc[c][nt] = (f32x4){0, 0, 0, 0};
    const ushort* wl = wfrag + ((size_t)(ntg * NTW) << 9) + lane * 8;
    #pragma unroll
    for (int ch = 0; ch < NCH; ++ch) {
        short8 nb[3][3];
        #pragma unroll
        for (int dy = 0; dy < 3; ++dy) {
            const int iy = oyh + dy - 1;
            const bool vy = (unsigned)iy < (unsigned)HIN;
            #pragma unroll
            for (int dx = 0; dx < 3; ++dx) {
                const int ix = oxh + dx - 1;
                short8 a = {0, 0, 0, 0, 0, 0, 0, 0};
                if (vy && (unsigned)ix < (unsigned)WIN)
                    a = *(const short8*)(ibase + (size_t)(iy * WIN + ix) * CIN + ch * 32 + kg * 8);
                nb[dy][dx] = a;
            }
        }
        #pragma unroll
        for (int cls = 0; cls < 4; ++cls) {
            const int py = cls >> 1, px = cls & 1;
            #pragma unroll
            for (int ti = 0; ti < 4; ++ti) {
                const int a2 = ti >> 1, b2 = ti & 1;
                #pragma unroll
                for (int nt = 0; nt < NTW; ++nt) {
                    const short8 b = *(const short8*)(wl + ((size_t)(((cls * 4 + ti) * NCH + ch) * NT + nt) << 9));
                    acc[cls][nt] = __builtin_amdgcn_mfma_f32_16x16x32_bf16(nb[py + a2][px + b2], b, acc[cls][nt], 0, 0, 0);
                }
            }
        }
    }
    #pragma unroll
    for (int nt = 0; nt < NTW; ++nt) {
        const int och = ((ntg * NTW + nt) << 4) + m;
        const float bv = bias[och];
        #pragma unroll
        for (int cls = 0; cls < 4; ++cls) {
            const int py = cls >> 1, px = cls & 1;
            #pragma unroll
            for (int r = 0; r < 4; ++r) {
                const int qq = (mtile << 4) + (kg << 2) + r;
                const int oxh2 = qq & (WIN - 1), oyh2 = (qq >> LW) & (HIN - 1), n2 = qq >> (LW + LH);
                const int oy = 2 * oyh2 + py, ox = 2 * oxh2 + px;
                float vv = acc[cls][nt][r] + bv;
                if (RELU) vv = fmaxf(vv, 0.f);
                out[(size_t)((n2 * HOUT + oy) * WOUT + ox) * COUT + och] = f2bf(vv);
            }
        }
    }
}

// ---- last deconv: 2 row-stacked mtiles/wave, 4 classes fused, LDS epilogue -
// wid: c01 = wid&1 (col group), rp = (wid>>1)&15 (input row-pair), n = wid>>5.
// Wave covers input rows rp*2, rp*2+1 x cols c01*16..+15. Block (4 waves) =
// input rows R0*2..R0*2+3 x 32 cols -> output 3ch x 8rows x 64cols slab.
__global__ __launch_bounds__(256)
void deconv_last_fused(const ushort* __restrict__ in, const ushort* __restrict__ wfrag,
                       const float* __restrict__ bias, float* __restrict__ out) {
    __shared__ float sbuf[3][8][64];
    const int lane = threadIdx.x & 63;
    const int w = threadIdx.x >> 6;
    const int wid = (blockIdx.x << 2) + w;
    const int c01 = wid & 1;
    const int rp = (wid >> 1) & 15;
    const int n = wid >> 5;
    const int m = lane & 15, kg = lane >> 4;
    const int ox0 = (c01 << 4) + m;
    const int iy0 = (rp << 1) - 1;
    const ushort* ib = in + ((size_t)n << 15);
    short8 nb[4][3];
    #pragma unroll
    for (int rr = 0; rr < 4; ++rr) {
        const int iy = iy0 + rr;
        const bool vy = (unsigned)iy < 32u;
        #pragma unroll
        for (int dc = 0; dc < 3; ++dc) {
            const int ix = ox0 - 1 + dc;
            short8 a = {0, 0, 0, 0, 0, 0, 0, 0};
            if (vy && (unsigned)ix < 32u)
                a = *(const short8*)(ib + (size_t)((iy << 5) + ix) * 32 + kg * 8);
            nb[rr][dc] = a;
        }
    }
    f32x4 acc[2][4];
    #pragma unroll
    for (int j = 0; j < 2; ++j)
        #pragma unroll
        for (int c = 0; c < 4; ++c) acc[j][c] = (f32x4){0, 0, 0, 0};
    const ushort* wl = wfrag + lane * 8;
    #pragma unroll
    for (int cls = 0; cls < 4; ++cls) {
        const int py = cls >> 1, px = cls & 1;
        short8 bf[4];
        #pragma unroll
        for (int ti = 0; ti < 4; ++ti)
            bf[ti] = *(const short8*)(wl + ((cls * 4 + ti) << 9));
        #pragma unroll
        for (int j = 0; j < 2; ++j)
            #pragma unroll
            for (int ti = 0; ti < 4; ++ti) {
                const int a2 = ti >> 1, b2 = ti & 1;
                acc[j][cls] = __builtin_amdgcn_mfma_f32_16x16x32_bf16(nb[j + py + a2][px + b2], bf[ti], acc[j][cls], 0, 0, 0);
            }
    }
    if (m < 3) {
        const float bv = bias[m];
        #pragma unroll
        for (int j = 0; j < 2; ++j)
            #pragma unroll
            for (int cls = 0; cls < 4; ++cls) {
                const int py = cls >> 1, px = cls & 1;
                const int oyl = 2 * (2 * (w >> 1) + j) + py;
                #pragma unroll
                for (int r = 0; r < 4; ++r) {
                    const int oxl = 2 * (((w & 1) << 4) + (kg << 2) + r) + px;
                    sbuf[m][oyl][oxl] = acc[j][cls][r] + bv;
                }
            }
    }
    __syncthreads();
    const int t = threadIdx.x;
    if (t < 192) {
        const int R0 = (blockIdx.x << 1) & 15;
        float* ob = out + (size_t)n * 12288;
        #pragma unroll
        for (int k = 0; k < 2; ++k) {
            const int idx = t + 192 * k;            // 0..383 float4s
            const int c = idx >> 7;
            const int rem = idx & 127;
            const int row = rem >> 4, x4 = rem & 15;
            const float4 v = *(const float4*)&sbuf[c][row][x4 << 2];
            *(float4*)(ob + c * 4096 + ((R0 << 2) + row) * 64 + (x4 << 2)) = v;
        }
    }
}

// ---------------- dense FC with optional remaps / bf16 IO ------------------
template<int DIN, int DOUT, bool RELU_IN, bool RELU_OUT, bool REMAP_IN, bool REMAP_OUT,
         bool IN_BF16, bool OUT_BF16>
__global__ __launch_bounds__(256)
void fc_kernel(const void* __restrict__ inv, const float* __restrict__ w,
               const float* __restrict__ bias, void* __restrict__ outv) {
    constexpr int TB = 4;
    __shared__ float a[TB][DIN];
    const int b0 = blockIdx.x * TB;
    for (int idx = threadIdx.x; idx < TB * DIN; idx += 256) {
        int r = idx / DIN, c = idx % DIN;
        float v = IN_BF16 ? bf2f(((const ushort*)inv)[(size_t)(b0 + r) * DIN + c])
                          : ((const float*)inv)[(size_t)(b0 + r) * DIN + c];
        if (RELU_IN) v = fmaxf(v, 0.f);
        int d = REMAP_IN ? ((c & 63) * 16 + (c >> 6)) : c;   // NHWC(p*64+ch) -> ch*16+p
        a[r][d] = v;
    }
    __syncthreads();
    for (int j = threadIdx.x; j < DOUT; j += 256) {
        float acc[TB];
        #pragma unroll
        for (int r = 0; r < TB; ++r) acc[r] = bias[j];
        for (int d = 0; d < DIN; ++d) {
            const float wv = w[(size_t)d * DOUT + j];
            #pragma unroll
            for (int r = 0; r < TB; ++r) acc[r] = fmaf(a[r][d], wv, acc[r]);
        }
        const int jo = REMAP_OUT ? (((j & 15) << 6) + (j >> 4)) : j;  // ch*16+p -> p*64+ch
        #pragma unroll
        for (int r = 0; r < TB; ++r) {
            float v = RELU_OUT ? fmaxf(acc[r], 0.f) : acc[r];
            if (OUT_BF16) ((ushort*)outv)[(size_t)(b0 + r) * DOUT + jo] = f2bf(v);
            else ((float*)outv)[(size_t)(b0 + r) * DOUT + jo] = v;
        }
    }
}

// ---------------- fused encoder switch chain (coalesced, 256 thr/row) ------
__global__ __launch_bounds__(256)
void enc_switch_all(float* __restrict__ h,
                    const float* __restrict__ winT_all,  // [L,192,100] (prepped)
                    const float* __restrict__ bin_all,   // [L,100]
                    const float* __restrict__ wout_all,  // [L,K,10,192]
                    const float* __restrict__ bout_all,  // [L,K,192]
                    const float* __restrict__ wsw_all,   // [L,K,10]
                    const float* __restrict__ bsw_all,   // [L,K]
                    const float* __restrict__ gn_all,    // [L,B,10]
                    int* __restrict__ yidx, float* __restrict__ gateArr) {
    const int b = blockIdx.x, t = threadIdx.x;
    __shared__ float hold[192], r[192], part[200], hid[100], lg[10];
    __shared__ int s_yi; __shared__ float s_gate;
    if (t < 192) { float v = h[(size_t)b * 192 + t]; hold[t] = v; r[t] = fmaxf(v, 0.f); }
    for (int i = 0; i < 10; ++i) {
        __syncthreads();   // r ready
        if (t < 200) {
            const int ks = (t < 100) ? t : t - 100;
            const int half = (t < 100) ? 0 : 1;
            const float* wp = winT_all + (size_t)i * 19200 + half * 9600 + ks;
            const float* rp = r + half * 96;
            float a0 = 0.f, a1 = 0.f, a2 = 0.f, a3 = 0.f;
            #pragma unroll
            for (int dd = 0; dd < 96; dd += 4) {
                a0 = fmaf(rp[dd + 0], wp[(dd + 0) * 100], a0);
                a1 = fmaf(rp[dd + 1], wp[(dd + 1) * 100], a1);
                a2 = fmaf(rp[dd + 2], wp[(dd + 2) * 100], a2);
                a3 = fmaf(rp[dd + 3], wp[(dd + 3) * 100], a3);
            }
            part[t] = (a0 + a1) + (a2 + a3);
        }
        __syncthreads();
        if (t < 100) hid[t] = part[t] + part[t + 100] + bin_all[i * 100 + t];
        __syncthreads();
        if (t < 10) {
            const float* wsw = wsw_all + i * 100 + t * 10;
            float acc = bsw_all[i * 10 + t];
            #pragma unroll
            for (int s = 0; s < 10; ++s) acc = fmaf(hid[t * 10 + s], wsw[s], acc);
            lg[t] = acc - logf(gn_all[(size_t)i * 10240 + b * 10 + t] + 1e-20f);
        }
        __syncthreads();
        if (t == 0) {
            int bi = 0; float best = lg[0];
            #pragma unroll
            for (int k = 1; k < 10; ++k) if (lg[k] > best) { best = lg[k]; bi = k; }
            float sum = 0.f;
            #pragma unroll
            for (int k = 0; k < 10; ++k) sum += expf(lg[k] - best);
            const float ysoft = 1.0f / sum;
            s_yi = bi; s_gate = (1.0f - ysoft) + ysoft;
            yidx[i * 1024 + b] = bi; gateArr[i * 1024 + b] = s_gate;
        }
        __syncthreads();
        const int yi = s_yi; const float gate = s_gate;
        if (t < 192) {
            const float* wp = wout_all + (size_t)i * 19200 + yi * 1920 + t;
            float acc = bout_all[i * 1920 + yi * 192 + t];
            #pragma unroll
            for (int s = 0; s < 10; ++s) acc = fmaf(hid[yi * 10 + s], wp[s * 192], acc);
            float nv = hold[t] + acc * gate;
            hold[t] = nv; r[t] = fmaxf(nv, 0.f);
        }
    }
    __syncthreads();
    if (t < 192) h[(size_t)b * 192 + t] = hold[t];
}

// ---------------- fused decoder switch chain (240-wide hid) ----------------
__global__ __launch_bounds__(256)
void dec_switch_all(float* __restrict__ h,
                    const float* __restrict__ win_all,   // [L,K,192,10]
                    const float* __restrict__ bin_all,   // [L,K,10]
                    const float* __restrict__ wout_all,  // [L,K,10,192]
                    const float* __restrict__ bout_all,  // [L,K,192]
                    const int* __restrict__ yidx, const float* __restrict__ gateArr) {
    const int b = blockIdx.x, t = threadIdx.x;
    __shared__ float hold[192], r[192], part[240], hid[10];
    if (t < 192) { float v = h[(size_t)b * 192 + t]; hold[t] = v; r[t] = fmaxf(v, 0.f); }
    for (int i = 0; i < 10; ++i) {
        const int yi = yidx[i * 1024 + b];
        const float gate = gateArr[i * 1024 + b];
        __syncthreads();   // r ready
        if (t < 240) {
            const int s = t % 10, g = t / 10;     // 24 groups x 8 d's
            const float* wp = win_all + (size_t)i * 19200 + yi * 1920 + s;
            const int d0 = g * 8;
            float a0 = 0.f, a1 = 0.f;
            #pragma unroll
            for (int dd = 0; dd < 8; dd += 2) {
                a0 = fmaf(r[d0 + dd + 0], wp[(d0 + dd + 0) * 10], a0);
                a1 = fmaf(r[d0 + dd + 1], wp[(d0 + dd + 1) * 10], a1);
            }
            part[t] = a0 + a1;
        }
        __syncthreads();
        if (t < 10) {
            float acc = bin_all[i * 100 + yi * 10 + t];
            #pragma unroll
            for (int g = 0; g < 24; ++g) acc += part[g * 10 + t];
            hid[t] = acc;
        }
        __syncthreads();
        if (t < 192) {
            const float* wp = wout_all + (size_t)i * 19200 + yi * 1920 + t;
            float acc = bout_all[i * 1920 + yi * 192 + t];
            #pragma unroll
            for (int s = 0; s < 10; ++s) acc = fmaf(hid[s], wp[s * 192], acc);
            float nv = hold[t] + acc * gate;
            hold[t] = nv; r[t] = fmaxf(nv, 0.f);
        }
    }
    __syncthreads();
    if (t < 192) h[(size_t)b * 192 + t] = hold[t];
}

// ------- z stats + reparameterize + decoder input FC -----------------------
__global__ __launch_bounds__(192)
void zfcl_kernel(const float* __restrict__ h,
                 const float* __restrict__ mw, const float* __restrict__ mb,
                 const float* __restrict__ lw, const float* __restrict__ lb,
                 const float* __restrict__ zn,
                 const float* __restrict__ fw, const float* __restrict__ fb,
                 float* __restrict__ out_z, float* __restrict__ out_mean,
                 float* __restrict__ out_lv, float* __restrict__ dbuf) {
    const int b = blockIdx.x, t = threadIdx.x;
    __shared__ float r[192], pm[160], pl[160], zsh[10];
    for (int d = t; d < 192; d += 192) r[d] = fmaxf(h[(size_t)b * 192 + d], 0.f);
    __syncthreads();
    if (t < 160) {
        const int l = t % 10, g = t / 10;
        float am = 0.f, al = 0.f;
        #pragma unroll
        for (int d = g * 12; d < g * 12 + 12; ++d) {
            am = fmaf(r[d], mw[d * 10 + l], am);
            al = fmaf(r[d], lw[d * 10 + l], al);
        }
        pm[t] = am; pl[t] = al;
    }
    __syncthreads();
    if (t < 10) {
        float zm = mb[t], zl = lb[t];
        #pragma unroll
        for (int g = 0; g < 16; ++g) { zm += pm[g * 10 + t]; zl += pl[g * 10 + t]; }
        const float z = zn[(size_t)b * 10 + t] * expf(zl * 0.5f) + zm;
        out_mean[(size_t)b * 10 + t] = zm;
        out_lv[(size_t)b * 10 + t] = zl;
        out_z[(size_t)b * 10 + t] = z;
        zsh[t] = z;
    }
    __syncthreads();
    for (int d = t; d < 192; d += 192) {
        float acc = fb[d];
        #pragma unroll
        for (int l = 0; l < 10; ++l) acc = fmaf(zsh[l], fw[l * 192 + d], acc);
        dbuf[(size_t)b * 192 + d] = acc;
    }
}

// ---------------------------------------------------------------------------
extern "C" void kernel_launch(void* const* d_in, const int* in_sizes, int n_in,
                              void* d_out, int out_size, void* d_ws, size_t ws_size,
                              hipStream_t stream) {
    const float* x      = (const float*)d_in[0];
    const float* gnoise = (const float*)d_in[1];
    const float* znoise = (const float*)d_in[2];
    const float* cw1 = (const float*)d_in[3];  const float* cb1 = (const float*)d_in[4];
    const float* cw2 = (const float*)d_in[5];  const float* cb2 = (const float*)d_in[6];
    const float* cw3 = (const float*)d_in[7];  const float* cb3 = (const float*)d_in[8];
    const float* cw4 = (const float*)d_in[9];  const float* cb4 = (const float*)d_in[10];
    const float* fc_w = (const float*)d_in[11]; const float* fc_b = (const float*)d_in[12];
    const float* ein_w = (const float*)d_in[13]; const float* ein_b = (const float*)d_in[14];
    const float* eout_w = (const float*)d_in[15]; const float* eout_b = (const float*)d_in[16];
    const float* esw_w = (const float*)d_in[17]; const float* esw_b = (const float*)d_in[18];
    const float* mean_w = (const float*)d_in[19]; const float* mean_b = (const float*)d_in[20];
    const float* lv_w = (const float*)d_in[21]; const float* lv_b = (const float*)d_in[22];
    const float* fcl_w = (const float*)d_in[23]; const float* fcl_b = (const float*)d_in[24];
    const float* din_w = (const float*)d_in[25]; const float* din_b = (const float*)d_in[26];
    const float* dout_w = (const float*)d_in[27]; const float* dout_b = (const float*)d_in[28];
    const float* dfc_w = (const float*)d_in[29]; const float* dfc_b = (const float*)d_in[30];
    const float* dw1 = (const float*)d_in[31]; const float* db1 = (const float*)d_in[32];
    const float* dw2 = (const float*)d_in[33]; const float* db2 = (const float*)d_in[34];
    const float* dw3 = (const float*)d_in[35]; const float* db3 = (const float*)d_in[36];
    const float* dw4 = (const float*)d_in[37]; const float* db4 = (const float*)d_in[38];

    float* out = (float*)d_out;
    float* recon  = out;
    float* z_out  = out + 12582912;
    float* zm_out = z_out + 10240;
    float* zl_out = zm_out + 10240;

    char* ws = (char*)d_ws;
    ushort* xpad  = (ushort*)(ws);                  // [B,64,64,4]  33.5 MB
    ushort* bufA  = (ushort*)(ws + 33554432);       // [B,32,32,32] 67 MB
    ushort* bufB  = (ushort*)(ws + 100663296);      // [B,16,16,32] 16.8 MB
    ushort* bufC  = (ushort*)(ws + 117440512);      // [B,8,8,64]   8.4 MB
    ushort* bufD  = (ushort*)(ws + 125829120);      // [B,4,4,64]   2.1 MB
    float*  bufH  = (float*) (ws + 127926272);      // [B,192]
    float*  bufD2 = (float*) (ws + 128712704);      // [B,192]
    int*    yidx  = (int*)   (ws + 129499136);
    float*  gate  = (float*) (ws + 129540096);
    char*   fb    = ws + 129581056;
    ushort* c1g = (ushort*)(fb);                    //   4096 B
    ushort* c2g = (ushort*)(fb + 4096);             //  32768 B
    ushort* c3g = (ushort*)(fb + 36864);            //  65536 B
    ushort* c4g = (ushort*)(fb + 102400);           // 131072 B
    ushort* d1g = (ushort*)(fb + 233472);           // 131072 B
    ushort* d2g = (ushort*)(fb + 364544);           //  65536 B
    ushort* d3g = (ushort*)(fb + 430080);           //  32768 B
    ushort* d4g = (ushort*)(fb + 462848);           //  16384 B
    float*  encwT = (float*)(fb + 479232);          // 768000 B [L,192,100]

    // ---- packs ----
    x_to_nhwc4<<<16384, 256, 0, stream>>>(x, xpad);
    prep_c1_wfrag<<<8, 256, 0, stream>>>(cw1, c1g);
    prep_conv_wfrag<<<64, 256, 0, stream>>>(cw2, c2g, 32, 32);
    prep_conv_wfrag<<<128, 256, 0, stream>>>(cw3, c3g, 32, 64);
    prep_conv_wfrag<<<256, 256, 0, stream>>>(cw4, c4g, 64, 64);
    prep_deconv_wfrag<<<256, 256, 0, stream>>>(dw1, d1g, 64, 64);
    prep_deconv_wfrag<<<128, 256, 0, stream>>>(dw2, d2g, 64, 32);
    prep_deconv_wfrag<<<64, 256, 0, stream>>>(dw3, d3g, 32, 32);
    prep_dlast_wfrag<<<32, 256, 0, stream>>>(dw4, d4g);
    prep_encwT<<<750, 256, 0, stream>>>(ein_w, encwT);

    // ---- encoder ----
    conv1_mfma<<<4096, 256, 0, stream>>>(xpad, c1g, cb1, bufA);
    conv_mfma<32, 32, 32, 32, 2, true><<<4096, 256, 0, stream>>>(bufA, c2g, cb2, bufB);
    conv_mfma<32, 64, 16, 16, 4, true><<<1024, 256, 0, stream>>>(bufB, c3g, cb3, bufC);
    conv_mfma<64, 64, 8, 8, 4, true><<<256, 256, 0, stream>>>(bufC, c4g, cb4, bufD);
    fc_kernel<1024, 192, false, false, true, false, true, false>
        <<<256, 256, 0, stream>>>(bufD, fc_w, fc_b, bufH);
    enc_switch_all<<<1024, 256, 0, stream>>>(bufH, encwT, ein_b, eout_w, eout_b,
                                             esw_w, esw_b, gnoise, yidx, gate);
    zfcl_kernel<<<1024, 192, 0, stream>>>(bufH, mean_w, mean_b, lv_w, lv_b,
                                          znoise, fcl_w, fcl_b,
                                          z_out, zm_out, zl_out, bufD2);
    dec_switch_all<<<1024, 256, 0, stream>>>(bufD2, din_w, din_b, dout_w, dout_b, yidx, gate);
    fc_kernel<192, 1024, true, true, false, true, false, true>
        <<<256, 256, 0, stream>>>(bufD2, dfc_w, dfc_b, bufD);

    // ---- decoder deconvs ----
    deconv_mfma_fused<64, 64, 4, 4, 4, true><<<256, 256, 0, stream>>>(bufD, d1g, db1, bufC);
    deconv_mfma_fused<64, 32, 8, 8, 2, true><<<1024, 256, 0, stream>>>(bufC, d2g, db2, bufB);
    deconv_mfma_fused<32, 32, 16, 16, 2, true><<<4096, 256, 0, stream>>>(bufB, d3g, db3, bufA);
    deconv_last_fused<<<8192, 256, 0, stream>>>(bufA, d4g, db4, recon);
}

// Round 8
// 356.323 us; speedup vs baseline: 40.4700x; 1.1654x over previous
//
#include <hip/hip_runtime.h>
#include <hip/hip_bf16.h>
#include <math.h>

// ---------------------------------------------------------------------------
// FCSwitchedBetaVAE forward. Conv/deconv/FC stack as implicit-GEMM on
// mfma_f32_16x16x32_bf16 (NHWC bf16 activations, f32 accum). Deconvs fuse all
// 4 parity classes per thread; waves carry multiple m-/n-tiles for latency
// hiding. B=1024, C=3, L=10, D=192, K=10, S=10.
// ---------------------------------------------------------------------------

#define BATCH 1024

using short8 = __attribute__((ext_vector_type(8))) short;
using f32x4  = __attribute__((ext_vector_type(4))) float;

__device__ __forceinline__ ushort f2bf(float f) {
    uint u = __float_as_uint(f);
    uint r = (u + 0x7fffu + ((u >> 16) & 1u)) >> 16;   // RNE
    return (ushort)r;
}
__device__ __forceinline__ float bf2f(ushort u) {
    return __uint_as_float(((uint)u) << 16);
}
constexpr int ilog2(int v) { return v <= 1 ? 0 : 1 + ilog2(v >> 1); }

// ------------------------- input pack: NCHW f32 -> NHWC4 bf16 --------------
__global__ __launch_bounds__(256)
void x_to_nhwc4(const float* __restrict__ x, ushort* __restrict__ xp) {
    int idx = blockIdx.x * 256 + threadIdx.x;       // B*4096
    int pix = idx & 4095; int n = idx >> 12;
    const float* xb = x + (size_t)n * 3 * 4096 + pix;
    ushort4 v;
    v.x = f2bf(xb[0]); v.y = f2bf(xb[4096]); v.z = f2bf(xb[8192]); v.w = 0;
    *(ushort4*)(xp + (size_t)idx * 4) = v;
}

// ------------------------- weight fragment prep ----------------------------
// conv frag [tap16][chunk][ntile][lane64][8]
__global__ void prep_conv_wfrag(const float* __restrict__ w, ushort* __restrict__ frag,
                                int CIN, int COUT) {
    int NCH = CIN / 32, NT = COUT / 16;
    int total = 16 * NCH * NT * 512;
    int idx = blockIdx.x * 256 + threadIdx.x;
    if (idx >= total) return;
    int j = idx & 7; int lane = (idx >> 3) & 63; int rest = idx >> 9;
    int ntile = rest % NT; rest /= NT;
    int ch = rest % NCH; int tap = rest / NCH;
    int o = ntile * 16 + (lane & 15);
    int i = ch * 32 + (lane >> 4) * 8 + j;
    frag[idx] = f2bf(w[((size_t)(o * CIN + i)) * 16 + tap]);
}
// deconv frag [cls4][tapidx4][chunk][ntile][lane64][8]
__global__ void prep_deconv_wfrag(const float* __restrict__ w, ushort* __restrict__ frag,
                                  int CIN, int COUT) {
    int NCH = CIN / 32, NT = COUT / 16;
    int total = 16 * NCH * NT * 512;
    int idx = blockIdx.x * 256 + threadIdx.x;
    if (idx >= total) return;
    int j = idx & 7; int lane = (idx >> 3) & 63; int rest = idx >> 9;
    int ntile = rest % NT; rest /= NT;
    int ch = rest % NCH; rest /= NCH;
    int tapidx = rest % 4; int cls = rest / 4;
    int py = cls >> 1, px = cls & 1, a = tapidx >> 1, b = tapidx & 1;
    int tap = (py + 2 * a) * 4 + (px + 2 * b);
    int o = ntile * 16 + (lane & 15);
    int i = ch * 32 + (lane >> 4) * 8 + j;
    frag[idx] = f2bf(w[((size_t)(o * CIN + i)) * 16 + tap]);
}
// conv1 frag [kstep2][ntile2][lane64][8]; K = tap*4 + c (c=3 is zero pad)
__global__ void prep_c1_wfrag(const float* __restrict__ w, ushort* __restrict__ frag) {
    int idx = blockIdx.x * 256 + threadIdx.x;
    if (idx >= 2 * 2 * 512) return;
    int j = idx & 7; int lane = (idx >> 3) & 63;
    int ntile = (idx >> 9) & 1; int s = idx >> 10;
    int o = ntile * 16 + (lane & 15);
    int kg = lane >> 4;
    int tap = s * 8 + kg * 2 + (j >> 2);
    int c = j & 3;
    frag[idx] = (c < 3) ? f2bf(w[((size_t)(o * 3 + c)) * 16 + tap]) : (ushort)0;
}
// deconv_last frag [cls4][tapidx4][lane64][8]; COUT 3 -> padded 16
__global__ void prep_dlast_wfrag(const float* __restrict__ w, ushort* __restrict__ frag) {
    int idx = blockIdx.x * 256 + threadIdx.x;
    if (idx >= 4 * 4 * 512) return;
    int j = idx & 7; int lane = (idx >> 3) & 63; int rest = idx >> 9;
    int tapidx = rest & 3; int cls = rest >> 2;
    int py = cls >> 1, px = cls & 1, a = tapidx >> 1, b = tapidx & 1;
    int tap = (py + 2 * a) * 4 + (px + 2 * b);
    int o = lane & 15;
    int i = (lane >> 4) * 8 + j;
    frag[idx] = (o < 3) ? f2bf(w[((size_t)(o * 32 + i)) * 16 + tap]) : (ushort)0;
}
// encoder switch win transpose: ein_w [L,K,D,S] -> winT [L,D,K*S]
__global__ void prep_encwT(const float* __restrict__ w, float* __restrict__ wt) {
    int idx = blockIdx.x * 256 + threadIdx.x;
    if (idx >= 10 * 192 * 100) return;
    int ks = idx % 100;
    int d = (idx / 100) % 192;
    int l = idx / 19200;
    int k = ks / 10, s = ks % 10;
    wt[idx] = w[(size_t)l * 19200 + k * 1920 + d * 10 + s];
}
// fc1 frag [kstep32][ntile12][lane64][8]; A is natural NHWC flat (p*64+ch),
// weight row d = ch*16+p baked in.
__global__ void prep_fc1_wfrag(const float* __restrict__ w, ushort* __restrict__ frag) {
    int idx = blockIdx.x * 256 + threadIdx.x;
    if (idx >= 32 * 12 * 512) return;
    int jj = idx & 7; int lane = (idx >> 3) & 63; int rest = idx >> 9;
    int nt = rest % 12, s = rest / 12;
    int k_nat = s * 32 + (lane >> 4) * 8 + jj;
    int d = (k_nat & 63) * 16 + (k_nat >> 6);
    int j = nt * 16 + (lane & 15);
    frag[idx] = f2bf(w[(size_t)d * 192 + j]);
}
// dfc frag [kstep6][ntile64][lane64][8]; output col is natural NHWC flat
// j_nat = p*64+ch, weight col d = ch*16+p baked in.
__global__ void prep_dfc_wfrag(const float* __restrict__ w, ushort* __restrict__ frag) {
    int idx = blockIdx.x * 256 + threadIdx.x;
    if (idx >= 6 * 64 * 512) return;
    int jj = idx & 7; int lane = (idx >> 3) & 63; int rest = idx >> 9;
    int nt = rest % 64, s = rest / 64;
    int k = s * 32 + (lane >> 4) * 8 + jj;
    int j_nat = nt * 16 + (lane & 15);
    int d = (j_nat & 63) * 16 + (j_nat >> 6);
    frag[idx] = f2bf(w[(size_t)k * 1024 + d]);
}

// -------- conv1 MFMA, 4 mtiles + 2 ntiles per wave: xpad -> [B,32,32,32] ---
__global__ __launch_bounds__(256)
void conv1_mfma(const ushort* __restrict__ xp, const ushort* __restrict__ wfrag,
                const float* __restrict__ bias, ushort* __restrict__ out) {
    const int lane = threadIdx.x & 63;
    const int mt0 = (((blockIdx.x << 2) + (threadIdx.x >> 6)) << 2);
    const int m = lane & 15, kg = lane >> 4;
    short8 bf[4];
    #pragma unroll
    for (int f = 0; f < 4; ++f)
        bf[f] = *(const short8*)(wfrag + (f << 9) + lane * 8);
    short8 av[4][2];
    #pragma unroll
    for (int j = 0; j < 4; ++j) {
        const int p = ((mt0 + j) << 4) + m;
        const int ox = p & 31, oy = (p >> 5) & 31, n = p >> 10;
        const ushort* ib = xp + ((size_t)n << 14);
        const int iy0 = 2 * oy - 1, ix0 = 2 * ox - 1;
        #pragma unroll
        for (int s = 0; s < 2; ++s) {
            short8 a;
            #pragma unroll
            for (int t = 0; t < 2; ++t) {
                const int tap = s * 8 + kg * 2 + t;
                const int ky = tap >> 2, kx = tap & 3;
                const int iy = iy0 + ky, ix = ix0 + kx;
                ushort4 half = {0, 0, 0, 0};
                if ((unsigned)iy < 64u && (unsigned)ix < 64u)
                    half = *(const ushort4*)(ib + (size_t)((iy << 6) + ix) * 4);
                a[4 * t + 0] = (short)half.x; a[4 * t + 1] = (short)half.y;
                a[4 * t + 2] = (short)half.z; a[4 * t + 3] = (short)half.w;
            }
            av[j][s] = a;
        }
    }
    f32x4 acc[4][2];
    #pragma unroll
    for (int j = 0; j < 4; ++j)
        #pragma unroll
        for (int nt = 0; nt < 2; ++nt) acc[j][nt] = (f32x4){0, 0, 0, 0};
    #pragma unroll
    for (int j = 0; j < 4; ++j)
        #pragma unroll
        for (int s = 0; s < 2; ++s)
            #pragma unroll
            for (int nt = 0; nt < 2; ++nt)
                acc[j][nt] = __builtin_amdgcn_mfma_f32_16x16x32_bf16(av[j][s], bf[s * 2 + nt], acc[j][nt], 0, 0, 0);
    #pragma unroll
    for (int j = 0; j < 4; ++j) {
        ushort* ob = out + (size_t)(((mt0 + j) << 4) + (kg << 2)) * 32;
        #pragma unroll
        for (int nt = 0; nt < 2; ++nt) {
            const int och = (nt << 4) + m;
            const float bv = bias[och];
            #pragma unroll
            for (int r = 0; r < 4; ++r) ob[r * 32 + och] = f2bf(fmaxf(acc[j][nt][r] + bv, 0.f));
        }
    }
}

// ------------- generic conv MFMA (s2,p1,k4), NTW ntiles per wave -----------
template<int CIN, int COUT, int HIN, int WIN, int NTW, bool RELU>
__global__ __launch_bounds__(256)
void conv_mfma(const ushort* __restrict__ in, const ushort* __restrict__ wfrag,
               const float* __restrict__ bias, ushort* __restrict__ out) {
    constexpr int HOUT = HIN / 2, WOUT = WIN / 2, NCH = CIN / 32, NT = COUT / 16;
    constexpr int NTG = NT / NTW;
    constexpr int LW = ilog2(WOUT), LH = ilog2(HOUT);
    const int lane = threadIdx.x & 63;
    const int gw = (blockIdx.x << 2) + (threadIdx.x >> 6);
    const int ntg = gw % NTG;
    const int mtile = gw / NTG;
    const int m = lane & 15, kg = lane >> 4;
    const int p = (mtile << 4) + m;
    const int ox = p & (WOUT - 1), oy = (p >> LW) & (HOUT - 1), n = p >> (LW + LH);
    const ushort* ibase = in + (size_t)n * (HIN * WIN * CIN);
    const int iy0 = 2 * oy - 1, ix0 = 2 * ox - 1;
    f32x4 acc[NTW];
    #pragma unroll
    for (int nt = 0; nt < NTW; ++nt) acc[nt] = (f32x4){0, 0, 0, 0};
    const ushort* wl = wfrag + ((size_t)(ntg * NTW) << 9) + lane * 8;
    #pragma unroll
    for (int ky = 0; ky < 4; ++ky) {
        const int iy = iy0 + ky;
        const bool vy = (unsigned)iy < (unsigned)HIN;
        #pragma unroll
        for (int kx = 0; kx < 4; ++kx) {
            const int ix = ix0 + kx;
            const bool v = vy && ((unsigned)ix < (unsigned)WIN);
            const int tap = ky * 4 + kx;
            #pragma unroll
            for (int ch = 0; ch < NCH; ++ch) {
                short8 a = {0, 0, 0, 0, 0, 0, 0, 0};
                if (v) a = *(const short8*)(ibase + (size_t)(iy * WIN + ix) * CIN + ch * 32 + kg * 8);
                #pragma unroll
                for (int nt = 0; nt < NTW; ++nt) {
                    const short8 b = *(const short8*)(wl + ((size_t)((tap * NCH + ch) * NT + nt) << 9));
                    acc[nt] = __builtin_amdgcn_mfma_f32_16x16x32_bf16(a, b, acc[nt], 0, 0, 0);
                }
            }
        }
    }
    ushort* ob = out + (size_t)((mtile << 4) + (kg << 2)) * COUT;
    #pragma unroll
    for (int nt = 0; nt < NTW; ++nt) {
        const int och = ((ntg * NTW + nt) << 4) + m;
        const float bv = bias[och];
        #pragma unroll
        for (int r = 0; r < 4; ++r) {
            float vv = acc[nt][r] + bv;
            if (RELU) vv = fmaxf(vv, 0.f);
            ob[r * COUT + och] = f2bf(vv);
        }
    }
}

// ------ deconv MFMA, 4 parity classes + NTW ntiles fused per thread --------
template<int CIN, int COUT, int HIN, int WIN, int NTW, bool RELU>
__global__ __launch_bounds__(256)
void deconv_mfma_fused(const ushort* __restrict__ in, const ushort* __restrict__ wfrag,
                       const float* __restrict__ bias, ushort* __restrict__ out) {
    constexpr int HOUT = 2 * HIN, WOUT = 2 * WIN, NCH = CIN / 32, NT = COUT / 16;
    constexpr int NTG = NT / NTW;
    constexpr int LW = ilog2(WIN), LH = ilog2(HIN);
    const int lane = threadIdx.x & 63;
    const int gw = (blockIdx.x << 2) + (threadIdx.x >> 6);
    const int ntg = gw % NTG;
    const int mtile = gw / NTG;
    const int m = lane & 15, kg = lane >> 4;
    const int q = (mtile << 4) + m;
    const int oxh = q & (WIN - 1), oyh = (q >> LW) & (HIN - 1), n = q >> (LW + LH);
    const ushort* ibase = in + (size_t)n * (HIN * WIN * CIN);
    f32x4 acc[4][NTW];
    #pragma unroll
    for (int c = 0; c < 4; ++c)
        #pragma unroll
        for (int nt = 0; nt < NTW; ++nt) acc[c][nt] = (f32x4){0, 0, 0, 0};
    const ushort* wl = wfrag + ((size_t)(ntg * NTW) << 9) + lane * 8;
    #pragma unroll
    for (int ch = 0; ch < NCH; ++ch) {
        short8 nb[3][3];
        #pragma unroll
        for (int dy = 0; dy < 3; ++dy) {
            const int iy = oyh + dy - 1;
            const bool vy = (unsigned)iy < (unsigned)HIN;
            #pragma unroll
            for (int dx = 0; dx < 3; ++dx) {
                const int ix = oxh + dx - 1;
                short8 a = {0, 0, 0, 0, 0, 0, 0, 0};
                if (vy && (unsigned)ix < (unsigned)WIN)
                    a = *(const short8*)(ibase + (size_t)(iy * WIN + ix) * CIN + ch * 32 + kg * 8);
                nb[dy][dx] = a;
            }
        }
        #pragma unroll
        for (int cls = 0; cls < 4; ++cls) {
            const int py = cls >> 1, px = cls & 1;
            #pragma unroll
            for (int ti = 0; ti < 4; ++ti) {
                const int a2 = ti >> 1, b2 = ti & 1;
                #pragma unroll
                for (int nt = 0; nt < NTW; ++nt) {
                    const short8 b = *(const short8*)(wl + ((size_t)(((cls * 4 + ti) * NCH + ch) * NT + nt) << 9));
                    acc[cls][nt] = __builtin_amdgcn_mfma_f32_16x16x32_bf16(nb[py + a2][px + b2], b, acc[cls][nt], 0, 0, 0);
                }
            }
        }
    }
    #pragma unroll
    for (int nt = 0; nt < NTW; ++nt) {
        const int och = ((ntg * NTW + nt) << 4) + m;
        const float bv = bias[och];
        #pragma unroll
        for (int cls = 0; cls < 4; ++cls) {
            const int py = cls >> 1, px = cls & 1;
            #pragma unroll
            for (int r = 0; r < 4; ++r) {
                const int qq = (mtile << 4) + (kg << 2) + r;
                const int oxh2 = qq & (WIN - 1), oyh2 = (qq >> LW) & (HIN - 1), n2 = qq >> (LW + LH);
                const int oy = 2 * oyh2 + py, ox = 2 * oxh2 + px;
                float vv = acc[cls][nt][r] + bv;
                if (RELU) vv = fmaxf(vv, 0.f);
                out[(size_t)((n2 * HOUT + oy) * WOUT + ox) * COUT + och] = f2bf(vv);
            }
        }
    }
}

// ---- last deconv: 2 row-stacked mtiles/wave, 4 classes fused, LDS epilogue -
__global__ __launch_bounds__(256)
void deconv_last_fused(const ushort* __restrict__ in, const ushort* __restrict__ wfrag,
                       const float* __restrict__ bias, float* __restrict__ out) {
    __shared__ float sbuf[3][8][64];
    const int lane = threadIdx.x & 63;
    const int w = threadIdx.x >> 6;
    const int wid = (blockIdx.x << 2) + w;
    const int c01 = wid & 1;
    const int rp = (wid >> 1) & 15;
    const int n = wid >> 5;
    const int m = lane & 15, kg = lane >> 4;
    const int ox0 = (c01 << 4) + m;
    const int iy0 = (rp << 1) - 1;
    const ushort* ib = in + ((size_t)n << 15);
    short8 nb[4][3];
    #pragma unroll
    for (int rr = 0; rr < 4; ++rr) {
        const int iy = iy0 + rr;
        const bool vy = (unsigned)iy < 32u;
        #pragma unroll
        for (int dc = 0; dc < 3; ++dc) {
            const int ix = ox0 - 1 + dc;
            short8 a = {0, 0, 0, 0, 0, 0, 0, 0};
            if (vy && (unsigned)ix < 32u)
                a = *(const short8*)(ib + (size_t)((iy << 5) + ix) * 32 + kg * 8);
            nb[rr][dc] = a;
        }
    }
    f32x4 acc[2][4];
    #pragma unroll
    for (int j = 0; j < 2; ++j)
        #pragma unroll
        for (int c = 0; c < 4; ++c) acc[j][c] = (f32x4){0, 0, 0, 0};
    const ushort* wl = wfrag + lane * 8;
    #pragma unroll
    for (int cls = 0; cls < 4; ++cls) {
        const int py = cls >> 1, px = cls & 1;
        short8 bf[4];
        #pragma unroll
        for (int ti = 0; ti < 4; ++ti)
            bf[ti] = *(const short8*)(wl + ((cls * 4 + ti) << 9));
        #pragma unroll
        for (int j = 0; j < 2; ++j)
            #pragma unroll
            for (int ti = 0; ti < 4; ++ti) {
                const int a2 = ti >> 1, b2 = ti & 1;
                acc[j][cls] = __builtin_amdgcn_mfma_f32_16x16x32_bf16(nb[j + py + a2][px + b2], bf[ti], acc[j][cls], 0, 0, 0);
            }
    }
    if (m < 3) {
        const float bv = bias[m];
        #pragma unroll
        for (int j = 0; j < 2; ++j)
            #pragma unroll
            for (int cls = 0; cls < 4; ++cls) {
                const int py = cls >> 1, px = cls & 1;
                const int oyl = 2 * (2 * (w >> 1) + j) + py;
                #pragma unroll
                for (int r = 0; r < 4; ++r) {
                    const int oxl = 2 * (((w & 1) << 4) + (kg << 2) + r) + px;
                    sbuf[m][oyl][oxl] = acc[j][cls][r] + bv;
                }
            }
    }
    __syncthreads();
    const int t = threadIdx.x;
    if (t < 192) {
        const int R0 = (blockIdx.x << 1) & 15;
        float* ob = out + (size_t)n * 12288;
        #pragma unroll
        for (int k = 0; k < 2; ++k) {
            const int idx = t + 192 * k;
            const int c = idx >> 7;
            const int rem = idx & 127;
            const int row = rem >> 4, x4 = rem & 15;
            const float4 v = *(const float4*)&sbuf[c][row][x4 << 2];
            *(float4*)(ob + c * 4096 + ((R0 << 2) + row) * 64 + (x4 << 2)) = v;
        }
    }
}

// ---------------- fc1 MFMA: bufD [B,1024] bf16 -> bufH [B,192] f32 ---------
__global__ __launch_bounds__(256)
void fc1_mfma(const ushort* __restrict__ in, const ushort* __restrict__ frag,
              const float* __restrict__ bias, float* __restrict__ out) {
    const int lane = threadIdx.x & 63;
    const int gw = (blockIdx.x << 2) + (threadIdx.x >> 6);   // [0,768)
    const int nt = gw % 12, mt = gw / 12;
    const int m = lane & 15, kg = lane >> 4;
    const ushort* arow = in + ((size_t)(mt * 16 + m) << 10) + kg * 8;
    const ushort* wl = frag + nt * 512 + lane * 8;
    f32x4 acc0 = {0, 0, 0, 0}, acc1 = {0, 0, 0, 0};
    #pragma unroll
    for (int s = 0; s < 32; s += 2) {
        const short8 a0 = *(const short8*)(arow + s * 32);
        const short8 a1 = *(const short8*)(arow + s * 32 + 32);
        const short8 b0 = *(const short8*)(wl + ((size_t)(s * 12) << 9));
        const short8 b1 = *(const short8*)(wl + ((size_t)((s + 1) * 12) << 9));
        acc0 = __builtin_amdgcn_mfma_f32_16x16x32_bf16(a0, b0, acc0, 0, 0, 0);
        acc1 = __builtin_amdgcn_mfma_f32_16x16x32_bf16(a1, b1, acc1, 0, 0, 0);
    }
    const int j = nt * 16 + m;
    const float bv = bias[j];
    #pragma unroll
    for (int r = 0; r < 4; ++r)
        out[(size_t)(mt * 16 + kg * 4 + r) * 192 + j] = (acc0[r] + acc1[r]) + bv;
}

// --------- dfc MFMA: dbf [B,192] bf16 -> bufD [B,1024] bf16 (NHWC), relu ---
__global__ __launch_bounds__(256)
void dfc_mfma(const ushort* __restrict__ in, const ushort* __restrict__ frag,
              const float* __restrict__ bias, ushort* __restrict__ out) {
    const int lane = threadIdx.x & 63;
    const int gw = (blockIdx.x << 2) + (threadIdx.x >> 6);   // [0,1024)
    const int ntg = gw & 15, mt = gw >> 4;
    const int m = lane & 15, kg = lane >> 4;
    const ushort* arow = in + (size_t)(mt * 16 + m) * 192 + kg * 8;
    const ushort* wl = frag + ((size_t)(ntg * 4) << 9) + lane * 8;
    f32x4 acc[4] = {{0,0,0,0},{0,0,0,0},{0,0,0,0},{0,0,0,0}};
    #pragma unroll
    for (int s = 0; s < 6; ++s) {
        const short8 a = *(const short8*)(arow + s * 32);
        #pragma unroll
        for (int q = 0; q < 4; ++q) {
            const short8 b = *(const short8*)(wl + ((size_t)(s * 64 + q) << 9));
            acc[q] = __builtin_amdgcn_mfma_f32_16x16x32_bf16(a, b, acc[q], 0, 0, 0);
        }
    }
    #pragma unroll
    for (int q = 0; q < 4; ++q) {
        const int j_nat = (ntg * 4 + q) * 16 + m;
        const int d = (j_nat & 63) * 16 + (j_nat >> 6);
        const float bv = bias[d];
        #pragma unroll
        for (int r = 0; r < 4; ++r) {
            const float vv = fmaxf(acc[q][r] + bv, 0.f);
            out[((size_t)(mt * 16 + kg * 4 + r) << 10) + j_nat] = f2bf(vv);
        }
    }
}

// ---------------- fused encoder switch chain (coalesced, 256 thr/row) ------
__global__ __launch_bounds__(256)
void enc_switch_all(float* __restrict__ h,
                    const float* __restrict__ winT_all,  // [L,192,100] (prepped)
                    const float* __restrict__ bin_all,   // [L,100]
                    const float* __restrict__ wout_all,  // [L,K,10,192]
                    const float* __restrict__ bout_all,  // [L,K,192]
                    const float* __restrict__ wsw_all,   // [L,K,10]
                    const float* __restrict__ bsw_all,   // [L,K]
                    const float* __restrict__ gn_all,    // [L,B,10]
                    int* __restrict__ yidx, float* __restrict__ gateArr) {
    const int b = blockIdx.x, t = threadIdx.x;
    __shared__ float hold[192], r[192], part[200], hid[100], lg[10];
    __shared__ int s_yi; __shared__ float s_gate;
    if (t < 192) { float v = h[(size_t)b * 192 + t]; hold[t] = v; r[t] = fmaxf(v, 0.f); }
    for (int i = 0; i < 10; ++i) {
        __syncthreads();   // r ready
        if (t < 200) {
            const int ks = (t < 100) ? t : t - 100;
            const int half = (t < 100) ? 0 : 1;
            const float* wp = winT_all + (size_t)i * 19200 + half * 9600 + ks;
            const float* rp = r + half * 96;
            float a0 = 0.f, a1 = 0.f, a2 = 0.f, a3 = 0.f;
            #pragma unroll
            for (int dd = 0; dd < 96; dd += 4) {
                a0 = fmaf(rp[dd + 0], wp[(dd + 0) * 100], a0);
                a1 = fmaf(rp[dd + 1], wp[(dd + 1) * 100], a1);
                a2 = fmaf(rp[dd + 2], wp[(dd + 2) * 100], a2);
                a3 = fmaf(rp[dd + 3], wp[(dd + 3) * 100], a3);
            }
            part[t] = (a0 + a1) + (a2 + a3);
        }
        __syncthreads();
        if (t < 100) hid[t] = part[t] + part[t + 100] + bin_all[i * 100 + t];
        __syncthreads();
        if (t < 10) {
            const float* wsw = wsw_all + i * 100 + t * 10;
            float acc = bsw_all[i * 10 + t];
            #pragma unroll
            for (int s = 0; s < 10; ++s) acc = fmaf(hid[t * 10 + s], wsw[s], acc);
            lg[t] = acc - logf(gn_all[(size_t)i * 10240 + b * 10 + t] + 1e-20f);
        }
        __syncthreads();
        if (t == 0) {
            int bi = 0; float best = lg[0];
            #pragma unroll
            for (int k = 1; k < 10; ++k) if (lg[k] > best) { best = lg[k]; bi = k; }
            float sum = 0.f;
            #pragma unroll
            for (int k = 0; k < 10; ++k) sum += expf(lg[k] - best);
            const float ysoft = 1.0f / sum;
            s_yi = bi; s_gate = (1.0f - ysoft) + ysoft;
            yidx[i * 1024 + b] = bi; gateArr[i * 1024 + b] = s_gate;
        }
        __syncthreads();
        const int yi = s_yi; const float gate = s_gate;
        if (t < 192) {
            const float* wp = wout_all + (size_t)i * 19200 + yi * 1920 + t;
            float acc = bout_all[i * 1920 + yi * 192 + t];
            #pragma unroll
            for (int s = 0; s < 10; ++s) acc = fmaf(hid[yi * 10 + s], wp[s * 192], acc);
            float nv = hold[t] + acc * gate;
            hold[t] = nv; r[t] = fmaxf(nv, 0.f);
        }
    }
    __syncthreads();
    if (t < 192) h[(size_t)b * 192 + t] = hold[t];
}

// ------- fused decoder switch chain; emits bf16 relu'd state for dfc -------
__global__ __launch_bounds__(256)
void dec_switch_all(const float* __restrict__ h,
                    const float* __restrict__ win_all,   // [L,K,192,10]
                    const float* __restrict__ bin_all,   // [L,K,10]
                    const float* __restrict__ wout_all,  // [L,K,10,192]
                    const float* __restrict__ bout_all,  // [L,K,192]
                    const int* __restrict__ yidx, const float* __restrict__ gateArr,
                    ushort* __restrict__ dbf) {
    const int b = blockIdx.x, t = threadIdx.x;
    __shared__ float hold[192], r[192], part[240], hid[10];
    if (t < 192) { float v = h[(size_t)b * 192 + t]; hold[t] = v; r[t] = fmaxf(v, 0.f); }
    for (int i = 0; i < 10; ++i) {
        const int yi = yidx[i * 1024 + b];
        const float gate = gateArr[i * 1024 + b];
        __syncthreads();   // r ready
        if (t < 240) {
            const int s = t % 10, g = t / 10;     // 24 groups x 8 d's
            const float* wp = win_all + (size_t)i * 19200 + yi * 1920 + s;
            const int d0 = g * 8;
            float a0 = 0.f, a1 = 0.f;
            #pragma unroll
            for (int dd = 0; dd < 8; dd += 2) {
                a0 = fmaf(r[d0 + dd + 0], wp[(d0 + dd + 0) * 10], a0);
                a1 = fmaf(r[d0 + dd + 1], wp[(d0 + dd + 1) * 10], a1);
            }
            part[t] = a0 + a1;
        }
        __syncthreads();
        if (t < 10) {
            float acc = bin_all[i * 100 + yi * 10 + t];
            #pragma unroll
            for (int g = 0; g < 24; ++g) acc += part[g * 10 + t];
            hid[t] = acc;
        }
        __syncthreads();
        if (t < 192) {
            const float* wp = wout_all + (size_t)i * 19200 + yi * 1920 + t;
            float acc = bout_all[i * 1920 + yi * 192 + t];
            #pragma unroll
            for (int s = 0; s < 10; ++s) acc = fmaf(hid[s], wp[s * 192], acc);
            float nv = hold[t] + acc * gate;
            hold[t] = nv; r[t] = fmaxf(nv, 0.f);
        }
    }
    if (t < 192) dbf[(size_t)b * 192 + t] = f2bf(r[t]);
}

// ------- z stats + reparameterize + decoder input FC -----------------------
__global__ __launch_bounds__(192)
void zfcl_kernel(const float* __restrict__ h,
                 const float* __restrict__ mw, const float* __restrict__ mb,
                 const float* __restrict__ lw, const float* __restrict__ lb,
                 const float* __restrict__ zn,
                 const float* __restrict__ fw, const float* __restrict__ fb,
                 float* __restrict__ out_z, float* __restrict__ out_mean,
                 float* __restrict__ out_lv, float* __restrict__ dbuf) {
    const int b = blockIdx.x, t = threadIdx.x;
    __shared__ float r[192], pm[160], pl[160], zsh[10];
    for (int d = t; d < 192; d += 192) r[d] = fmaxf(h[(size_t)b * 192 + d], 0.f);
    __syncthreads();
    if (t < 160) {
        const int l = t % 10, g = t / 10;
        float am = 0.f, al = 0.f;
        #pragma unroll
        for (int d = g * 12; d < g * 12 + 12; ++d) {
            am = fmaf(r[d], mw[d * 10 + l], am);
            al = fmaf(r[d], lw[d * 10 + l], al);
        }
        pm[t] = am; pl[t] = al;
    }
    __syncthreads();
    if (t < 10) {
        float zm = mb[t], zl = lb[t];
        #pragma unroll
        for (int g = 0; g < 16; ++g) { zm += pm[g * 10 + t]; zl += pl[g * 10 + t]; }
        const float z = zn[(size_t)b * 10 + t] * expf(zl * 0.5f) + zm;
        out_mean[(size_t)b * 10 + t] = zm;
        out_lv[(size_t)b * 10 + t] = zl;
        out_z[(size_t)b * 10 + t] = z;
        zsh[t] = z;
    }
    __syncthreads();
    for (int d = t; d < 192; d += 192) {
        float acc = fb[d];
        #pragma unroll
        for (int l = 0; l < 10; ++l) acc = fmaf(zsh[l], fw[l * 192 + d], acc);
        dbuf[(size_t)b * 192 + d] = acc;
    }
}

// ---------------------------------------------------------------------------
extern "C" void kernel_launch(void* const* d_in, const int* in_sizes, int n_in,
                              void* d_out, int out_size, void* d_ws, size_t ws_size,
                              hipStream_t stream) {
    const float* x      = (const float*)d_in[0];
    const float* gnoise = (const float*)d_in[1];
    const float* znoise = (const float*)d_in[2];
    const float* cw1 = (const float*)d_in[3];  const float* cb1 = (const float*)d_in[4];
    const float* cw2 = (const float*)d_in[5];  const float* cb2 = (const float*)d_in[6];
    const float* cw3 = (const float*)d_in[7];  const float* cb3 = (const float*)d_in[8];
    const float* cw4 = (const float*)d_in[9];  const float* cb4 = (const float*)d_in[10];
    const float* fc_w = (const float*)d_in[11]; const float* fc_b = (const float*)d_in[12];
    const float* ein_w = (const float*)d_in[13]; const float* ein_b = (const float*)d_in[14];
    const float* eout_w = (const float*)d_in[15]; const float* eout_b = (const float*)d_in[16];
    const float* esw_w = (const float*)d_in[17]; const float* esw_b = (const float*)d_in[18];
    const float* mean_w = (const float*)d_in[19]; const float* mean_b = (const float*)d_in[20];
    const float* lv_w = (const float*)d_in[21]; const float* lv_b = (const float*)d_in[22];
    const float* fcl_w = (const float*)d_in[23]; const float* fcl_b = (const float*)d_in[24];
    const float* din_w = (const float*)d_in[25]; const float* din_b = (const float*)d_in[26];
    const float* dout_w = (const float*)d_in[27]; const float* dout_b = (const float*)d_in[28];
    const float* dfc_w = (const float*)d_in[29]; const float* dfc_b = (const float*)d_in[30];
    const float* dw1 = (const float*)d_in[31]; const float* db1 = (const float*)d_in[32];
    const float* dw2 = (const float*)d_in[33]; const float* db2 = (const float*)d_in[34];
    const float* dw3 = (const float*)d_in[35]; const float* db3 = (const float*)d_in[36];
    const float* dw4 = (const float*)d_in[37]; const float* db4 = (const float*)d_in[38];

    float* out = (float*)d_out;
    float* recon  = out;
    float* z_out  = out + 12582912;
    float* zm_out = z_out + 10240;
    float* zl_out = zm_out + 10240;

    char* ws = (char*)d_ws;
    ushort* xpad  = (ushort*)(ws);                  // [B,64,64,4]  33.5 MB
    ushort* bufA  = (ushort*)(ws + 33554432);       // [B,32,32,32] 67 MB
    ushort* bufB  = (ushort*)(ws + 100663296);      // [B,16,16,32] 16.8 MB
    ushort* bufC  = (ushort*)(ws + 117440512);      // [B,8,8,64]   8.4 MB
    ushort* bufD  = (ushort*)(ws + 125829120);      // [B,4,4,64]   2.1 MB
    float*  bufH  = (float*) (ws + 127926272);      // [B,192]
    float*  bufD2 = (float*) (ws + 128712704);      // [B,192]
    int*    yidx  = (int*)   (ws + 129499136);
    float*  gate  = (float*) (ws + 129540096);
    char*   fb    = ws + 129581056;
    ushort* c1g = (ushort*)(fb);                    //   4096 B
    ushort* c2g = (ushort*)(fb + 4096);             //  32768 B
    ushort* c3g = (ushort*)(fb + 36864);            //  65536 B
    ushort* c4g = (ushort*)(fb + 102400);           // 131072 B
    ushort* d1g = (ushort*)(fb + 233472);           // 131072 B
    ushort* d2g = (ushort*)(fb + 364544);           //  65536 B
    ushort* d3g = (ushort*)(fb + 430080);           //  32768 B
    ushort* d4g = (ushort*)(fb + 462848);           //  16384 B
    float*  encwT = (float*)(fb + 479232);          // 768000 B [L,192,100]
    ushort* fc1g  = (ushort*)(fb + 1247232);        // 393216 B [32][12][512]
    ushort* dfcg  = (ushort*)(fb + 1640448);        // 393216 B [6][64][512]
    ushort* dbf   = (ushort*)(fb + 2033664);        // 393216 B [B,192] bf16

    // ---- packs ----
    x_to_nhwc4<<<16384, 256, 0, stream>>>(x, xpad);
    prep_c1_wfrag<<<8, 256, 0, stream>>>(cw1, c1g);
    prep_conv_wfrag<<<64, 256, 0, stream>>>(cw2, c2g, 32, 32);
    prep_conv_wfrag<<<128, 256, 0, stream>>>(cw3, c3g, 32, 64);
    prep_conv_wfrag<<<256, 256, 0, stream>>>(cw4, c4g, 64, 64);
    prep_deconv_wfrag<<<256, 256, 0, stream>>>(dw1, d1g, 64, 64);
    prep_deconv_wfrag<<<128, 256, 0, stream>>>(dw2, d2g, 64, 32);
    prep_deconv_wfrag<<<64, 256, 0, stream>>>(dw3, d3g, 32, 32);
    prep_dlast_wfrag<<<32, 256, 0, stream>>>(dw4, d4g);
    prep_encwT<<<750, 256, 0, stream>>>(ein_w, encwT);
    prep_fc1_wfrag<<<768, 256, 0, stream>>>(fc_w, fc1g);
    prep_dfc_wfrag<<<768, 256, 0, stream>>>(dfc_w, dfcg);

    // ---- encoder ----
    conv1_mfma<<<4096, 256, 0, stream>>>(xpad, c1g, cb1, bufA);
    conv_mfma<32, 32, 32, 32, 2, true><<<4096, 256, 0, stream>>>(bufA, c2g, cb2, bufB);
    conv_mfma<32, 64, 16, 16, 4, true><<<1024, 256, 0, stream>>>(bufB, c3g, cb3, bufC);
    conv_mfma<64, 64, 8, 8, 4, true><<<256, 256, 0, stream>>>(bufC, c4g, cb4, bufD);
    fc1_mfma<<<192, 256, 0, stream>>>(bufD, fc1g, fc_b, bufH);
    enc_switch_all<<<1024, 256, 0, stream>>>(bufH, encwT, ein_b, eout_w, eout_b,
                                             esw_w, esw_b, gnoise, yidx, gate);
    zfcl_kernel<<<1024, 192, 0, stream>>>(bufH, mean_w, mean_b, lv_w, lv_b,
                                          znoise, fcl_w, fcl_b,
                                          z_out, zm_out, zl_out, bufD2);
    dec_switch_all<<<1024, 256, 0, stream>>>(bufD2, din_w, din_b, dout_w, dout_b,
                                             yidx, gate, dbf);
    dfc_mfma<<<256, 256, 0, stream>>>(dbf, dfcg, dfc_b, bufD);

    // ---- decoder deconvs ----
    deconv_mfma_fused<64, 64, 4, 4, 4, true><<<256, 256, 0, stream>>>(bufD, d1g, db1, bufC);
    deconv_mfma_fused<64, 32, 8, 8, 2, true><<<1024, 256, 0, stream>>>(bufC, d2g, db2, bufB);
    deconv_mfma_fused<32, 32, 16, 16, 2, true><<<4096, 256, 0, stream>>>(bufB, d3g, db3, bufA);
    deconv_last_fused<<<8192, 256, 0, stream>>>(bufA, d4g, db4, recon);
}